// Round 7
// baseline (1166.564 us; speedup 1.0000x reference)
//
#include <hip/hip_runtime.h>
#include <hip/hip_bf16.h>
#include <cstdint>
#include <cstddef>

// Problem constants
#define BATCH 64
#define LSEQ 200
#define HID 256
#define NH 8
#define DH 256            // per-head dim = HID
#define HD (NH*DH)        // 2048
#define MROWS (BATCH*LSEQ)   // 12800
#define EPS 1e-5f
#define CSCALE 0.09014195f   // (1/sqrt(256)) * log2(e), folded into Q projection

typedef unsigned short ushort_t;
typedef __attribute__((ext_vector_type(8))) short bf16x8;         // MFMA A/B frag (4 VGPR)
typedef __attribute__((ext_vector_type(8))) unsigned short u16x8; // 16B of bf16
typedef __attribute__((ext_vector_type(4))) float f32x4;          // MFMA C/D frag

__device__ __forceinline__ float b2f(ushort_t u) {
    union { unsigned int i; float f; } c; c.i = ((unsigned int)u) << 16; return c.f;
}
__device__ __forceinline__ ushort_t f2b(float f) {
    __hip_bfloat16 h = __float2bfloat16(f);
    union { __hip_bfloat16 h; ushort_t u; } c; c.h = h; return c.u;
}
__device__ __forceinline__ float to_f32(float x) { return x; }
__device__ __forceinline__ float to_f32(ushort_t x) { return b2f(x); }
__device__ __forceinline__ void store_val(float* p, float v) { *p = v; }
__device__ __forceinline__ void store_val(ushort_t* p, float v) { *p = f2b(v); }

// packed bf16 max / add on 8 elements
__device__ __forceinline__ u16x8 bmax8(u16x8 a, u16x8 b) {
    union U { u16x8 v; __hip_bfloat162 h[4]; };
    U ua, ub, r; ua.v = a; ub.v = b;
    #pragma unroll
    for (int i = 0; i < 4; ++i) r.h[i] = __hmax2(ua.h[i], ub.h[i]);
    return r.v;
}
__device__ __forceinline__ u16x8 badd8(u16x8 a, u16x8 b) {
    union U { u16x8 v; __hip_bfloat162 h[4]; };
    U ua, ub, r; ua.v = a; ub.v = b;
    #pragma unroll
    for (int i = 0; i < 4; ++i) r.h[i] = __hadd2(ua.h[i], ub.h[i]);
    return r.v;
}

// async global->LDS, 16 bytes per lane (LDS dest = wave-uniform base + lane*16)
__device__ __forceinline__ void gll16(const void* g, void* l) {
    __builtin_amdgcn_global_load_lds(
        (const __attribute__((address_space(1))) unsigned int*)g,
        (__attribute__((address_space(3))) unsigned int*)l, 16, 0, 0);
}

// ================= bf16 MFMA GEMM:  C[M,N] = A[M,K] @ Bt[N,K]^T + bias =================
// 128x128 tile, BK=32, 4 waves (2x2 of 64x64), global_load_lds staging, XOR-swizzled LDS.
// OMODE: 0 = row-major [m][n]; 1 = head-major [b][h][l][d]; 2 = transposed head-major
// [b][h][d][l] (row length LSEQ=200, 8B packed stores). Modes 1/2 require N==2048.
// SCALEC: multiply (acc+bias) by CSCALE (folds softmax scale*log2e into Q projection).
template<bool RELU, int OMODE, bool SCALEC>
__global__ __launch_bounds__(256) void gemm_bt(
    const ushort_t* __restrict__ A, const ushort_t* __restrict__ Bt,
    const float* __restrict__ bias, ushort_t* __restrict__ C,
    int M, int N, int K)
{
    __shared__ ushort_t As[128 * 32];
    __shared__ ushort_t Bs[128 * 32];
    const int t = threadIdx.x;
    const int m0 = blockIdx.y * 128, n0 = blockIdx.x * 128;
    const int wave = t >> 6, lane = t & 63;
    const int l15 = lane & 15, lq = lane >> 4;
    const int wr = wave >> 1, wc = wave & 1;

    f32x4 acc[4][4];
    #pragma unroll
    for (int i = 0; i < 4; ++i)
        #pragma unroll
        for (int j = 0; j < 4; ++j) acc[i][j] = (f32x4){0.f, 0.f, 0.f, 0.f};

    for (int k0 = 0; k0 < K; k0 += 32) {
        __syncthreads();
        #pragma unroll
        for (int i = 0; i < 2; ++i) {      // stage A (2 x 16B per thread)
            int li = i * 256 + t;
            int ml = li >> 2, cp = li & 3;
            int cg = cp ^ ((ml ^ (ml >> 2)) & 3);
            gll16(A + (size_t)(m0 + ml) * K + k0 + cg * 8, &As[li * 8]);
        }
        #pragma unroll
        for (int i = 0; i < 2; ++i) {      // stage B
            int li = i * 256 + t;
            int nl = li >> 2, cp = li & 3;
            int cg = cp ^ ((nl ^ (nl >> 2)) & 3);
            gll16(Bt + (size_t)(n0 + nl) * K + k0 + cg * 8, &Bs[li * 8]);
        }
        __syncthreads();
        bf16x8 af[4], bfr[4];
        #pragma unroll
        for (int i = 0; i < 4; ++i) {
            int r = wr * 64 + i * 16 + l15;
            int pc = lq ^ ((r ^ (r >> 2)) & 3);
            af[i] = *(const bf16x8*)&As[r * 32 + pc * 8];
        }
        #pragma unroll
        for (int j = 0; j < 4; ++j) {
            int r = wc * 64 + j * 16 + l15;
            int pc = lq ^ ((r ^ (r >> 2)) & 3);
            bfr[j] = *(const bf16x8*)&Bs[r * 32 + pc * 8];
        }
        #pragma unroll
        for (int i = 0; i < 4; ++i)
            #pragma unroll
            for (int j = 0; j < 4; ++j)
                acc[i][j] = __builtin_amdgcn_mfma_f32_16x16x32_bf16(af[i], bfr[j], acc[i][j], 0, 0, 0);
    }
    // epilogue: C layout col=lane&15, row=4*quad+e
    if (OMODE == 2) {
        #pragma unroll
        for (int i = 0; i < 4; ++i) {
            int mbase = m0 + wr * 64 + i * 16 + 4 * lq;         // 4-aligned; 200%4==0
            int bb = (int)(((unsigned)mbase * 5243u) >> 20);    // mbase/200
            int ll = mbase - bb * 200;
            #pragma unroll
            for (int j = 0; j < 4; ++j) {
                int n = n0 + wc * 64 + j * 16 + l15;
                float bsv = bias[n];
                ushort4 o4;
                o4.x = f2b(acc[i][j][0] + bsv); o4.y = f2b(acc[i][j][1] + bsv);
                o4.z = f2b(acc[i][j][2] + bsv); o4.w = f2b(acc[i][j][3] + bsv);
                size_t addr = ((size_t)(bb * NH + (n >> 8)) * 256 + (n & 255)) * LSEQ + ll;
                *(ushort4*)&C[addr] = o4;
            }
        }
    } else {
        #pragma unroll
        for (int i = 0; i < 4; ++i) {
            #pragma unroll
            for (int e = 0; e < 4; ++e) {
                int m = m0 + wr * 64 + i * 16 + 4 * lq + e;
                #pragma unroll
                for (int j = 0; j < 4; ++j) {
                    int n = n0 + wc * 64 + j * 16 + l15;
                    float v = acc[i][j][e] + bias[n];
                    if (RELU) v = fmaxf(v, 0.f);
                    if (SCALEC) v *= CSCALE;
                    if (OMODE == 1) {
                        int bb = (int)(((unsigned)m * 5243u) >> 20);
                        int ll = m - bb * 200;
                        size_t addr = ((((size_t)(bb * NH + (n >> 8))) * LSEQ + ll) << 8) + (n & 255);
                        C[addr] = f2b(v);
                    } else {
                        C[(size_t)m * N + n] = f2b(v);
                    }
                }
            }
        }
    }
}

// ================= fused area-attention v18 (v16 + single-barrier dbuf, no reg state) =
// v16 algorithm (raw-V PV via P aggregation, operand-swapped QK^T, in-register P) with
// v17's single-barrier double-buffered schedule, but ZERO registers live across compute:
// per class step: {compute on Ks[cur]/Vs[vcur] -> sched_barrier(0) -> stage next ->
// barrier}. Staging loads are issued after compute and consumed immediately (transient).
// Pooled-K running state lives in LDS: RMW reads own frag from Ks[cur] (same thread
// wrote it last step), bmax with fresh raw row, writes Ks[next]. Tile-boundary raw-K
// staging uses global_load_lds with pre-swizzled source (zero register traffic, async).
// Latency hides via inter-wave drift across the single barrier (staging || MFMA on the
// sibling wave). Barriers 32 -> 16. LDS 128 KB (dbuf) -- still 1 block/CU (reg-bound).
__global__ __launch_bounds__(512, 2) void attn_mfma18(
    const ushort_t* __restrict__ Q, const ushort_t* __restrict__ Khm,
    const ushort_t* __restrict__ Vt, ushort_t* __restrict__ O)  // O may alias Q
{
    const int id = blockIdx.x;
    const int xcd = id & 7, slot_ = id >> 3;    // 1024 blocks: 8 xcd x 128 slots
    const int qt = slot_ & 1;
    const int bh = ((slot_ >> 1) << 3) + xcd;   // both q-blocks of bh share an XCD
    const int b = bh >> 3, h = bh & 7;
    const int q0 = qt * 128;
    const int t = threadIdx.x;
    const int wave = t >> 6, lane = t & 63;
    const int l15 = lane & 15, lq = lane >> 4;

    __shared__ ushort_t Ks[2 * 64 * 256];  // pooled K, dbuf, phys chunk p = logical ^ (m&15)
    __shared__ ushort_t Vs[2 * 256 * 64];  // raw V [d][kpos], dbuf, chunk ^ (d&7)

    const ushort_t* kbh = Khm + (size_t)bh * LSEQ * DH;
    const ushort_t* vtb = Vt + (size_t)bh * DH * LSEQ;   // [d][l]
    const ushort_t* qbh = Q + ((size_t)b * LSEQ) * HD + h * DH;
    const int qrow = q0 + wave * 16 + l15;

    // Q fragments (row=lane&15, k=8*quad+j); pre-scaled by CSCALE in GEMM.
    bf16x8 qf[8];
    if (qrow < LSEQ) {
        const ushort_t* qp = qbh + (size_t)qrow * HD + 8 * lq;
        #pragma unroll
        for (int g = 0; g < 8; ++g) qf[g] = *(const bf16x8*)(qp + 32 * g);
    } else {
        bf16x8 zf = {0,0,0,0,0,0,0,0};
        #pragma unroll
        for (int g = 0; g < 8; ++g) qf[g] = zf;
    }

    f32x4 oacc[16];
    #pragma unroll
    for (int i = 0; i < 16; ++i) oacc[i] = (f32x4){0.f, 0.f, 0.f, 0.f};
    float l4[4];                           // split softmax-denominator accumulators
    #pragma unroll
    for (int e = 0; e < 4; ++e) l4[e] = 0.f;
    float carry[4];                        // Pagg spill into next tile's slots 0..3
    #pragma unroll
    for (int e = 0; e < 4; ++e) carry[e] = 0.f;

    // staging roles for 512 threads
    const int dc = t & 31, mb = t >> 5;      // K: lane->d-chunk, thread->4 m's (mb 0..15)
    const int vd = t >> 1, vh = t & 1;       // V: thread -> d row, half (4 chunks each)

    // async raw-K tile staging: LDS linear dest, pre-swizzled global source
    auto stageK_async = [&](int dstBase, int row0) {
        #pragma unroll
        for (int j = 0; j < 4; ++j) {
            int li = j * 512 + t;          // 0..2047 (16B units)
            int m  = li >> 5;              // row 0..63
            int p  = li & 31;              // physical chunk
            int cg = p ^ (m & 15);         // logical chunk at this physical slot
            gll16(kbh + (size_t)(row0 + m) * DH + cg * 8, &Ks[dstBase + li * 8]);
        }
    };
    auto loadV = [&](u16x8* vc, int s0) {
        const ushort_t* vrow = vtb + (size_t)vd * LSEQ + s0 + vh * 32;
        #pragma unroll
        for (int c2 = 0; c2 < 4; ++c2) vc[c2] = *(const u16x8*)(vrow + c2 * 8);
    };
    auto storeV = [&](int bo, const u16x8* vc) {
        #pragma unroll
        for (int cl = 0; cl < 4; ++cl) {
            const int cg = vh * 4 + cl;                    // natural chunk 0..7
            const int kc = (cg >> 2) * 4 + (cg & 1) * 2;   // sigma chunk (lo half)
            const int par4 = ((cg >> 1) & 1) * 4;
            union VH { u16x8 v; ushort4 hh[2]; } nv;
            nv.v = vc[cl];
            *(ushort4*)&Vs[bo + vd * 64 + ((kc ^ (vd & 7)) * 8) + par4] = nv.hh[0];
            *(ushort4*)&Vs[bo + vd * 64 + (((kc + 1) ^ (vd & 7)) * 8) + par4] = nv.hh[1];
        }
    };

    // shift slot axis down by 1 (T'[slot] = T[slot-1], 0 fill at slot 0)
    auto shift1 = [&](float T[4][4]) {
        float up0 = __shfl(T[0][3], (lane - 16) & 63);
        float up1 = __shfl(T[1][3], (lane - 16) & 63);
        float up2 = __shfl(T[2][3], (lane - 16) & 63);
        float up3 = __shfl(T[3][3], (lane - 16) & 63);
        #pragma unroll
        for (int ms = 0; ms < 4; ++ms) {
            T[ms][3] = T[ms][2]; T[ms][2] = T[ms][1]; T[ms][1] = T[ms][0];
        }
        T[3][0] = (lq > 0) ? up3 : up2;
        T[2][0] = (lq > 0) ? up2 : up1;
        T[1][0] = (lq > 0) ? up1 : up0;
        T[0][0] = (lq > 0) ? up0 : 0.f;
    };

    // PV over the staged V tile (buffer bo) with A-frags from float P[4][4]
    auto pv32 = [&](int bo, const float P[4][4]) {
        unsigned int w[8];
        #pragma unroll
        for (int ms = 0; ms < 4; ++ms) {
            asm("v_cvt_pk_bf16_f32 %0, %1, %2" : "=v"(w[2*ms])   : "v"(P[ms][0]), "v"(P[ms][1]));
            asm("v_cvt_pk_bf16_f32 %0, %1, %2" : "=v"(w[2*ms+1]) : "v"(P[ms][2]), "v"(P[ms][3]));
        }
        union FR { unsigned int u[4]; bf16x8 v; };
        FR f0, f1;
        f0.u[0] = w[0]; f0.u[1] = w[1]; f0.u[2] = w[2]; f0.u[3] = w[3];
        f1.u[0] = w[4]; f1.u[1] = w[5]; f1.u[2] = w[6]; f1.u[3] = w[7];
        const bf16x8 pf0 = f0.v, pf1 = f1.v;
        __builtin_amdgcn_s_setprio(1);
        #pragma unroll
        for (int dt = 0; dt < 16; ++dt) {
            const int d = dt * 16 + l15;
            const int p0 = lq ^ (d & 7);
            const int p1 = (lq + 4) ^ (d & 7);
            oacc[dt] = __builtin_amdgcn_mfma_f32_16x16x32_bf16(
                           pf0, *(const bf16x8*)&Vs[bo + d * 64 + p0 * 8], oacc[dt], 0, 0, 0);
            oacc[dt] = __builtin_amdgcn_mfma_f32_16x16x32_bf16(
                           pf1, *(const bf16x8*)&Vs[bo + d * 64 + p1 * 8], oacc[dt], 0, 0, 0);
        }
        __builtin_amdgcn_s_setprio(0);
    };

    // ---- prologue: raw K(tile0) -> Ks[0] (async), raw V(tile0) -> Vs[0] ----
    {
        stageK_async(0, 0);
        u16x8 vc[4];
        loadV(vc, 0);
        storeV(0, vc);
    }
    __syncthreads();

    // ---- 3 tiles x 5 class steps; ONE barrier per step ----
    int cb = 0;                                  // current Ks buffer index
    for (int ti = 0; ti < 3; ++ti) {
        const int st0 = ti * 64;
        const int vbo = (ti & 1) * 16384;
        // carry-in: prev tile's spill -> this tile's slots 0..3 (lq==0 lanes)
        float Pagg[4][4];
        {
            float pin0 = __shfl(carry[0], (lane + 48) & 63);
            float pin1 = __shfl(carry[1], (lane + 48) & 63);
            float pin2 = __shfl(carry[2], (lane + 48) & 63);
            float pin3 = __shfl(carry[3], (lane + 48) & 63);
            #pragma unroll
            for (int ms = 0; ms < 4; ++ms)
                #pragma unroll
                for (int e = 0; e < 4; ++e) Pagg[ms][e] = 0.f;
            if (lq == 0) {
                Pagg[0][0] = pin0; Pagg[0][1] = pin1; Pagg[0][2] = pin2; Pagg[0][3] = pin3;
            }
            #pragma unroll
            for (int e = 0; e < 4; ++e) carry[e] = 0.f;
        }
        #pragma unroll
        for (int cls = 0; cls < 5; ++cls) {
            const int kbo = cb * 16384, knx = kbo ^ 16384;
            const bool lastS = (cls == 4) && (ti == 2);

            // ---- compute on Ks[kbo] (staged by previous step) ----
            f32x4 sacc[4];
            __builtin_amdgcn_s_setprio(1);
            #pragma unroll
            for (int ms = 0; ms < 4; ++ms) {
                f32x4 s = (f32x4){0.f, 0.f, 0.f, 0.f};
                const int row = ms * 16 + l15;
                #pragma unroll
                for (int g = 0; g < 8; ++g) {
                    const int phys = (lq + 4 * g) ^ l15;
                    s = __builtin_amdgcn_mfma_f32_16x16x32_bf16(
                            *(const bf16x8*)&Ks[kbo + row * 256 + phys * 8], qf[g], s, 0, 0, 0);
                }
                sacc[ms] = s;
            }
            __builtin_amdgcn_s_setprio(0);

            // P_c = exp2(s); accumulate Pagg += sum_{u=0..cls} shift_u(P_c)
            float Pc[4][4];
            #pragma unroll
            for (int ms = 0; ms < 4; ++ms)
                #pragma unroll
                for (int e = 0; e < 4; ++e) {
                    float pe = __builtin_exp2f(sacc[ms][e]);
                    l4[e] += pe;
                    Pc[ms][e] = pe;
                    Pagg[ms][e] += pe;
                }
            if (cls >= 1) {
                float T[4][4];
                #pragma unroll
                for (int ms = 0; ms < 4; ++ms)
                    #pragma unroll
                    for (int e = 0; e < 4; ++e) T[ms][e] = Pc[ms][e];
                #pragma unroll
                for (int u = 1; u <= 4; ++u) {
                    if (u <= cls) {
                        shift1(T);
                        #pragma unroll
                        for (int ms = 0; ms < 4; ++ms)
                            #pragma unroll
                            for (int e = 0; e < 4; ++e) Pagg[ms][e] += T[ms][e];
                    }
                }
            }
            // carry-out: spill to next tile's slot i (meaningful in lq==3 lanes)
            #pragma unroll
            for (int i = 0; i < 4; ++i)
                #pragma unroll
                for (int e = 0; e < 4; ++e)
                    if (cls >= 4 + i - e) carry[i] += Pc[3][e];

            if (cls == 4) pv32(vbo, Pagg);   // one PV over raw V for the whole tile

            // ---- stage next step (transient regs only; pinned after compute) ----
            __builtin_amdgcn_sched_barrier(0);
            if (cls < 4) {
                // pooled-K advance: Ks[knx] = max(Ks[kbo], K[st0+cls+1+m])
                #pragma unroll
                for (int k4 = 0; k4 < 4; ++k4) {
                    const int m = mb + 16 * k4;
                    const int off = m * 256 + ((dc ^ (m & 15)) * 8);
                    u16x8 kf = *(const u16x8*)(kbh + (size_t)(st0 + cls + 1 + m) * DH + dc * 8);
                    *(u16x8*)&Ks[knx + off] = bmax8(*(const u16x8*)&Ks[kbo + off], kf);
                }
            } else if (!lastS) {
                stageK_async(knx, st0 + 64);         // raw K(tile+1), class 0
                u16x8 vc[4];
                loadV(vc, st0 + 64);
                storeV(vbo ^ 16384, vc);
            } else {
                // tail staging: pooled tail K -> Ks[knx], tail V windows -> Vs[16384]
                if (mb < 8) {
                    u16x8 krun = *(const u16x8*)(kbh + (size_t)(192 + mb) * DH + dc * 8);
                    const u16x8 kz = {0,0,0,0,0,0,0,0};
                    #pragma unroll
                    for (int k8 = 0; k8 < 8; ++k8) {
                        const bool vv = (k8 <= 4) && (mb <= 7 - k8);
                        if (k8 > 0 && vv)
                            krun = bmax8(krun, *(const u16x8*)(kbh + (size_t)(192 + mb + k8) * DH + dc * 8));
                        int slot = k8 * 8 + mb;
                        *(u16x8*)&Ks[knx + slot * 256 + ((dc ^ (slot & 15)) * 8)] = vv ? krun : kz;
                    }
                }
                {
                    u16x8 v0 = *(const u16x8*)(vtb + (size_t)vd * LSEQ + 192);
                    float f[8];
                    #pragma unroll
                    for (int e = 0; e < 8; ++e) f[e] = b2f(v0[e]);
                    #pragma unroll
                    for (int cl = 0; cl < 4; ++cl) {
                        const int c = vh * 4 + cl;     // chunk c == class c (slots 8c..8c+7)
                        union VH { u16x8 v; ushort4 hh[2]; } ov;
                        #pragma unroll
                        for (int j = 0; j < 8; ++j) ov.v[j] = 0;
                        if (c <= 4) {
                            #pragma unroll
                            for (int j = 0; j < 8; ++j) {
                                if (j <= 7 - c) {
                                    float acc = 0.f;
                                    #pragma unroll
                                    for (int u = 0; u <= 4; ++u)
                                        if (u <= c) acc += f[j + u];
                                    ov.v[j] = f2b(acc);
                                }
                            }
                        } else if (c == 5) {
                            #pragma unroll
                            for (int j = 0; j < 4; ++j) ov.v[j] = v0[j];   // raw V[192+j]
                        }
                        const int kc = (c >> 2) * 4 + (c & 1) * 2;
                        const int par4 = ((c >> 1) & 1) * 4;
                        *(ushort4*)&Vs[16384 + vd * 64 + ((kc ^ (vd & 7)) * 8) + par4] = ov.hh[0];
                        *(ushort4*)&Vs[16384 + vd * 64 + (((kc + 1) ^ (vd & 7)) * 8) + par4] = ov.hh[1];
                    }
                }
            }
            __syncthreads();
            cb ^= 1;
        }
    }

    // ---- tail compute: QK on Ks[cb], softmax + carry injection, PV on Vs[1] ----
    {
        const int kbo = cb * 16384;
        f32x4 sacc[4];
        __builtin_amdgcn_s_setprio(1);
        #pragma unroll
        for (int ms = 0; ms < 4; ++ms) {
            f32x4 s = (f32x4){0.f, 0.f, 0.f, 0.f};
            const int row = ms * 16 + l15;
            #pragma unroll
            for (int g = 0; g < 8; ++g) {
                const int phys = (lq + 4 * g) ^ l15;
                s = __builtin_amdgcn_mfma_f32_16x16x32_bf16(
                        *(const bf16x8*)&Ks[kbo + row * 256 + phys * 8], qf[g], s, 0, 0, 0);
            }
            sacc[ms] = s;
        }
        __builtin_amdgcn_s_setprio(0);

        float pullc[4];
        #pragma unroll
        for (int e = 0; e < 4; ++e) pullc[e] = __shfl(carry[e], (lane + 16) & 63);
        float Pt[4][4];
        #pragma unroll
        for (int ms = 0; ms < 4; ++ms)
            #pragma unroll
            for (int e = 0; e < 4; ++e) {
                const int slot = ms * 16 + 4 * lq + e;
                const bool inval = ((slot & 7) > 7 - (slot >> 3)) || ((slot >> 3) > 4);
                float pe = __builtin_exp2f(inval ? -1e30f : sacc[ms][e]);
                l4[e] += pe;           // carry slots are invalid -> pe==0 here
                float pfrag = pe;
                if (ms == 2 && lq == 2) pfrag = pullc[e];
                Pt[ms][e] = pfrag;
            }
        pv32(16384, Pt);
    }

    // epilogue: l for q-row l15 -> reduce over the 4 lq groups, invert, redistribute
    float l_part = (l4[0] + l4[1]) + (l4[2] + l4[3]);
    l_part += __shfl_xor(l_part, 16);
    l_part += __shfl_xor(l_part, 32);
    const float inv = 1.f / l_part;

    ushort_t* ob = O + ((size_t)b * LSEQ) * HD + h * DH;
    #pragma unroll
    for (int e = 0; e < 4; ++e) {
        const int q = q0 + wave * 16 + 4 * lq + e;
        const float linv = __shfl(inv, 4 * lq + e);
        if (q < LSEQ) {
            #pragma unroll
            for (int dt = 0; dt < 16; ++dt)
                ob[(size_t)q * HD + dt * 16 + l15] = f2b(oacc[dt][e] * linv);
        }
    }
}

// ================= residual + LayerNorm: Out = LN(bf16 X + R) =================
template<typename TR, typename TO>
__global__ __launch_bounds__(256) void residual_ln(
    const ushort_t* __restrict__ X, const TR* __restrict__ R, TO* __restrict__ Out)
{
    const int row = blockIdx.x;
    const int t = threadIdx.x;
    const size_t base = (size_t)row * HID;
    float v = b2f(X[base + t]) + to_f32(R[base + t]);
    float s = v, q = v * v;
    #pragma unroll
    for (int o = 32; o > 0; o >>= 1) {
        s += __shfl_xor(s, o, 64);
        q += __shfl_xor(q, o, 64);
    }
    __shared__ float ss[4], sq[4];
    const int wave = t >> 6, lane = t & 63;
    if (lane == 0) { ss[wave] = s; sq[wave] = q; }
    __syncthreads();
    s = ss[0] + ss[1] + ss[2] + ss[3];
    q = sq[0] + sq[1] + sq[2] + sq[3];
    float mean = s * (1.f / HID);
    float var  = q * (1.f / HID) - mean * mean;
    store_val(&Out[base + t], (v - mean) * rsqrtf(var + EPS));
}

// ================= converts =================
__global__ __launch_bounds__(256) void cvt_f32_bf16(const float* __restrict__ in,
                                                    ushort_t* __restrict__ out) {
    const int i = (blockIdx.x * 256 + threadIdx.x) * 4;
    float4 v = *(const float4*)(in + i);
    ushort4 o;
    o.x = f2b(v.x); o.y = f2b(v.y); o.z = f2b(v.z); o.w = f2b(v.w);
    *(ushort4*)(out + i) = o;
}

// W[K,N] f32 -> Wt[N,K] bf16
__global__ __launch_bounds__(256) void wtrans(const float* __restrict__ W,
                                              ushort_t* __restrict__ Wt, int K, int N) {
    __shared__ float tile[32][33];
    const int t = threadIdx.x;
    const int tx = t & 31, ty = t >> 5;
    const int n0 = blockIdx.x * 32, k0 = blockIdx.y * 32;
    #pragma unroll
    for (int s = 0; s < 4; ++s)
        tile[ty + 8 * s][tx] = W[(size_t)(k0 + ty + 8 * s) * N + n0 + tx];
    __syncthreads();
    #pragma unroll
    for (int s = 0; s < 4; ++s)
        Wt[(size_t)(n0 + ty + 8 * s) * K + k0 + tx] = f2b(tile[tx][ty + 8 * s]);
}

// ================= launch =================
extern "C" void kernel_launch(void* const* d_in, const int* in_sizes, int n_in,
                              void* d_out, int out_size, void* d_ws, size_t ws_size,
                              hipStream_t stream) {
    const float* hidden = (const float*)d_in[1];
    const float* Wq = (const float*)d_in[2];  const float* bq = (const float*)d_in[3];
    const float* Wk = (const float*)d_in[4];  const float* bk = (const float*)d_in[5];
    const float* Wv = (const float*)d_in[6];  const float* bv = (const float*)d_in[7];
    const float* Wo = (const float*)d_in[8];  const float* bo = (const float*)d_in[9];
    const float* W1 = (const float*)d_in[10]; const float* b1 = (const float*)d_in[11];
    const float* W2 = (const float*)d_in[12]; const float* b2 = (const float*)d_in[13];
    float* out = (float*)d_out;

    constexpr size_t SZ_BF   = (size_t)MROWS * HD * 2;      // 52,428,800
    constexpr size_t SZ_HBF  = (size_t)MROWS * HID * 2;     // 6,553,600
    constexpr size_t SZ_WQKV = (size_t)HID * HD * 2;        // 1,048,576
    constexpr size_t SZ_W12  = (size_t)HID * 4 * HID * 2;   // 524,288
    char* ws = (char*)d_ws;
    size_t off = 0;
    ushort_t* kb   = (ushort_t*)(ws + off); off += SZ_BF;   // K head-major [b,h][l][d]
    ushort_t* vt   = (ushort_t*)(ws + off); off += SZ_BF;   // V transposed  [b,h][d][l]
    ushort_t* qo   = (ushort_t*)(ws + off); off += SZ_BF;   // q / attn-out / ffn1
    ushort_t* hb   = (ushort_t*)(ws + off); off += SZ_HBF;  // hidden bf16
    ushort_t* at1  = (ushort_t*)(ws + off); off += SZ_HBF;
    ushort_t* at2  = (ushort_t*)(ws + off); off += SZ_HBF;
    ushort_t* proj = (ushort_t*)(ws + off); off += SZ_HBF;
    ushort_t* WtQ  = (ushort_t*)(ws + off); off += SZ_WQKV;
    ushort_t* WtK  = (ushort_t*)(ws + off); off += SZ_WQKV;
    ushort_t* WtV  = (ushort_t*)(ws + off); off += SZ_WQKV;
    ushort_t* WtO  = (ushort_t*)(ws + off); off += SZ_WQKV;
    ushort_t* Wt1  = (ushort_t*)(ws + off); off += SZ_W12;
    ushort_t* Wt2  = (ushort_t*)(ws + off); off += SZ_W12;
    if (ws_size < off) return;  // total == 188,743,680 B (same as passing R3/R5-R11)
    ushort_t* ffn1 = qo;        // alias: qo free after out-proj2

    dim3 blk(256);
    cvt_f32_bf16<<<MROWS * HID / 1024, blk, 0, stream>>>(hidden, hb);
    wtrans<<<dim3(HD / 32, HID / 32), blk, 0, stream>>>(Wq, WtQ, HID, HD);
    wtrans<<<dim3(HD / 32, HID / 32), blk, 0, stream>>>(Wk, WtK, HID, HD);
    wtrans<<<dim3(HD / 32, HID / 32), blk, 0, stream>>>(Wv, WtV, HID, HD);
    wtrans<<<dim3(HID / 32, HD / 32), blk, 0, stream>>>(Wo, WtO, HD, HID);
    wtrans<<<dim3(4 * HID / 32, HID / 32), blk, 0, stream>>>(W1, Wt1, HID, 4 * HID);
    wtrans<<<dim3(HID / 32, 4 * HID / 32), blk, 0, stream>>>(W2, Wt2, 4 * HID, HID);

    const dim3 gProj(HD / 128, MROWS / 128);
    const dim3 gOut(HID / 128, MROWS / 128);
    const dim3 gF1(4 * HID / 128, MROWS / 128);

    // K head-major; V transposed head-major (shared by both MHAs)
    gemm_bt<false, 1, false><<<gProj, blk, 0, stream>>>(hb, WtK, bk, kb, MROWS, HD, HID);
    gemm_bt<false, 2, false><<<gProj, blk, 0, stream>>>(hb, WtV, bv, vt, MROWS, HD, HID);

    // MHA1 (Q pre-scaled by CSCALE)
    gemm_bt<false, 0, true><<<gProj, blk, 0, stream>>>(hb, WtQ, bq, qo, MROWS, HD, HID);
    attn_mfma18<<<2 * BATCH * NH, 512, 0, stream>>>(qo, kb, vt, qo);
    gemm_bt<false, 0, false><<<gOut, blk, 0, stream>>>(qo, WtO, bo, proj, MROWS, HID, HD);
    residual_ln<float, ushort_t><<<MROWS, blk, 0, stream>>>(proj, hidden, at1);

    // MHA2 (q from attn1; pooled K/V rebuilt from same kb/vt)
    gemm_bt<false, 0, true><<<gProj, blk, 0, stream>>>(at1, WtQ, bq, qo, MROWS, HD, HID);
    attn_mfma18<<<2 * BATCH * NH, 512, 0, stream>>>(qo, kb, vt, qo);
    gemm_bt<false, 0, false><<<gOut, blk, 0, stream>>>(qo, WtO, bo, proj, MROWS, HID, HD);
    residual_ln<ushort_t, ushort_t><<<MROWS, blk, 0, stream>>>(proj, at1, at2);

    // FFN
    gemm_bt<true, 0, false><<<gF1, blk, 0, stream>>>(at2, Wt1, b1, ffn1, MROWS, 4 * HID, HID);
    gemm_bt<false, 0, false><<<gOut, blk, 0, stream>>>(ffn1, Wt2, b2, proj, MROWS, HID, 4 * HID);
    residual_ln<ushort_t, float><<<MROWS, blk, 0, stream>>>(proj, at2, out);
}

// Round 9
// 1100.409 us; speedup vs baseline: 1.0601x; 1.0601x over previous
//
#include <hip/hip_runtime.h>
#include <hip/hip_bf16.h>
#include <cstdint>
#include <cstddef>

// Problem constants
#define BATCH 64
#define LSEQ 200
#define HID 256
#define NH 8
#define DH 256            // per-head dim = HID
#define HD (NH*DH)        // 2048
#define MROWS (BATCH*LSEQ)   // 12800
#define EPS 1e-5f
#define CSCALE 0.09014195f   // (1/sqrt(256)) * log2(e), folded into Q projection

typedef unsigned short ushort_t;
typedef __attribute__((ext_vector_type(8))) short bf16x8;         // MFMA A/B frag (4 VGPR)
typedef __attribute__((ext_vector_type(8))) unsigned short u16x8; // 16B of bf16
typedef __attribute__((ext_vector_type(4))) float f32x4;          // MFMA C/D frag

__device__ __forceinline__ float b2f(ushort_t u) {
    union { unsigned int i; float f; } c; c.i = ((unsigned int)u) << 16; return c.f;
}
__device__ __forceinline__ ushort_t f2b(float f) {
    __hip_bfloat16 h = __float2bfloat16(f);
    union { __hip_bfloat16 h; ushort_t u; } c; c.h = h; return c.u;
}
__device__ __forceinline__ float to_f32(float x) { return x; }
__device__ __forceinline__ float to_f32(ushort_t x) { return b2f(x); }
__device__ __forceinline__ void store_val(float* p, float v) { *p = v; }
__device__ __forceinline__ void store_val(ushort_t* p, float v) { *p = f2b(v); }

// packed bf16 max / add on 8 elements
__device__ __forceinline__ u16x8 bmax8(u16x8 a, u16x8 b) {
    union U { u16x8 v; __hip_bfloat162 h[4]; };
    U ua, ub, r; ua.v = a; ub.v = b;
    #pragma unroll
    for (int i = 0; i < 4; ++i) r.h[i] = __hmax2(ua.h[i], ub.h[i]);
    return r.v;
}
__device__ __forceinline__ u16x8 badd8(u16x8 a, u16x8 b) {
    union U { u16x8 v; __hip_bfloat162 h[4]; };
    U ua, ub, r; ua.v = a; ub.v = b;
    #pragma unroll
    for (int i = 0; i < 4; ++i) r.h[i] = __hadd2(ua.h[i], ub.h[i]);
    return r.v;
}

// async global->LDS, 16 bytes per lane (LDS dest = wave-uniform base + lane*16)
__device__ __forceinline__ void gll16(const void* g, void* l) {
    __builtin_amdgcn_global_load_lds(
        (const __attribute__((address_space(1))) unsigned int*)g,
        (__attribute__((address_space(3))) unsigned int*)l, 16, 0, 0);
}

// ================= bf16 MFMA GEMM:  C[M,N] = A[M,K] @ Bt[N,K]^T + bias =================
// 128x128 tile, BK=32, 4 waves (2x2 of 64x64), global_load_lds staging, XOR-swizzled LDS.
// OMODE: 0 = row-major [m][n]; 1 = head-major [b][h][l][d]; 2 = transposed head-major
// [b][h][d][l] (row length LSEQ=200, 8B packed stores). Modes 1/2 require N==2048.
// SCALEC: multiply (acc+bias) by CSCALE (folds softmax scale*log2e into Q projection).
template<bool RELU, int OMODE, bool SCALEC>
__global__ __launch_bounds__(256) void gemm_bt(
    const ushort_t* __restrict__ A, const ushort_t* __restrict__ Bt,
    const float* __restrict__ bias, ushort_t* __restrict__ C,
    int M, int N, int K)
{
    __shared__ ushort_t As[128 * 32];
    __shared__ ushort_t Bs[128 * 32];
    const int t = threadIdx.x;
    const int m0 = blockIdx.y * 128, n0 = blockIdx.x * 128;
    const int wave = t >> 6, lane = t & 63;
    const int l15 = lane & 15, lq = lane >> 4;
    const int wr = wave >> 1, wc = wave & 1;

    f32x4 acc[4][4];
    #pragma unroll
    for (int i = 0; i < 4; ++i)
        #pragma unroll
        for (int j = 0; j < 4; ++j) acc[i][j] = (f32x4){0.f, 0.f, 0.f, 0.f};

    for (int k0 = 0; k0 < K; k0 += 32) {
        __syncthreads();
        #pragma unroll
        for (int i = 0; i < 2; ++i) {      // stage A (2 x 16B per thread)
            int li = i * 256 + t;
            int ml = li >> 2, cp = li & 3;
            int cg = cp ^ ((ml ^ (ml >> 2)) & 3);
            gll16(A + (size_t)(m0 + ml) * K + k0 + cg * 8, &As[li * 8]);
        }
        #pragma unroll
        for (int i = 0; i < 2; ++i) {      // stage B
            int li = i * 256 + t;
            int nl = li >> 2, cp = li & 3;
            int cg = cp ^ ((nl ^ (nl >> 2)) & 3);
            gll16(Bt + (size_t)(n0 + nl) * K + k0 + cg * 8, &Bs[li * 8]);
        }
        __syncthreads();
        bf16x8 af[4], bfr[4];
        #pragma unroll
        for (int i = 0; i < 4; ++i) {
            int r = wr * 64 + i * 16 + l15;
            int pc = lq ^ ((r ^ (r >> 2)) & 3);
            af[i] = *(const bf16x8*)&As[r * 32 + pc * 8];
        }
        #pragma unroll
        for (int j = 0; j < 4; ++j) {
            int r = wc * 64 + j * 16 + l15;
            int pc = lq ^ ((r ^ (r >> 2)) & 3);
            bfr[j] = *(const bf16x8*)&Bs[r * 32 + pc * 8];
        }
        #pragma unroll
        for (int i = 0; i < 4; ++i)
            #pragma unroll
            for (int j = 0; j < 4; ++j)
                acc[i][j] = __builtin_amdgcn_mfma_f32_16x16x32_bf16(af[i], bfr[j], acc[i][j], 0, 0, 0);
    }
    // epilogue: C layout col=lane&15, row=4*quad+e
    if (OMODE == 2) {
        #pragma unroll
        for (int i = 0; i < 4; ++i) {
            int mbase = m0 + wr * 64 + i * 16 + 4 * lq;         // 4-aligned; 200%4==0
            int bb = (int)(((unsigned)mbase * 5243u) >> 20);    // mbase/200
            int ll = mbase - bb * 200;
            #pragma unroll
            for (int j = 0; j < 4; ++j) {
                int n = n0 + wc * 64 + j * 16 + l15;
                float bsv = bias[n];
                ushort4 o4;
                o4.x = f2b(acc[i][j][0] + bsv); o4.y = f2b(acc[i][j][1] + bsv);
                o4.z = f2b(acc[i][j][2] + bsv); o4.w = f2b(acc[i][j][3] + bsv);
                size_t addr = ((size_t)(bb * NH + (n >> 8)) * 256 + (n & 255)) * LSEQ + ll;
                *(ushort4*)&C[addr] = o4;
            }
        }
    } else {
        #pragma unroll
        for (int i = 0; i < 4; ++i) {
            #pragma unroll
            for (int e = 0; e < 4; ++e) {
                int m = m0 + wr * 64 + i * 16 + 4 * lq + e;
                #pragma unroll
                for (int j = 0; j < 4; ++j) {
                    int n = n0 + wc * 64 + j * 16 + l15;
                    float v = acc[i][j][e] + bias[n];
                    if (RELU) v = fmaxf(v, 0.f);
                    if (SCALEC) v *= CSCALE;
                    if (OMODE == 1) {
                        int bb = (int)(((unsigned)m * 5243u) >> 20);
                        int ll = m - bb * 200;
                        size_t addr = ((((size_t)(bb * NH + (n >> 8))) * LSEQ + ll) << 8) + (n & 255);
                        C[addr] = f2b(v);
                    } else {
                        C[(size_t)m * N + n] = f2b(v);
                    }
                }
            }
        }
    }
}

// ================= fused area-attention v19 (v16 in 4-wave blocks, 2 blk/CU drift) ===
// Identical per-thread algorithm to v16 (raw-V PV via P aggregation, operand-swapped
// QK^T, in-register P pack, sigma-permuted V, 2-barrier class steps) but organized as
// 256-thread / 4-wave blocks, 2048-block grid (4 q-blocks of 64 rows per bh). LDS
// 64 KB/block -> at ~190 unified regs (2 waves/SIMD) a CU hosts TWO independent blocks
// whose barriers drift: one block's staging overlaps the other's MFMA (register-free
// pipelining -- every register-based variant v14/v15/v17/v18 spilled). Staging work
// per thread doubles (8 K-rows, full V d-row); that VALU fills the former 35% idle.
__global__ __launch_bounds__(256, 2) void attn_mfma19(
    const ushort_t* __restrict__ Q, const ushort_t* __restrict__ Khm,
    const ushort_t* __restrict__ Vt, ushort_t* __restrict__ O)  // O may alias Q
{
    const int id = blockIdx.x;
    const int xcd = id & 7, slot_ = id >> 3;    // 2048 blocks: 8 xcd x 256 slots
    const int qt = slot_ & 3;
    const int bh = ((slot_ >> 2) << 3) + xcd;   // all 4 q-blocks of bh share an XCD
    const int b = bh >> 3, h = bh & 7;
    const int q0 = qt * 64;
    const int t = threadIdx.x;
    const int wave = t >> 6, lane = t & 63;
    const int l15 = lane & 15, lq = lane >> 4;

    __shared__ ushort_t Ks[64 * 256];      // pooled K [m][d], chunk ^ (m&15), 32 KB
    __shared__ ushort_t Vs[256 * 64];      // V [d][kpos=sigma^-1(m)], chunk ^ (d&7), 32 KB

    const ushort_t* kbh = Khm + (size_t)bh * LSEQ * DH;
    const ushort_t* vtb = Vt + (size_t)bh * DH * LSEQ;   // [d][l]
    const ushort_t* qbh = Q + ((size_t)b * LSEQ) * HD + h * DH;
    const int qrow = q0 + wave * 16 + l15;   // q0 in {0,64,128,192}

    // Q fragments (row=lane&15, k=8*quad+j); pre-scaled by CSCALE in GEMM.
    bf16x8 qf[8];
    if (qrow < LSEQ) {
        const ushort_t* qp = qbh + (size_t)qrow * HD + 8 * lq;
        #pragma unroll
        for (int g = 0; g < 8; ++g) qf[g] = *(const bf16x8*)(qp + 32 * g);
    } else {
        bf16x8 zf = {0,0,0,0,0,0,0,0};
        #pragma unroll
        for (int g = 0; g < 8; ++g) qf[g] = zf;
    }

    f32x4 oacc[16];
    #pragma unroll
    for (int i = 0; i < 16; ++i) oacc[i] = (f32x4){0.f, 0.f, 0.f, 0.f};
    float l_part = 0.f;
    float carry[4];                        // Pagg spill into next tile's slots 0..3
    #pragma unroll
    for (int e = 0; e < 4; ++e) carry[e] = 0.f;

    // staging roles for 256 threads
    const int dc = t & 31, mb = t >> 5;      // K: lane->d-chunk, thread->8 m's (mb 0..7)
    const int vd = t;                        // V: thread -> full d row (8 chunks)

    // shift slot axis down by 1 (T'[slot] = T[slot-1], 0 fill at slot 0)
    auto shift1 = [&](float T[4][4]) {
        float up0 = __shfl(T[0][3], (lane - 16) & 63);
        float up1 = __shfl(T[1][3], (lane - 16) & 63);
        float up2 = __shfl(T[2][3], (lane - 16) & 63);
        float up3 = __shfl(T[3][3], (lane - 16) & 63);
        #pragma unroll
        for (int ms = 0; ms < 4; ++ms) {
            T[ms][3] = T[ms][2]; T[ms][2] = T[ms][1]; T[ms][1] = T[ms][0];
        }
        T[3][0] = (lq > 0) ? up3 : up2;
        T[2][0] = (lq > 0) ? up2 : up1;
        T[1][0] = (lq > 0) ? up1 : up0;
        T[0][0] = (lq > 0) ? up0 : 0.f;
    };

    // PV over the staged V tile with A-frags from float P[4][4]
    auto pv32 = [&](const float P[4][4]) {
        unsigned int w[8];
        #pragma unroll
        for (int ms = 0; ms < 4; ++ms) {
            asm("v_cvt_pk_bf16_f32 %0, %1, %2" : "=v"(w[2*ms])   : "v"(P[ms][0]), "v"(P[ms][1]));
            asm("v_cvt_pk_bf16_f32 %0, %1, %2" : "=v"(w[2*ms+1]) : "v"(P[ms][2]), "v"(P[ms][3]));
        }
        union FR { unsigned int u[4]; bf16x8 v; };
        FR f0, f1;
        f0.u[0] = w[0]; f0.u[1] = w[1]; f0.u[2] = w[2]; f0.u[3] = w[3];
        f1.u[0] = w[4]; f1.u[1] = w[5]; f1.u[2] = w[6]; f1.u[3] = w[7];
        const bf16x8 pf0 = f0.v, pf1 = f1.v;
        __builtin_amdgcn_s_setprio(1);
        #pragma unroll
        for (int dt = 0; dt < 16; ++dt) {
            const int d = dt * 16 + l15;
            const int p0 = lq ^ (d & 7);
            const int p1 = (lq + 4) ^ (d & 7);
            oacc[dt] = __builtin_amdgcn_mfma_f32_16x16x32_bf16(
                           pf0, *(const bf16x8*)&Vs[d * 64 + p0 * 8], oacc[dt], 0, 0, 0);
            oacc[dt] = __builtin_amdgcn_mfma_f32_16x16x32_bf16(
                           pf1, *(const bf16x8*)&Vs[d * 64 + p1 * 8], oacc[dt], 0, 0, 0);
        }
        __builtin_amdgcn_s_setprio(0);
    };

    // V chunk store (sigma-permuted split halves)
    auto storeVchunk = [&](int cg, u16x8 val) {
        const int kc = (cg >> 2) * 4 + (cg & 1) * 2;
        const int par4 = ((cg >> 1) & 1) * 4;
        union VH { u16x8 v; ushort4 hh[2]; } nv;
        nv.v = val;
        *(ushort4*)&Vs[vd * 64 + ((kc ^ (vd & 7)) * 8) + par4] = nv.hh[0];
        *(ushort4*)&Vs[vd * 64 + (((kc + 1) ^ (vd & 7)) * 8) + par4] = nv.hh[1];
    };

    // ---- 3 full tiles x 5 QK classes + 1 PV each ----
    for (int ti = 0; ti < 3; ++ti) {
        const int st0 = ti * 64;
        // carry-in: prev tile's spill -> this tile's slots 0..3 (lq==0 lanes)
        float Pagg[4][4];
        {
            float pin0 = __shfl(carry[0], (lane + 48) & 63);
            float pin1 = __shfl(carry[1], (lane + 48) & 63);
            float pin2 = __shfl(carry[2], (lane + 48) & 63);
            float pin3 = __shfl(carry[3], (lane + 48) & 63);
            #pragma unroll
            for (int ms = 0; ms < 4; ++ms)
                #pragma unroll
                for (int e = 0; e < 4; ++e) Pagg[ms][e] = 0.f;
            if (lq == 0) {
                Pagg[0][0] = pin0; Pagg[0][1] = pin1; Pagg[0][2] = pin2; Pagg[0][3] = pin3;
            }
            #pragma unroll
            for (int e = 0; e < 4; ++e) carry[e] = 0.f;
        }
        #pragma unroll
        for (int cls = 0; cls < 5; ++cls) {
            // prefetch first 4 K rows (+cls); first 4 raw V chunks at cls==0
            u16x8 kf[4];
            #pragma unroll
            for (int k8 = 0; k8 < 4; ++k8)
                kf[k8] = *(const u16x8*)(kbh + (size_t)(st0 + mb + 8 * k8 + cls) * DH + dc * 8);
            u16x8 vc[4];
            if (cls == 0) {
                const ushort_t* vrow = vtb + (size_t)vd * LSEQ + st0;
                #pragma unroll
                for (int c2 = 0; c2 < 4; ++c2) vc[c2] = *(const u16x8*)(vrow + c2 * 8);
            }
            __syncthreads();   // previous step's frag reads done

            // K pooled: running max in Ks (in-place RMW), 8 m's per thread (4+4)
            #pragma unroll
            for (int k8 = 0; k8 < 4; ++k8) {
                int m = mb + 8 * k8;
                ushort_t* kp = &Ks[m * 256 + ((dc ^ (m & 15)) * 8)];
                *(u16x8*)kp = (cls == 0) ? kf[k8] : bmax8(*(const u16x8*)kp, kf[k8]);
            }
            #pragma unroll
            for (int k8 = 4; k8 < 8; ++k8) {
                u16x8 kv = *(const u16x8*)(kbh + (size_t)(st0 + mb + 8 * k8 + cls) * DH + dc * 8);
                int m = mb + 8 * k8;
                ushort_t* kp = &Ks[m * 256 + ((dc ^ (m & 15)) * 8)];
                *(u16x8*)kp = (cls == 0) ? kv : bmax8(*(const u16x8*)kp, kv);
            }
            // raw V staged once per tile: chunks 0..3 from prefetch, 4..7 direct
            if (cls == 0) {
                #pragma unroll
                for (int cg = 0; cg < 4; ++cg) storeVchunk(cg, vc[cg]);
                const ushort_t* vrow = vtb + (size_t)vd * LSEQ + st0;
                #pragma unroll
                for (int cg = 4; cg < 8; ++cg)
                    storeVchunk(cg, *(const u16x8*)(vrow + cg * 8));
            }
            __syncthreads();

            // QK^T for this class (swapped operands): sacc[ms][e] = S^T[slot][q=l15]
            f32x4 sacc[4];
            __builtin_amdgcn_s_setprio(1);
            #pragma unroll
            for (int ms = 0; ms < 4; ++ms) {
                f32x4 s = (f32x4){0.f, 0.f, 0.f, 0.f};
                const int row = ms * 16 + l15;
                #pragma unroll
                for (int g = 0; g < 8; ++g) {
                    const int phys = (lq + 4 * g) ^ l15;
                    s = __builtin_amdgcn_mfma_f32_16x16x32_bf16(
                            *(const bf16x8*)&Ks[row * 256 + phys * 8], qf[g], s, 0, 0, 0);
                }
                sacc[ms] = s;
            }
            __builtin_amdgcn_s_setprio(0);

            // P_c = exp2(s); accumulate Pagg += sum_{u=0..cls} shift_u(P_c)
            float Pc[4][4];
            #pragma unroll
            for (int ms = 0; ms < 4; ++ms)
                #pragma unroll
                for (int e = 0; e < 4; ++e) {
                    float pe = __builtin_exp2f(sacc[ms][e]);
                    l_part += pe;
                    Pc[ms][e] = pe;
                    Pagg[ms][e] += pe;
                }
            if (cls >= 1) {
                float T[4][4];
                #pragma unroll
                for (int ms = 0; ms < 4; ++ms)
                    #pragma unroll
                    for (int e = 0; e < 4; ++e) T[ms][e] = Pc[ms][e];
                #pragma unroll
                for (int u = 1; u <= 4; ++u) {
                    if (u <= cls) {
                        shift1(T);
                        #pragma unroll
                        for (int ms = 0; ms < 4; ++ms)
                            #pragma unroll
                            for (int e = 0; e < 4; ++e) Pagg[ms][e] += T[ms][e];
                    }
                }
            }
            // carry-out: spill to next tile's slot i (meaningful in lq==3 lanes)
            #pragma unroll
            for (int i = 0; i < 4; ++i)
                #pragma unroll
                for (int e = 0; e < 4; ++e)
                    if (cls >= 4 + i - e) carry[i] += Pc[3][e];

            if (cls == 4) pv32(Pagg);   // one PV over raw V for the whole tile
        }
    }

    // ---- tail step (pooled-V tail) + tile-2 carry injection ----
    {
        __syncthreads();   // previous step's frag reads (incl. PV) done
        // K: thread covers slots k8*8+mb (cls=k8, off=mb), incremental max
        {
            u16x8 krun = *(const u16x8*)(kbh + (size_t)(192 + mb) * DH + dc * 8);
            const u16x8 kz = {0,0,0,0,0,0,0,0};
            #pragma unroll
            for (int k8 = 0; k8 < 8; ++k8) {
                const bool vv = (k8 <= 4) && (mb <= 7 - k8);
                if (k8 > 0 && vv)
                    krun = bmax8(krun, *(const u16x8*)(kbh + (size_t)(192 + mb + k8) * DH + dc * 8));
                int slot = k8 * 8 + mb;
                *(u16x8*)&Ks[slot * 256 + ((dc ^ (slot & 15)) * 8)] = vv ? krun : kz;
            }
        }
        // V: thread owns full d-row vd; window sums for c<=4, chunk 5 = raw V[192..195]
        {
            u16x8 v0 = *(const u16x8*)(vtb + (size_t)vd * LSEQ + 192);
            float f[8];
            #pragma unroll
            for (int e = 0; e < 8; ++e) f[e] = b2f(v0[e]);
            #pragma unroll
            for (int c = 0; c < 8; ++c) {
                u16x8 ov;
                #pragma unroll
                for (int j = 0; j < 8; ++j) ov[j] = 0;
                if (c <= 4) {
                    // direct window sums for class c: ov[j] = sum f[j..j+c], j <= 7-c
                    #pragma unroll
                    for (int j = 0; j < 8; ++j) {
                        if (j <= 7 - c) {
                            float acc = 0.f;
                            #pragma unroll
                            for (int u = 0; u <= 4; ++u)
                                if (u <= c) acc += f[j + u];
                            ov[j] = f2b(acc);
                        }
                    }
                } else if (c == 5) {
                    #pragma unroll
                    for (int j = 0; j < 4; ++j) ov[j] = v0[j];   // raw V[192+j]
                }
                storeVchunk(c, ov);
            }
        }
        __syncthreads();

        // QK^T tail
        f32x4 sacc[4];
        __builtin_amdgcn_s_setprio(1);
        #pragma unroll
        for (int ms = 0; ms < 4; ++ms) {
            f32x4 s = (f32x4){0.f, 0.f, 0.f, 0.f};
            const int row = ms * 16 + l15;
            #pragma unroll
            for (int g = 0; g < 8; ++g) {
                const int phys = (lq + 4 * g) ^ l15;
                s = __builtin_amdgcn_mfma_f32_16x16x32_bf16(
                        *(const bf16x8*)&Ks[row * 256 + phys * 8], qf[g], s, 0, 0, 0);
            }
            sacc[ms] = s;
        }
        __builtin_amdgcn_s_setprio(0);

        // softmax + carry injection into slots 40..43 (ms==2, lq==2)
        float pullc[4];
        #pragma unroll
        for (int e = 0; e < 4; ++e) pullc[e] = __shfl(carry[e], (lane + 16) & 63);
        float Pt[4][4];
        #pragma unroll
        for (int ms = 0; ms < 4; ++ms)
            #pragma unroll
            for (int e = 0; e < 4; ++e) {
                const int slot = ms * 16 + 4 * lq + e;
                const bool inval = ((slot & 7) > 7 - (slot >> 3)) || ((slot >> 3) > 4);
                float pe = __builtin_exp2f(inval ? -1e30f : sacc[ms][e]);
                l_part += pe;          // carry slots are invalid -> pe==0 here
                float pfrag = pe;
                if (ms == 2 && lq == 2) pfrag = pullc[e];
                Pt[ms][e] = pfrag;
            }
        pv32(Pt);
    }

    // epilogue: reduce l over the 4 lq groups (2 shuffles), invert, redistribute
    l_part += __shfl_xor(l_part, 16);
    l_part += __shfl_xor(l_part, 32);
    const float inv = 1.f / l_part;

    ushort_t* ob = O + ((size_t)b * LSEQ) * HD + h * DH;
    #pragma unroll
    for (int e = 0; e < 4; ++e) {
        const int q = q0 + wave * 16 + 4 * lq + e;
        const float linv = __shfl(inv, 4 * lq + e);
        if (q < LSEQ) {
            #pragma unroll
            for (int dt = 0; dt < 16; ++dt)
                ob[(size_t)q * HD + dt * 16 + l15] = f2b(oacc[dt][e] * linv);
        }
    }
}

// ================= residual + LayerNorm: Out = LN(bf16 X + R) =================
template<typename TR, typename TO>
__global__ __launch_bounds__(256) void residual_ln(
    const ushort_t* __restrict__ X, const TR* __restrict__ R, TO* __restrict__ Out)
{
    const int row = blockIdx.x;
    const int t = threadIdx.x;
    const size_t base = (size_t)row * HID;
    float v = b2f(X[base + t]) + to_f32(R[base + t]);
    float s = v, q = v * v;
    #pragma unroll
    for (int o = 32; o > 0; o >>= 1) {
        s += __shfl_xor(s, o, 64);
        q += __shfl_xor(q, o, 64);
    }
    __shared__ float ss[4], sq[4];
    const int wave = t >> 6, lane = t & 63;
    if (lane == 0) { ss[wave] = s; sq[wave] = q; }
    __syncthreads();
    s = ss[0] + ss[1] + ss[2] + ss[3];
    q = sq[0] + sq[1] + sq[2] + sq[3];
    float mean = s * (1.f / HID);
    float var  = q * (1.f / HID) - mean * mean;
    store_val(&Out[base + t], (v - mean) * rsqrtf(var + EPS));
}

// ================= converts =================
__global__ __launch_bounds__(256) void cvt_f32_bf16(const float* __restrict__ in,
                                                    ushort_t* __restrict__ out) {
    const int i = (blockIdx.x * 256 + threadIdx.x) * 4;
    float4 v = *(const float4*)(in + i);
    ushort4 o;
    o.x = f2b(v.x); o.y = f2b(v.y); o.z = f2b(v.z); o.w = f2b(v.w);
    *(ushort4*)(out + i) = o;
}

// W[K,N] f32 -> Wt[N,K] bf16
__global__ __launch_bounds__(256) void wtrans(const float* __restrict__ W,
                                              ushort_t* __restrict__ Wt, int K, int N) {
    __shared__ float tile[32][33];
    const int t = threadIdx.x;
    const int tx = t & 31, ty = t >> 5;
    const int n0 = blockIdx.x * 32, k0 = blockIdx.y * 32;
    #pragma unroll
    for (int s = 0; s < 4; ++s)
        tile[ty + 8 * s][tx] = W[(size_t)(k0 + ty + 8 * s) * N + n0 + tx];
    __syncthreads();
    #pragma unroll
    for (int s = 0; s < 4; ++s)
        Wt[(size_t)(n0 + ty + 8 * s) * K + k0 + tx] = f2b(tile[tx][ty + 8 * s]);
}

// ================= launch =================
extern "C" void kernel_launch(void* const* d_in, const int* in_sizes, int n_in,
                              void* d_out, int out_size, void* d_ws, size_t ws_size,
                              hipStream_t stream) {
    const float* hidden = (const float*)d_in[1];
    const float* Wq = (const float*)d_in[2];  const float* bq = (const float*)d_in[3];
    const float* Wk = (const float*)d_in[4];  const float* bk = (const float*)d_in[5];
    const float* Wv = (const float*)d_in[6];  const float* bv = (const float*)d_in[7];
    const float* Wo = (const float*)d_in[8];  const float* bo = (const float*)d_in[9];
    const float* W1 = (const float*)d_in[10]; const float* b1 = (const float*)d_in[11];
    const float* W2 = (const float*)d_in[12]; const float* b2 = (const float*)d_in[13];
    float* out = (float*)d_out;

    constexpr size_t SZ_BF   = (size_t)MROWS * HD * 2;      // 52,428,800
    constexpr size_t SZ_HBF  = (size_t)MROWS * HID * 2;     // 6,553,600
    constexpr size_t SZ_WQKV = (size_t)HID * HD * 2;        // 1,048,576
    constexpr size_t SZ_W12  = (size_t)HID * 4 * HID * 2;   // 524,288
    char* ws = (char*)d_ws;
    size_t off = 0;
    ushort_t* kb   = (ushort_t*)(ws + off); off += SZ_BF;   // K head-major [b,h][l][d]
    ushort_t* vt   = (ushort_t*)(ws + off); off += SZ_BF;   // V transposed  [b,h][d][l]
    ushort_t* qo   = (ushort_t*)(ws + off); off += SZ_BF;   // q / attn-out / ffn1
    ushort_t* hb   = (ushort_t*)(ws + off); off += SZ_HBF;  // hidden bf16
    ushort_t* at1  = (ushort_t*)(ws + off); off += SZ_HBF;
    ushort_t* at2  = (ushort_t*)(ws + off); off += SZ_HBF;
    ushort_t* proj = (ushort_t*)(ws + off); off += SZ_HBF;
    ushort_t* WtQ  = (ushort_t*)(ws + off); off += SZ_WQKV;
    ushort_t* WtK  = (ushort_t*)(ws + off); off += SZ_WQKV;
    ushort_t* WtV  = (ushort_t*)(ws + off); off += SZ_WQKV;
    ushort_t* WtO  = (ushort_t*)(ws + off); off += SZ_WQKV;
    ushort_t* Wt1  = (ushort_t*)(ws + off); off += SZ_W12;
    ushort_t* Wt2  = (ushort_t*)(ws + off); off += SZ_W12;
    if (ws_size < off) return;  // total == 188,743,680 B (same as passing R3/R5-R11)
    ushort_t* ffn1 = qo;        // alias: qo free after out-proj2

    dim3 blk(256);
    cvt_f32_bf16<<<MROWS * HID / 1024, blk, 0, stream>>>(hidden, hb);
    wtrans<<<dim3(HD / 32, HID / 32), blk, 0, stream>>>(Wq, WtQ, HID, HD);
    wtrans<<<dim3(HD / 32, HID / 32), blk, 0, stream>>>(Wk, WtK, HID, HD);
    wtrans<<<dim3(HD / 32, HID / 32), blk, 0, stream>>>(Wv, WtV, HID, HD);
    wtrans<<<dim3(HID / 32, HD / 32), blk, 0, stream>>>(Wo, WtO, HD, HID);
    wtrans<<<dim3(4 * HID / 32, HID / 32), blk, 0, stream>>>(W1, Wt1, HID, 4 * HID);
    wtrans<<<dim3(HID / 32, 4 * HID / 32), blk, 0, stream>>>(W2, Wt2, 4 * HID, HID);

    const dim3 gProj(HD / 128, MROWS / 128);
    const dim3 gOut(HID / 128, MROWS / 128);
    const dim3 gF1(4 * HID / 128, MROWS / 128);

    // K head-major; V transposed head-major (shared by both MHAs)
    gemm_bt<false, 1, false><<<gProj, blk, 0, stream>>>(hb, WtK, bk, kb, MROWS, HD, HID);
    gemm_bt<false, 2, false><<<gProj, blk, 0, stream>>>(hb, WtV, bv, vt, MROWS, HD, HID);

    // MHA1 (Q pre-scaled by CSCALE)
    gemm_bt<false, 0, true><<<gProj, blk, 0, stream>>>(hb, WtQ, bq, qo, MROWS, HD, HID);
    attn_mfma19<<<4 * BATCH * NH, 256, 0, stream>>>(qo, kb, vt, qo);
    gemm_bt<false, 0, false><<<gOut, blk, 0, stream>>>(qo, WtO, bo, proj, MROWS, HID, HD);
    residual_ln<float, ushort_t><<<MROWS, blk, 0, stream>>>(proj, hidden, at1);

    // MHA2 (q from attn1; pooled K/V rebuilt from same kb/vt)
    gemm_bt<false, 0, true><<<gProj, blk, 0, stream>>>(at1, WtQ, bq, qo, MROWS, HD, HID);
    attn_mfma19<<<4 * BATCH * NH, 256, 0, stream>>>(qo, kb, vt, qo);
    gemm_bt<false, 0, false><<<gOut, blk, 0, stream>>>(qo, WtO, bo, proj, MROWS, HID, HD);
    residual_ln<ushort_t, ushort_t><<<MROWS, blk, 0, stream>>>(proj, at1, at2);

    // FFN
    gemm_bt<true, 0, false><<<gF1, blk, 0, stream>>>(at2, Wt1, b1, ffn1, MROWS, 4 * HID, HID);
    gemm_bt<false, 0, false><<<gOut, blk, 0, stream>>>(ffn1, Wt2, b2, proj, MROWS, HID, 4 * HID);
    residual_ln<ushort_t, float><<<MROWS, blk, 0, stream>>>(proj, at2, out);
}

// Round 10
// 972.889 us; speedup vs baseline: 1.1991x; 1.1311x over previous
//
#include <hip/hip_runtime.h>
#include <hip/hip_bf16.h>
#include <cstdint>
#include <cstddef>

// Problem constants
#define BATCH 64
#define LSEQ 200
#define HID 256
#define NH 8
#define DH 256            // per-head dim = HID
#define HD (NH*DH)        // 2048
#define MROWS (BATCH*LSEQ)   // 12800
#define EPS 1e-5f
#define CSCALE 0.09014195f   // (1/sqrt(256)) * log2(e), folded into Q projection

typedef unsigned short ushort_t;
typedef __attribute__((ext_vector_type(8))) short bf16x8;         // MFMA A/B frag (4 VGPR)
typedef __attribute__((ext_vector_type(8))) unsigned short u16x8; // 16B of bf16
typedef __attribute__((ext_vector_type(4))) float f32x4;          // MFMA C/D frag

__device__ __forceinline__ float b2f(ushort_t u) {
    union { unsigned int i; float f; } c; c.i = ((unsigned int)u) << 16; return c.f;
}
__device__ __forceinline__ ushort_t f2b(float f) {
    __hip_bfloat16 h = __float2bfloat16(f);
    union { __hip_bfloat16 h; ushort_t u; } c; c.h = h; return c.u;
}
__device__ __forceinline__ float to_f32(float x) { return x; }
__device__ __forceinline__ float to_f32(ushort_t x) { return b2f(x); }
__device__ __forceinline__ void store_val(float* p, float v) { *p = v; }
__device__ __forceinline__ void store_val(ushort_t* p, float v) { *p = f2b(v); }

// packed bf16 max / add on 8 elements
__device__ __forceinline__ u16x8 bmax8(u16x8 a, u16x8 b) {
    union U { u16x8 v; __hip_bfloat162 h[4]; };
    U ua, ub, r; ua.v = a; ub.v = b;
    #pragma unroll
    for (int i = 0; i < 4; ++i) r.h[i] = __hmax2(ua.h[i], ub.h[i]);
    return r.v;
}

// async global->LDS, 16 bytes per lane (LDS dest = wave-uniform base + lane*16)
__device__ __forceinline__ void gll16(const void* g, void* l) {
    __builtin_amdgcn_global_load_lds(
        (const __attribute__((address_space(1))) unsigned int*)g,
        (__attribute__((address_space(3))) unsigned int*)l, 16, 0, 0);
}

// ================= bf16 MFMA GEMM:  C[M,N] = A[M,K] @ Bt[N,K]^T + bias =================
// 128x128 tile, BK=32, 4 waves (2x2 of 64x64), global_load_lds staging, XOR-swizzled LDS.
// OMODE: 0 = row-major [m][n]; 1 = head-major [b][h][l][d]; 2 = transposed head-major
// [b][h][d][l] (row length LSEQ=200, 8B packed stores). Modes 1/2 require N==2048.
// SCALEC: multiply (acc+bias) by CSCALE (folds softmax scale*log2e into Q projection).
template<bool RELU, int OMODE, bool SCALEC>
__global__ __launch_bounds__(256) void gemm_bt(
    const ushort_t* __restrict__ A, const ushort_t* __restrict__ Bt,
    const float* __restrict__ bias, ushort_t* __restrict__ C,
    int M, int N, int K)
{
    __shared__ ushort_t As[128 * 32];
    __shared__ ushort_t Bs[128 * 32];
    const int t = threadIdx.x;
    const int m0 = blockIdx.y * 128, n0 = blockIdx.x * 128;
    const int wave = t >> 6, lane = t & 63;
    const int l15 = lane & 15, lq = lane >> 4;
    const int wr = wave >> 1, wc = wave & 1;

    f32x4 acc[4][4];
    #pragma unroll
    for (int i = 0; i < 4; ++i)
        #pragma unroll
        for (int j = 0; j < 4; ++j) acc[i][j] = (f32x4){0.f, 0.f, 0.f, 0.f};

    for (int k0 = 0; k0 < K; k0 += 32) {
        __syncthreads();
        #pragma unroll
        for (int i = 0; i < 2; ++i) {      // stage A (2 x 16B per thread)
            int li = i * 256 + t;
            int ml = li >> 2, cp = li & 3;
            int cg = cp ^ ((ml ^ (ml >> 2)) & 3);
            gll16(A + (size_t)(m0 + ml) * K + k0 + cg * 8, &As[li * 8]);
        }
        #pragma unroll
        for (int i = 0; i < 2; ++i) {      // stage B
            int li = i * 256 + t;
            int nl = li >> 2, cp = li & 3;
            int cg = cp ^ ((nl ^ (nl >> 2)) & 3);
            gll16(Bt + (size_t)(n0 + nl) * K + k0 + cg * 8, &Bs[li * 8]);
        }
        __syncthreads();
        bf16x8 af[4], bfr[4];
        #pragma unroll
        for (int i = 0; i < 4; ++i) {
            int r = wr * 64 + i * 16 + l15;
            int pc = lq ^ ((r ^ (r >> 2)) & 3);
            af[i] = *(const bf16x8*)&As[r * 32 + pc * 8];
        }
        #pragma unroll
        for (int j = 0; j < 4; ++j) {
            int r = wc * 64 + j * 16 + l15;
            int pc = lq ^ ((r ^ (r >> 2)) & 3);
            bfr[j] = *(const bf16x8*)&Bs[r * 32 + pc * 8];
        }
        #pragma unroll
        for (int i = 0; i < 4; ++i)
            #pragma unroll
            for (int j = 0; j < 4; ++j)
                acc[i][j] = __builtin_amdgcn_mfma_f32_16x16x32_bf16(af[i], bfr[j], acc[i][j], 0, 0, 0);
    }
    // epilogue: C layout col=lane&15, row=4*quad+e
    if (OMODE == 2) {
        #pragma unroll
        for (int i = 0; i < 4; ++i) {
            int mbase = m0 + wr * 64 + i * 16 + 4 * lq;         // 4-aligned; 200%4==0
            int bb = (int)(((unsigned)mbase * 5243u) >> 20);    // mbase/200
            int ll = mbase - bb * 200;
            #pragma unroll
            for (int j = 0; j < 4; ++j) {
                int n = n0 + wc * 64 + j * 16 + l15;
                float bsv = bias[n];
                ushort4 o4;
                o4.x = f2b(acc[i][j][0] + bsv); o4.y = f2b(acc[i][j][1] + bsv);
                o4.z = f2b(acc[i][j][2] + bsv); o4.w = f2b(acc[i][j][3] + bsv);
                size_t addr = ((size_t)(bb * NH + (n >> 8)) * 256 + (n & 255)) * LSEQ + ll;
                *(ushort4*)&C[addr] = o4;
            }
        }
    } else {
        #pragma unroll
        for (int i = 0; i < 4; ++i) {
            #pragma unroll
            for (int e = 0; e < 4; ++e) {
                int m = m0 + wr * 64 + i * 16 + 4 * lq + e;
                #pragma unroll
                for (int j = 0; j < 4; ++j) {
                    int n = n0 + wc * 64 + j * 16 + l15;
                    float v = acc[i][j][e] + bias[n];
                    if (RELU) v = fmaxf(v, 0.f);
                    if (SCALEC) v *= CSCALE;
                    if (OMODE == 1) {
                        int bb = (int)(((unsigned)m * 5243u) >> 20);
                        int ll = m - bb * 200;
                        size_t addr = ((((size_t)(bb * NH + (n >> 8))) * LSEQ + ll) << 8) + (n & 255);
                        C[addr] = f2b(v);
                    } else {
                        C[(size_t)m * N + n] = f2b(v);
                    }
                }
            }
        }
    }
}

// ================= fused area-attention v20 (sigma-swap slots + pair-steps) ==========
// v16 algorithm (raw-V PV via P aggregation, operand-swapped QK^T, in-register P) with:
// 1) sigma-swap slot layout: start = lq*16 + 4*ms + e (swap ms<->lq). Consecutive starts
//    are consecutive registers in one lane -> shift1 needs ONE ds_bpermute (was 4);
//    tile bpermutes 40 -> 10. K staging loads row sigma(p); V staging becomes single
//    full-chunk stores (natural chunk cg -> kpos chunk (cg&1)*4+(cg>>1), contiguous).
//    Carry-in/out registers provably unchanged. Tail keeps physical K layout; tail V
//    placed by the derived (cls,off)->kpos map; raw-V carry rows land in kpos chunk 6.
// 2) pair-steps: two pooled-K classes per barrier window (Ks dbuf A/B, 96 KB LDS,
//    still 1 blk/CU - register-bound). Barriers 32 -> 21; each window has 64 MFMA +
//    2 independent softmax chains (ILP). Only sacc_b (+16 regs) added vs v16.
__global__ __launch_bounds__(512, 2) void attn_mfma20(
    const ushort_t* __restrict__ Q, const ushort_t* __restrict__ Khm,
    const ushort_t* __restrict__ Vt, ushort_t* __restrict__ O)  // O may alias Q
{
    const int id = blockIdx.x;
    const int xcd = id & 7, slot_ = id >> 3;    // 1024 blocks: 8 xcd x 128 slots
    const int qt = slot_ & 1;
    const int bh = ((slot_ >> 1) << 3) + xcd;   // both q-blocks of bh share an XCD
    const int b = bh >> 3, h = bh & 7;
    const int q0 = qt * 128;
    const int t = threadIdx.x;
    const int wave = t >> 6, lane = t & 63;
    const int l15 = lane & 15, lq = lane >> 4;

    __shared__ ushort_t Ks[2 * 64 * 256];  // A = [0], B = [16384] (ushort idx)
    __shared__ ushort_t Vs[256 * 64];      // V [d][kpos], chunk ^ (d&7)

    const ushort_t* kbh = Khm + (size_t)bh * LSEQ * DH;
    const ushort_t* vtb = Vt + (size_t)bh * DH * LSEQ;   // [d][l]
    const ushort_t* qbh = Q + ((size_t)b * LSEQ) * HD + h * DH;
    const int qrow = q0 + wave * 16 + l15;

    // Q fragments (row=lane&15, k=8*quad+j); pre-scaled by CSCALE in GEMM.
    bf16x8 qf[8];
    if (qrow < LSEQ) {
        const ushort_t* qp = qbh + (size_t)qrow * HD + 8 * lq;
        #pragma unroll
        for (int g = 0; g < 8; ++g) qf[g] = *(const bf16x8*)(qp + 32 * g);
    } else {
        bf16x8 zf = {0,0,0,0,0,0,0,0};
        #pragma unroll
        for (int g = 0; g < 8; ++g) qf[g] = zf;
    }

    f32x4 oacc[16];
    #pragma unroll
    for (int i = 0; i < 16; ++i) oacc[i] = (f32x4){0.f, 0.f, 0.f, 0.f};
    float l4[4];
    #pragma unroll
    for (int e = 0; e < 4; ++e) l4[e] = 0.f;
    float carry[4];
    #pragma unroll
    for (int e = 0; e < 4; ++e) carry[e] = 0.f;
    float Pagg[4][4];

    // staging roles
    const int dc = t & 31, mb = t >> 5;      // K: lane->d-chunk, thread->4 positions
    const int vd = t >> 1, vh = t & 1;       // V: thread -> d row, half (4 chunks)
    // sigma: position m = mb+16*k4 holds pooled-K for start srow+4*k4
    const int srow = ((mb >> 2) << 4) + (mb & 3);

    auto kOff = [&](int k4) {                // LDS offset of this thread's position k4
        int m = mb + 16 * k4;
        return m * 256 + ((dc ^ (m & 15)) * 8);
    };

    // ---- QK on buffer bo -> sacc (swapped operands) ----
    auto qk = [&](int bo, f32x4* sacc) {
        __builtin_amdgcn_s_setprio(1);
        #pragma unroll
        for (int ms = 0; ms < 4; ++ms) {
            f32x4 s = (f32x4){0.f, 0.f, 0.f, 0.f};
            const int row = ms * 16 + l15;
            #pragma unroll
            for (int g = 0; g < 8; ++g) {
                const int phys = (lq + 4 * g) ^ l15;
                s = __builtin_amdgcn_mfma_f32_16x16x32_bf16(
                        *(const bf16x8*)&Ks[bo + row * 256 + phys * 8], qf[g], s, 0, 0, 0);
            }
            sacc[ms] = s;
        }
        __builtin_amdgcn_s_setprio(0);
    };

    // ---- softmax for one class: P=exp2(s); Pagg += sum_{u<=cls} shift_u(P) ----
    // start = lq*16 + 4*ms + e; shift1 = 1 bpermute + register renames.
    auto smClass = [&](const f32x4* sacc, int cls) {
        float Pc[4][4];
        #pragma unroll
        for (int ms = 0; ms < 4; ++ms)
            #pragma unroll
            for (int e = 0; e < 4; ++e) {
                float pe = __builtin_exp2f(sacc[ms][e]);
                l4[e] += pe;
                Pc[ms][e] = pe;
                Pagg[ms][e] += pe;
            }
        if (cls >= 1) {
            float T[4][4];
            #pragma unroll
            for (int ms = 0; ms < 4; ++ms)
                #pragma unroll
                for (int e = 0; e < 4; ++e) T[ms][e] = Pc[ms][e];
            #pragma unroll
            for (int u = 1; u <= 4; ++u) {
                if (u <= cls) {
                    float up = __shfl(T[3][3], (lane - 16) & 63);
                    #pragma unroll
                    for (int ms = 3; ms >= 0; --ms) {
                        float nv = (ms > 0) ? T[ms - 1][3] : ((lq > 0) ? up : 0.f);
                        T[ms][3] = T[ms][2]; T[ms][2] = T[ms][1]; T[ms][1] = T[ms][0];
                        T[ms][0] = nv;
                    }
                    #pragma unroll
                    for (int ms = 0; ms < 4; ++ms)
                        #pragma unroll
                        for (int e = 0; e < 4; ++e) Pagg[ms][e] += T[ms][e];
                }
            }
        }
        // carry-out: starts 60..63 = (lq==3, ms==3, e); cond is compile-time folded
        #pragma unroll
        for (int i = 0; i < 4; ++i)
            #pragma unroll
            for (int e = 0; e < 4; ++e)
                if (cls >= 4 + i - e) carry[i] += Pc[3][e];
    };

    // ---- PV over Vs with A-frags from float P[4][4] ----
    auto pv32 = [&](const float P[4][4]) {
        unsigned int w[8];
        #pragma unroll
        for (int ms = 0; ms < 4; ++ms) {
            asm("v_cvt_pk_bf16_f32 %0, %1, %2" : "=v"(w[2*ms])   : "v"(P[ms][0]), "v"(P[ms][1]));
            asm("v_cvt_pk_bf16_f32 %0, %1, %2" : "=v"(w[2*ms+1]) : "v"(P[ms][2]), "v"(P[ms][3]));
        }
        union FR { unsigned int u[4]; bf16x8 v; };
        FR f0, f1;
        f0.u[0] = w[0]; f0.u[1] = w[1]; f0.u[2] = w[2]; f0.u[3] = w[3];
        f1.u[0] = w[4]; f1.u[1] = w[5]; f1.u[2] = w[6]; f1.u[3] = w[7];
        const bf16x8 pf0 = f0.v, pf1 = f1.v;
        __builtin_amdgcn_s_setprio(1);
        #pragma unroll
        for (int dt = 0; dt < 16; ++dt) {
            const int d = dt * 16 + l15;
            const int p0 = lq ^ (d & 7);
            const int p1 = (lq + 4) ^ (d & 7);
            oacc[dt] = __builtin_amdgcn_mfma_f32_16x16x32_bf16(
                           pf0, *(const bf16x8*)&Vs[d * 64 + p0 * 8], oacc[dt], 0, 0, 0);
            oacc[dt] = __builtin_amdgcn_mfma_f32_16x16x32_bf16(
                           pf1, *(const bf16x8*)&Vs[d * 64 + p1 * 8], oacc[dt], 0, 0, 0);
        }
        __builtin_amdgcn_s_setprio(0);
    };

    // ---- V chunk store: natural chunk cg -> kpos chunk (cg&1)*4 + (cg>>1), full 16B
    auto storeVchunk = [&](int kc, u16x8 val) {
        *(u16x8*)&Vs[vd * 64 + ((kc ^ (vd & 7)) * 8)] = val;
    };

    // =================== pipeline ===================
    // prologue: stage tile0 {A<-c0, B<-c1, Vs<-V}
    {
        u16x8 r0[4], r1[4], vc[4];
        #pragma unroll
        for (int k4 = 0; k4 < 4; ++k4) {
            const int s = srow + 4 * k4;
            r0[k4] = *(const u16x8*)(kbh + (size_t)(s) * DH + dc * 8);
            r1[k4] = *(const u16x8*)(kbh + (size_t)(s + 1) * DH + dc * 8);
        }
        const ushort_t* vrow = vtb + (size_t)vd * LSEQ + vh * 32;
        #pragma unroll
        for (int cl = 0; cl < 4; ++cl) vc[cl] = *(const u16x8*)(vrow + cl * 8);
        #pragma unroll
        for (int k4 = 0; k4 < 4; ++k4) {
            const int off = kOff(k4);
            *(u16x8*)&Ks[off] = r0[k4];
            *(u16x8*)&Ks[16384 + off] = bmax8(r0[k4], r1[k4]);
        }
        #pragma unroll
        for (int cl = 0; cl < 4; ++cl) {
            const int cg = vh * 4 + cl;
            storeVchunk((cg & 1) * 4 + (cg >> 1), vc[cl]);
        }
    }
    __syncthreads();

    for (int ti = 0; ti < 3; ++ti) {
        const int st0 = ti * 64;
        // Pagg init with carry-in (starts 0..3 = (lq==0, ms==0, e))
        {
            float pin0 = __shfl(carry[0], (lane + 48) & 63);
            float pin1 = __shfl(carry[1], (lane + 48) & 63);
            float pin2 = __shfl(carry[2], (lane + 48) & 63);
            float pin3 = __shfl(carry[3], (lane + 48) & 63);
            #pragma unroll
            for (int ms = 0; ms < 4; ++ms)
                #pragma unroll
                for (int e = 0; e < 4; ++e) Pagg[ms][e] = 0.f;
            if (lq == 0) {
                Pagg[0][0] = pin0; Pagg[0][1] = pin1; Pagg[0][2] = pin2; Pagg[0][3] = pin3;
            }
            #pragma unroll
            for (int e = 0; e < 4; ++e) carry[e] = 0.f;
        }
        // ---- compute pair (c0 on A, c1 on B) ----
        {
            f32x4 sa[4], sb[4];
            qk(0, sa); qk(16384, sb);
            smClass(sa, 0); smClass(sb, 1);
        }
        // ---- stage Q: A<-c2 = max(B_lds, +2), B<-c3 = max(c2, +3) ----
        {
            u16x8 r2[4], r3[4];
            #pragma unroll
            for (int k4 = 0; k4 < 4; ++k4) {
                const int s = st0 + srow + 4 * k4;
                r2[k4] = *(const u16x8*)(kbh + (size_t)(s + 2) * DH + dc * 8);
                r3[k4] = *(const u16x8*)(kbh + (size_t)(s + 3) * DH + dc * 8);
            }
            __syncthreads();
            #pragma unroll
            for (int k4 = 0; k4 < 4; ++k4) {
                const int off = kOff(k4);
                u16x8 c2 = bmax8(*(const u16x8*)&Ks[16384 + off], r2[k4]);
                *(u16x8*)&Ks[off] = c2;
                *(u16x8*)&Ks[16384 + off] = bmax8(c2, r3[k4]);
            }
            __syncthreads();
        }
        // ---- compute pair (c2 on A, c3 on B) ----
        {
            f32x4 sa[4], sb[4];
            qk(0, sa); qk(16384, sb);
            smClass(sa, 2); smClass(sb, 3);
        }
        // ---- stage R: A<-c4 = max(B_lds, +4) ----
        {
            u16x8 r4[4];
            #pragma unroll
            for (int k4 = 0; k4 < 4; ++k4) {
                const int s = st0 + srow + 4 * k4;
                r4[k4] = *(const u16x8*)(kbh + (size_t)(s + 4) * DH + dc * 8);
            }
            __syncthreads();
            #pragma unroll
            for (int k4 = 0; k4 < 4; ++k4) {
                const int off = kOff(k4);
                *(u16x8*)&Ks[off] = bmax8(*(const u16x8*)&Ks[16384 + off], r4[k4]);
            }
            __syncthreads();
        }
        // ---- compute single (c4 on A) + PV over this tile's raw V ----
        {
            f32x4 sa[4];
            qk(0, sa);
            smClass(sa, 4);
            pv32(Pagg);
        }
        // ---- stage next: tile ti+1 {A<-c0,B<-c1,Vs<-V} or tail ----
        if (ti < 2) {
            const int nt0 = st0 + 64;
            u16x8 r0[4], r1[4], vc[4];
            #pragma unroll
            for (int k4 = 0; k4 < 4; ++k4) {
                const int s = nt0 + srow + 4 * k4;
                r0[k4] = *(const u16x8*)(kbh + (size_t)(s) * DH + dc * 8);
                r1[k4] = *(const u16x8*)(kbh + (size_t)(s + 1) * DH + dc * 8);
            }
            const ushort_t* vrow = vtb + (size_t)vd * LSEQ + nt0 + vh * 32;
            #pragma unroll
            for (int cl = 0; cl < 4; ++cl) vc[cl] = *(const u16x8*)(vrow + cl * 8);
            __syncthreads();
            #pragma unroll
            for (int k4 = 0; k4 < 4; ++k4) {
                const int off = kOff(k4);
                *(u16x8*)&Ks[off] = r0[k4];
                *(u16x8*)&Ks[16384 + off] = bmax8(r0[k4], r1[k4]);
            }
            #pragma unroll
            for (int cl = 0; cl < 4; ++cl) {
                const int cg = vh * 4 + cl;
                storeVchunk((cg & 1) * 4 + (cg >> 1), vc[cl]);
            }
            __syncthreads();
        } else {
            // ---- tail staging: pooled tail K -> A (PHYSICAL layout), tail V -> Vs ----
            u16x8 v0 = *(const u16x8*)(vtb + (size_t)vd * LSEQ + 192);
            __syncthreads();
            if (mb < 8) {
                u16x8 krun = *(const u16x8*)(kbh + (size_t)(192 + mb) * DH + dc * 8);
                const u16x8 kz = {0,0,0,0,0,0,0,0};
                #pragma unroll
                for (int k8 = 0; k8 < 8; ++k8) {
                    const bool vv = (k8 <= 4) && (mb <= 7 - k8);
                    if (k8 > 0 && vv)
                        krun = bmax8(krun, *(const u16x8*)(kbh + (size_t)(192 + mb + k8) * DH + dc * 8));
                    int slot = k8 * 8 + mb;
                    *(u16x8*)&Ks[slot * 256 + ((dc ^ (slot & 15)) * 8)] = vv ? krun : kz;
                }
            }
            {
                float f[8];
                #pragma unroll
                for (int e = 0; e < 8; ++e) f[e] = b2f(v0[e]);
                // kpos chunk kc: elems o=0..3 -> cls_lo, o=4..7 -> cls_lo+2; off = 4*(kc&1)+(o&3)
                #pragma unroll
                for (int ck = 0; ck < 4; ++ck) {
                    const int kc = vh * 4 + ck;
                    const int cls_lo = 4 * (kc >> 2) + ((kc >> 1) & 1);
                    const int offb = 4 * (kc & 1);
                    u16x8 ov;
                    #pragma unroll
                    for (int o = 0; o < 8; ++o) {
                        const int cls = cls_lo + 2 * (o >> 2);
                        const int off = offb + (o & 3);
                        ushort_t val = 0;
                        if (cls <= 4 && off <= 7 - cls) {
                            float a = 0.f;
                            #pragma unroll
                            for (int u = 0; u <= 4; ++u)
                                if (u <= cls) a += f[off + u];
                            val = f2b(a);
                        }
                        if (kc == 6 && o < 4) val = v0[o];   // raw V[192+o] for carry slots
                        ov[o] = val;
                    }
                    storeVchunk(kc, ov);
                }
            }
            __syncthreads();
        }
    }

    // ---- tail compute: QK on A (physical slots), softmax + carry injection, PV ----
    {
        f32x4 sacc[4];
        qk(0, sacc);
        float pullc[4];
        #pragma unroll
        for (int e = 0; e < 4; ++e) pullc[e] = __shfl(carry[e], (lane + 16) & 63);
        float Pt[4][4];
        #pragma unroll
        for (int ms = 0; ms < 4; ++ms)
            #pragma unroll
            for (int e = 0; e < 4; ++e) {
                const int slot = ms * 16 + 4 * lq + e;   // PHYSICAL slot = 8*cls + off
                const bool inval = ((slot & 7) > 7 - (slot >> 3)) || ((slot >> 3) > 4);
                float pe = __builtin_exp2f(inval ? -1e30f : sacc[ms][e]);
                l4[e] += pe;           // carry slots are invalid -> pe==0 here
                float pfrag = pe;
                if (ms == 2 && lq == 2) pfrag = pullc[e];   // pairs with raw V in kc 6
                Pt[ms][e] = pfrag;
            }
        pv32(Pt);
    }

    // epilogue: reduce l over the 4 lq groups, invert, redistribute
    float l_part = (l4[0] + l4[1]) + (l4[2] + l4[3]);
    l_part += __shfl_xor(l_part, 16);
    l_part += __shfl_xor(l_part, 32);
    const float inv = 1.f / l_part;

    ushort_t* ob = O + ((size_t)b * LSEQ) * HD + h * DH;
    #pragma unroll
    for (int e = 0; e < 4; ++e) {
        const int q = q0 + wave * 16 + 4 * lq + e;
        const float linv = __shfl(inv, 4 * lq + e);
        if (q < LSEQ) {
            #pragma unroll
            for (int dt = 0; dt < 16; ++dt)
                ob[(size_t)q * HD + dt * 16 + l15] = f2b(oacc[dt][e] * linv);
        }
    }
}

// ================= residual + LayerNorm: Out = LN(bf16 X + R) =================
template<typename TR, typename TO>
__global__ __launch_bounds__(256) void residual_ln(
    const ushort_t* __restrict__ X, const TR* __restrict__ R, TO* __restrict__ Out)
{
    const int row = blockIdx.x;
    const int t = threadIdx.x;
    const size_t base = (size_t)row * HID;
    float v = b2f(X[base + t]) + to_f32(R[base + t]);
    float s = v, q = v * v;
    #pragma unroll
    for (int o = 32; o > 0; o >>= 1) {
        s += __shfl_xor(s, o, 64);
        q += __shfl_xor(q, o, 64);
    }
    __shared__ float ss[4], sq[4];
    const int wave = t >> 6, lane = t & 63;
    if (lane == 0) { ss[wave] = s; sq[wave] = q; }
    __syncthreads();
    s = ss[0] + ss[1] + ss[2] + ss[3];
    q = sq[0] + sq[1] + sq[2] + sq[3];
    float mean = s * (1.f / HID);
    float var  = q * (1.f / HID) - mean * mean;
    store_val(&Out[base + t], (v - mean) * rsqrtf(var + EPS));
}

// ================= converts =================
__global__ __launch_bounds__(256) void cvt_f32_bf16(const float* __restrict__ in,
                                                    ushort_t* __restrict__ out) {
    const int i = (blockIdx.x * 256 + threadIdx.x) * 4;
    float4 v = *(const float4*)(in + i);
    ushort4 o;
    o.x = f2b(v.x); o.y = f2b(v.y); o.z = f2b(v.z); o.w = f2b(v.w);
    *(ushort4*)(out + i) = o;
}

// W[K,N] f32 -> Wt[N,K] bf16
__global__ __launch_bounds__(256) void wtrans(const float* __restrict__ W,
                                              ushort_t* __restrict__ Wt, int K, int N) {
    __shared__ float tile[32][33];
    const int t = threadIdx.x;
    const int tx = t & 31, ty = t >> 5;
    const int n0 = blockIdx.x * 32, k0 = blockIdx.y * 32;
    #pragma unroll
    for (int s = 0; s < 4; ++s)
        tile[ty + 8 * s][tx] = W[(size_t)(k0 + ty + 8 * s) * N + n0 + tx];
    __syncthreads();
    #pragma unroll
    for (int s = 0; s < 4; ++s)
        Wt[(size_t)(n0 + ty + 8 * s) * K + k0 + tx] = f2b(tile[tx][ty + 8 * s]);
}

// ================= launch =================
extern "C" void kernel_launch(void* const* d_in, const int* in_sizes, int n_in,
                              void* d_out, int out_size, void* d_ws, size_t ws_size,
                              hipStream_t stream) {
    const float* hidden = (const float*)d_in[1];
    const float* Wq = (const float*)d_in[2];  const float* bq = (const float*)d_in[3];
    const float* Wk = (const float*)d_in[4];  const float* bk = (const float*)d_in[5];
    const float* Wv = (const float*)d_in[6];  const float* bv = (const float*)d_in[7];
    const float* Wo = (const float*)d_in[8];  const float* bo = (const float*)d_in[9];
    const float* W1 = (const float*)d_in[10]; const float* b1 = (const float*)d_in[11];
    const float* W2 = (const float*)d_in[12]; const float* b2 = (const float*)d_in[13];
    float* out = (float*)d_out;

    constexpr size_t SZ_BF   = (size_t)MROWS * HD * 2;      // 52,428,800
    constexpr size_t SZ_HBF  = (size_t)MROWS * HID * 2;     // 6,553,600
    constexpr size_t SZ_WQKV = (size_t)HID * HD * 2;        // 1,048,576
    constexpr size_t SZ_W12  = (size_t)HID * 4 * HID * 2;   // 524,288
    char* ws = (char*)d_ws;
    size_t off = 0;
    ushort_t* kb   = (ushort_t*)(ws + off); off += SZ_BF;   // K head-major [b,h][l][d]
    ushort_t* vt   = (ushort_t*)(ws + off); off += SZ_BF;   // V transposed  [b,h][d][l]
    ushort_t* qo   = (ushort_t*)(ws + off); off += SZ_BF;   // q / attn-out / ffn1
    ushort_t* hb   = (ushort_t*)(ws + off); off += SZ_HBF;  // hidden bf16
    ushort_t* at1  = (ushort_t*)(ws + off); off += SZ_HBF;
    ushort_t* at2  = (ushort_t*)(ws + off); off += SZ_HBF;
    ushort_t* proj = (ushort_t*)(ws + off); off += SZ_HBF;
    ushort_t* WtQ  = (ushort_t*)(ws + off); off += SZ_WQKV;
    ushort_t* WtK  = (ushort_t*)(ws + off); off += SZ_WQKV;
    ushort_t* WtV  = (ushort_t*)(ws + off); off += SZ_WQKV;
    ushort_t* WtO  = (ushort_t*)(ws + off); off += SZ_WQKV;
    ushort_t* Wt1  = (ushort_t*)(ws + off); off += SZ_W12;
    ushort_t* Wt2  = (ushort_t*)(ws + off); off += SZ_W12;
    if (ws_size < off) return;  // total == 188,743,680 B (same as passing R3/R5-R11)
    ushort_t* ffn1 = qo;        // alias: qo free after out-proj2

    dim3 blk(256);
    cvt_f32_bf16<<<MROWS * HID / 1024, blk, 0, stream>>>(hidden, hb);
    wtrans<<<dim3(HD / 32, HID / 32), blk, 0, stream>>>(Wq, WtQ, HID, HD);
    wtrans<<<dim3(HD / 32, HID / 32), blk, 0, stream>>>(Wk, WtK, HID, HD);
    wtrans<<<dim3(HD / 32, HID / 32), blk, 0, stream>>>(Wv, WtV, HID, HD);
    wtrans<<<dim3(HID / 32, HD / 32), blk, 0, stream>>>(Wo, WtO, HD, HID);
    wtrans<<<dim3(4 * HID / 32, HID / 32), blk, 0, stream>>>(W1, Wt1, HID, 4 * HID);
    wtrans<<<dim3(HID / 32, 4 * HID / 32), blk, 0, stream>>>(W2, Wt2, 4 * HID, HID);

    const dim3 gProj(HD / 128, MROWS / 128);
    const dim3 gOut(HID / 128, MROWS / 128);
    const dim3 gF1(4 * HID / 128, MROWS / 128);

    // K head-major; V transposed head-major (shared by both MHAs)
    gemm_bt<false, 1, false><<<gProj, blk, 0, stream>>>(hb, WtK, bk, kb, MROWS, HD, HID);
    gemm_bt<false, 2, false><<<gProj, blk, 0, stream>>>(hb, WtV, bv, vt, MROWS, HD, HID);

    // MHA1 (Q pre-scaled by CSCALE)
    gemm_bt<false, 0, true><<<gProj, blk, 0, stream>>>(hb, WtQ, bq, qo, MROWS, HD, HID);
    attn_mfma20<<<2 * BATCH * NH, 512, 0, stream>>>(qo, kb, vt, qo);
    gemm_bt<false, 0, false><<<gOut, blk, 0, stream>>>(qo, WtO, bo, proj, MROWS, HID, HD);
    residual_ln<float, ushort_t><<<MROWS, blk, 0, stream>>>(proj, hidden, at1);

    // MHA2 (q from attn1; pooled K/V rebuilt from same kb/vt)
    gemm_bt<false, 0, true><<<gProj, blk, 0, stream>>>(at1, WtQ, bq, qo, MROWS, HD, HID);
    attn_mfma20<<<2 * BATCH * NH, 512, 0, stream>>>(qo, kb, vt, qo);
    gemm_bt<false, 0, false><<<gOut, blk, 0, stream>>>(qo, WtO, bo, proj, MROWS, HID, HD);
    residual_ln<ushort_t, ushort_t><<<MROWS, blk, 0, stream>>>(proj, at1, at2);

    // FFN
    gemm_bt<true, 0, false><<<gF1, blk, 0, stream>>>(at2, Wt1, b1, ffn1, MROWS, 4 * HID, HID);
    gemm_bt<false, 0, false><<<gOut, blk, 0, stream>>>(ffn1, Wt2, b2, proj, MROWS, HID, 4 * HID);
    residual_ln<ushort_t, float><<<MROWS, blk, 0, stream>>>(proj, at2, out);
}

// Round 11
// 904.181 us; speedup vs baseline: 1.2902x; 1.0760x over previous
//
#include <hip/hip_runtime.h>
#include <hip/hip_bf16.h>
#include <cstdint>
#include <cstddef>

// Problem constants
#define BATCH 64
#define LSEQ 200
#define HID 256
#define NH 8
#define DH 256            // per-head dim = HID
#define HD (NH*DH)        // 2048
#define MROWS (BATCH*LSEQ)   // 12800
#define EPS 1e-5f
#define CSCALE 0.09014195f   // (1/sqrt(256)) * log2(e), folded into Q projection

typedef unsigned short ushort_t;
typedef __attribute__((ext_vector_type(8))) short bf16x8;         // MFMA A/B frag (4 VGPR)
typedef __attribute__((ext_vector_type(8))) unsigned short u16x8; // 16B of bf16
typedef __attribute__((ext_vector_type(4))) float f32x4;          // MFMA C/D frag

__device__ __forceinline__ float b2f(ushort_t u) {
    union { unsigned int i; float f; } c; c.i = ((unsigned int)u) << 16; return c.f;
}
__device__ __forceinline__ ushort_t f2b(float f) {
    __hip_bfloat16 h = __float2bfloat16(f);
    union { __hip_bfloat16 h; ushort_t u; } c; c.h = h; return c.u;
}
__device__ __forceinline__ float to_f32(float x) { return x; }
__device__ __forceinline__ float to_f32(ushort_t x) { return b2f(x); }
__device__ __forceinline__ void store_val(float* p, float v) { *p = v; }
__device__ __forceinline__ void store_val(ushort_t* p, float v) { *p = f2b(v); }

// packed bf16 max on 8 elements
__device__ __forceinline__ u16x8 bmax8(u16x8 a, u16x8 b) {
    union U { u16x8 v; __hip_bfloat162 h[4]; };
    U ua, ub, r; ua.v = a; ub.v = b;
    #pragma unroll
    for (int i = 0; i < 4; ++i) r.h[i] = __hmax2(ua.h[i], ub.h[i]);
    return r.v;
}

// async global->LDS, 16 bytes per lane (LDS dest = wave-uniform base + lane*16)
__device__ __forceinline__ void gll16(const void* g, void* l) {
    __builtin_amdgcn_global_load_lds(
        (const __attribute__((address_space(1))) unsigned int*)g,
        (__attribute__((address_space(3))) unsigned int*)l, 16, 0, 0);
}

// ================= bf16 MFMA GEMM:  C[M,N] = A[M,K] @ Bt[N,K]^T + bias =================
// 128x128 tile, BK=32, 4 waves (2x2 of 64x64), global_load_lds staging, XOR-swizzled LDS.
// OMODE: 0 = row-major [m][n]; 1 = head-major [b][h][l][d]; 2 = transposed head-major
// [b][h][d][l] (row length LSEQ=200, 8B packed stores). Modes 1/2 require N==2048.
// SCALEC: multiply (acc+bias) by CSCALE (folds softmax scale*log2e into Q projection).
template<bool RELU, int OMODE, bool SCALEC>
__global__ __launch_bounds__(256) void gemm_bt(
    const ushort_t* __restrict__ A, const ushort_t* __restrict__ Bt,
    const float* __restrict__ bias, ushort_t* __restrict__ C,
    int M, int N, int K)
{
    __shared__ ushort_t As[128 * 32];
    __shared__ ushort_t Bs[128 * 32];
    const int t = threadIdx.x;
    const int m0 = blockIdx.y * 128, n0 = blockIdx.x * 128;
    const int wave = t >> 6, lane = t & 63;
    const int l15 = lane & 15, lq = lane >> 4;
    const int wr = wave >> 1, wc = wave & 1;

    f32x4 acc[4][4];
    #pragma unroll
    for (int i = 0; i < 4; ++i)
        #pragma unroll
        for (int j = 0; j < 4; ++j) acc[i][j] = (f32x4){0.f, 0.f, 0.f, 0.f};

    for (int k0 = 0; k0 < K; k0 += 32) {
        __syncthreads();
        #pragma unroll
        for (int i = 0; i < 2; ++i) {      // stage A (2 x 16B per thread)
            int li = i * 256 + t;
            int ml = li >> 2, cp = li & 3;
            int cg = cp ^ ((ml ^ (ml >> 2)) & 3);
            gll16(A + (size_t)(m0 + ml) * K + k0 + cg * 8, &As[li * 8]);
        }
        #pragma unroll
        for (int i = 0; i < 2; ++i) {      // stage B
            int li = i * 256 + t;
            int nl = li >> 2, cp = li & 3;
            int cg = cp ^ ((nl ^ (nl >> 2)) & 3);
            gll16(Bt + (size_t)(n0 + nl) * K + k0 + cg * 8, &Bs[li * 8]);
        }
        __syncthreads();
        bf16x8 af[4], bfr[4];
        #pragma unroll
        for (int i = 0; i < 4; ++i) {
            int r = wr * 64 + i * 16 + l15;
            int pc = lq ^ ((r ^ (r >> 2)) & 3);
            af[i] = *(const bf16x8*)&As[r * 32 + pc * 8];
        }
        #pragma unroll
        for (int j = 0; j < 4; ++j) {
            int r = wc * 64 + j * 16 + l15;
            int pc = lq ^ ((r ^ (r >> 2)) & 3);
            bfr[j] = *(const bf16x8*)&Bs[r * 32 + pc * 8];
        }
        #pragma unroll
        for (int i = 0; i < 4; ++i)
            #pragma unroll
            for (int j = 0; j < 4; ++j)
                acc[i][j] = __builtin_amdgcn_mfma_f32_16x16x32_bf16(af[i], bfr[j], acc[i][j], 0, 0, 0);
    }
    // epilogue: C layout col=lane&15, row=4*quad+e
    if (OMODE == 2) {
        #pragma unroll
        for (int i = 0; i < 4; ++i) {
            int mbase = m0 + wr * 64 + i * 16 + 4 * lq;         // 4-aligned; 200%4==0
            int bb = (int)(((unsigned)mbase * 5243u) >> 20);    // mbase/200
            int ll = mbase - bb * 200;
            #pragma unroll
            for (int j = 0; j < 4; ++j) {
                int n = n0 + wc * 64 + j * 16 + l15;
                float bsv = bias[n];
                ushort4 o4;
                o4.x = f2b(acc[i][j][0] + bsv); o4.y = f2b(acc[i][j][1] + bsv);
                o4.z = f2b(acc[i][j][2] + bsv); o4.w = f2b(acc[i][j][3] + bsv);
                size_t addr = ((size_t)(bb * NH + (n >> 8)) * 256 + (n & 255)) * LSEQ + ll;
                *(ushort4*)&C[addr] = o4;
            }
        }
    } else {
        #pragma unroll
        for (int i = 0; i < 4; ++i) {
            #pragma unroll
            for (int e = 0; e < 4; ++e) {
                int m = m0 + wr * 64 + i * 16 + 4 * lq + e;
                #pragma unroll
                for (int j = 0; j < 4; ++j) {
                    int n = n0 + wc * 64 + j * 16 + l15;
                    float v = acc[i][j][e] + bias[n];
                    if (RELU) v = fmaxf(v, 0.f);
                    if (SCALEC) v *= CSCALE;
                    if (OMODE == 1) {
                        int bb = (int)(((unsigned)m * 5243u) >> 20);
                        int ll = m - bb * 200;
                        size_t addr = ((((size_t)(bb * NH + (n >> 8))) * LSEQ + ll) << 8) + (n & 255);
                        C[addr] = f2b(v);
                    } else {
                        C[(size_t)m * N + n] = f2b(v);
                    }
                }
            }
        }
    }
}

// ================= fused area-attention v21 (v16 skeleton + sigma-swap slots) ========
// v16's exact loop structure and register profile (raw-V PV via P aggregation,
// operand-swapped QK^T, in-register P, single Ks buffer, in-place K RMW, 2 barriers
// per class step) with v20's VALIDATED sigma-swap slot layout: start = lq*16+4*ms+e.
// Effects: shift1 = ONE shuffle (was 4; tile xlane ops 40 -> 10); V staging = full
// 16B chunk stores (natural chunk cg -> kpos chunk (cg&1)*4+(cg>>1)); K staging loads
// row sigma(p) (same cost). Tail uses physical layout + derived kpos table + raw-V
// carry rows in kpos chunk 6 (all validated in v20). Pair-step dropped: it spilled
// (+86 MB writes) and doubled staging LDS traffic (conflicts 262K -> 786K).
__global__ __launch_bounds__(512, 2) void attn_mfma21(
    const ushort_t* __restrict__ Q, const ushort_t* __restrict__ Khm,
    const ushort_t* __restrict__ Vt, ushort_t* __restrict__ O)  // O may alias Q
{
    const int id = blockIdx.x;
    const int xcd = id & 7, slot_ = id >> 3;    // 1024 blocks: 8 xcd x 128 slots
    const int qt = slot_ & 1;
    const int bh = ((slot_ >> 1) << 3) + xcd;   // both q-blocks of bh share an XCD
    const int b = bh >> 3, h = bh & 7;
    const int q0 = qt * 128;
    const int t = threadIdx.x;
    const int wave = t >> 6, lane = t & 63;
    const int l15 = lane & 15, lq = lane >> 4;

    __shared__ ushort_t Ks[64 * 256];      // pooled K (sigma rows), chunk ^ (m&15), 32 KB
    __shared__ ushort_t Vs[256 * 64];      // V [d][kpos], chunk ^ (d&7), 32 KB

    const ushort_t* kbh = Khm + (size_t)bh * LSEQ * DH;
    const ushort_t* vtb = Vt + (size_t)bh * DH * LSEQ;   // [d][l]
    const ushort_t* qbh = Q + ((size_t)b * LSEQ) * HD + h * DH;
    const int qrow = q0 + wave * 16 + l15;

    // Q fragments (row=lane&15, k=8*quad+j); pre-scaled by CSCALE in GEMM.
    bf16x8 qf[8];
    if (qrow < LSEQ) {
        const ushort_t* qp = qbh + (size_t)qrow * HD + 8 * lq;
        #pragma unroll
        for (int g = 0; g < 8; ++g) qf[g] = *(const bf16x8*)(qp + 32 * g);
    } else {
        bf16x8 zf = {0,0,0,0,0,0,0,0};
        #pragma unroll
        for (int g = 0; g < 8; ++g) qf[g] = zf;
    }

    f32x4 oacc[16];
    #pragma unroll
    for (int i = 0; i < 16; ++i) oacc[i] = (f32x4){0.f, 0.f, 0.f, 0.f};
    float l4[4];
    #pragma unroll
    for (int e = 0; e < 4; ++e) l4[e] = 0.f;
    float carry[4];                        // Pagg spill into next tile's starts 0..3
    #pragma unroll
    for (int e = 0; e < 4; ++e) carry[e] = 0.f;
    float Pagg[4][4];

    // staging roles for 512 threads
    const int dc = t & 31, mb = t >> 5;      // K: lane->d-chunk, thread->4 positions
    const int vd = t >> 1, vh = t & 1;       // V: thread -> d row, half (4 chunks each)
    // sigma: physical position m = mb + 16*k4 holds pooled-K for start srow + 4*k4
    const int srow = ((mb >> 2) << 4) + (mb & 3);

    auto kOff = [&](int k4) {
        int m = mb + 16 * k4;
        return m * 256 + ((dc ^ (m & 15)) * 8);
    };
    auto storeVchunk = [&](int kc, u16x8 val) {   // full 16B, kpos chunk kc
        *(u16x8*)&Vs[vd * 64 + ((kc ^ (vd & 7)) * 8)] = val;
    };

    // QK on Ks -> sacc (swapped operands): sacc[ms][e] = S^T[phys row][q=l15]
    auto qk = [&](f32x4* sacc) {
        __builtin_amdgcn_s_setprio(1);
        #pragma unroll
        for (int ms = 0; ms < 4; ++ms) {
            f32x4 s = (f32x4){0.f, 0.f, 0.f, 0.f};
            const int row = ms * 16 + l15;
            #pragma unroll
            for (int g = 0; g < 8; ++g) {
                const int phys = (lq + 4 * g) ^ l15;
                s = __builtin_amdgcn_mfma_f32_16x16x32_bf16(
                        *(const bf16x8*)&Ks[row * 256 + phys * 8], qf[g], s, 0, 0, 0);
            }
            sacc[ms] = s;
        }
        __builtin_amdgcn_s_setprio(0);
    };

    // softmax for one class under start = lq*16 + 4*ms + e; shift1 = ONE shuffle
    auto smClass = [&](const f32x4* sacc, int cls) {
        float Pc[4][4];
        #pragma unroll
        for (int ms = 0; ms < 4; ++ms)
            #pragma unroll
            for (int e = 0; e < 4; ++e) {
                float pe = __builtin_exp2f(sacc[ms][e]);
                l4[e] += pe;
                Pc[ms][e] = pe;
                Pagg[ms][e] += pe;
            }
        if (cls >= 1) {
            float T[4][4];
            #pragma unroll
            for (int ms = 0; ms < 4; ++ms)
                #pragma unroll
                for (int e = 0; e < 4; ++e) T[ms][e] = Pc[ms][e];
            #pragma unroll
            for (int u = 1; u <= 4; ++u) {
                if (u <= cls) {
                    float up = __shfl(T[3][3], (lane - 16) & 63);
                    #pragma unroll
                    for (int ms = 3; ms >= 0; --ms) {
                        float nv = (ms > 0) ? T[ms - 1][3] : ((lq > 0) ? up : 0.f);
                        T[ms][3] = T[ms][2]; T[ms][2] = T[ms][1]; T[ms][1] = T[ms][0];
                        T[ms][0] = nv;
                    }
                    #pragma unroll
                    for (int ms = 0; ms < 4; ++ms)
                        #pragma unroll
                        for (int e = 0; e < 4; ++e) Pagg[ms][e] += T[ms][e];
                }
            }
        }
        // carry-out: starts 60..63 = (lq==3, ms==3, e)
        #pragma unroll
        for (int i = 0; i < 4; ++i)
            #pragma unroll
            for (int e = 0; e < 4; ++e)
                if (cls >= 4 + i - e) carry[i] += Pc[3][e];
    };

    // PV over Vs with A-frags from float P[4][4]
    auto pv32 = [&](const float P[4][4]) {
        unsigned int w[8];
        #pragma unroll
        for (int ms = 0; ms < 4; ++ms) {
            asm("v_cvt_pk_bf16_f32 %0, %1, %2" : "=v"(w[2*ms])   : "v"(P[ms][0]), "v"(P[ms][1]));
            asm("v_cvt_pk_bf16_f32 %0, %1, %2" : "=v"(w[2*ms+1]) : "v"(P[ms][2]), "v"(P[ms][3]));
        }
        union FR { unsigned int u[4]; bf16x8 v; };
        FR f0, f1;
        f0.u[0] = w[0]; f0.u[1] = w[1]; f0.u[2] = w[2]; f0.u[3] = w[3];
        f1.u[0] = w[4]; f1.u[1] = w[5]; f1.u[2] = w[6]; f1.u[3] = w[7];
        const bf16x8 pf0 = f0.v, pf1 = f1.v;
        __builtin_amdgcn_s_setprio(1);
        #pragma unroll
        for (int dt = 0; dt < 16; ++dt) {
            const int d = dt * 16 + l15;
            const int p0 = lq ^ (d & 7);
            const int p1 = (lq + 4) ^ (d & 7);
            oacc[dt] = __builtin_amdgcn_mfma_f32_16x16x32_bf16(
                           pf0, *(const bf16x8*)&Vs[d * 64 + p0 * 8], oacc[dt], 0, 0, 0);
            oacc[dt] = __builtin_amdgcn_mfma_f32_16x16x32_bf16(
                           pf1, *(const bf16x8*)&Vs[d * 64 + p1 * 8], oacc[dt], 0, 0, 0);
        }
        __builtin_amdgcn_s_setprio(0);
    };

    // ---- 3 full tiles x 5 QK classes + 1 PV each ----
    for (int ti = 0; ti < 3; ++ti) {
        const int st0 = ti * 64;
        // carry-in: prev tile's spill -> this tile's starts 0..3 (lq==0, ms==0)
        {
            float pin0 = __shfl(carry[0], (lane + 48) & 63);
            float pin1 = __shfl(carry[1], (lane + 48) & 63);
            float pin2 = __shfl(carry[2], (lane + 48) & 63);
            float pin3 = __shfl(carry[3], (lane + 48) & 63);
            #pragma unroll
            for (int ms = 0; ms < 4; ++ms)
                #pragma unroll
                for (int e = 0; e < 4; ++e) Pagg[ms][e] = 0.f;
            if (lq == 0) {
                Pagg[0][0] = pin0; Pagg[0][1] = pin1; Pagg[0][2] = pin2; Pagg[0][3] = pin3;
            }
            #pragma unroll
            for (int e = 0; e < 4; ++e) carry[e] = 0.f;
        }
        #pragma unroll
        for (int cls = 0; cls < 5; ++cls) {
            // prefetch sigma-swapped K rows (+cls); raw V rows at cls==0 (once/tile)
            u16x8 kf[4];
            #pragma unroll
            for (int k4 = 0; k4 < 4; ++k4)
                kf[k4] = *(const u16x8*)(kbh + (size_t)(st0 + srow + 4 * k4 + cls) * DH + dc * 8);
            u16x8 vc[4];
            if (cls == 0) {
                const ushort_t* vrow = vtb + (size_t)vd * LSEQ + st0 + vh * 32;
                #pragma unroll
                for (int c2 = 0; c2 < 4; ++c2) vc[c2] = *(const u16x8*)(vrow + c2 * 8);
            }
            __syncthreads();   // previous step's frag reads done

            // K pooled: running max in Ks (in-place RMW), 4 positions/thread
            #pragma unroll
            for (int k4 = 0; k4 < 4; ++k4) {
                ushort_t* kp = &Ks[kOff(k4)];
                *(u16x8*)kp = (cls == 0) ? kf[k4] : bmax8(*(const u16x8*)kp, kf[k4]);
            }
            // raw V staged once per tile: natural chunk cg -> kpos chunk (cg&1)*4+(cg>>1)
            if (cls == 0) {
                #pragma unroll
                for (int cl = 0; cl < 4; ++cl) {
                    const int cg = vh * 4 + cl;
                    storeVchunk((cg & 1) * 4 + (cg >> 1), vc[cl]);
                }
            }
            __syncthreads();

            f32x4 sacc[4];
            qk(sacc);
            smClass(sacc, cls);
            if (cls == 4) pv32(Pagg);   // one PV over raw V for the whole tile
        }
    }

    // ---- tail step: pooled tail K (PHYSICAL layout) + tail V via kpos table ----
    {
        __syncthreads();   // previous step's frag reads (incl. PV) done
        // K: threads with mb<8 cover physical slots k8*8+mb (cls=k8, off=mb)
        if (mb < 8) {
            u16x8 krun = *(const u16x8*)(kbh + (size_t)(192 + mb) * DH + dc * 8);
            const u16x8 kz = {0,0,0,0,0,0,0,0};
            #pragma unroll
            for (int k8 = 0; k8 < 8; ++k8) {
                const bool vv = (k8 <= 4) && (mb <= 7 - k8);
                if (k8 > 0 && vv)
                    krun = bmax8(krun, *(const u16x8*)(kbh + (size_t)(192 + mb + k8) * DH + dc * 8));
                int slot = k8 * 8 + mb;
                *(u16x8*)&Ks[slot * 256 + ((dc ^ (slot & 15)) * 8)] = vv ? krun : kz;
            }
        }
        // V: kpos chunk kc holds (cls,off) per derived map; kc==6 o<4 = raw V[192..195]
        {
            u16x8 v0 = *(const u16x8*)(vtb + (size_t)vd * LSEQ + 192);
            float f[8];
            #pragma unroll
            for (int e = 0; e < 8; ++e) f[e] = b2f(v0[e]);
            #pragma unroll
            for (int ck = 0; ck < 4; ++ck) {
                const int kc = vh * 4 + ck;
                const int cls_lo = 4 * (kc >> 2) + ((kc >> 1) & 1);
                const int offb = 4 * (kc & 1);
                u16x8 ov;
                #pragma unroll
                for (int o = 0; o < 8; ++o) {
                    const int cls = cls_lo + 2 * (o >> 2);
                    const int off = offb + (o & 3);
                    ushort_t val = 0;
                    if (cls <= 4 && off <= 7 - cls) {
                        float a = 0.f;
                        #pragma unroll
                        for (int u = 0; u <= 4; ++u)
                            if (u <= cls) a += f[off + u];
                        val = f2b(a);
                    }
                    if (kc == 6 && o < 4) val = v0[o];   // raw V for carry slots
                    ov[o] = val;
                }
                storeVchunk(kc, ov);
            }
        }
        __syncthreads();

        // tail compute: QK (physical slots), softmax + carry injection, PV
        f32x4 sacc[4];
        qk(sacc);
        float pullc[4];
        #pragma unroll
        for (int e = 0; e < 4; ++e) pullc[e] = __shfl(carry[e], (lane + 16) & 63);
        float Pt[4][4];
        #pragma unroll
        for (int ms = 0; ms < 4; ++ms)
            #pragma unroll
            for (int e = 0; e < 4; ++e) {
                const int slot = ms * 16 + 4 * lq + e;   // PHYSICAL slot = 8*cls + off
                const bool inval = ((slot & 7) > 7 - (slot >> 3)) || ((slot >> 3) > 4);
                float pe = __builtin_exp2f(inval ? -1e30f : sacc[ms][e]);
                l4[e] += pe;           // carry slots are invalid -> pe==0 here
                float pfrag = pe;
                if (ms == 2 && lq == 2) pfrag = pullc[e];   // pairs with raw V in kc 6
                Pt[ms][e] = pfrag;
            }
        pv32(Pt);
    }

    // epilogue: reduce l over the 4 lq groups, invert, redistribute
    float l_part = (l4[0] + l4[1]) + (l4[2] + l4[3]);
    l_part += __shfl_xor(l_part, 16);
    l_part += __shfl_xor(l_part, 32);
    const float inv = 1.f / l_part;

    ushort_t* ob = O + ((size_t)b * LSEQ) * HD + h * DH;
    #pragma unroll
    for (int e = 0; e < 4; ++e) {
        const int q = q0 + wave * 16 + 4 * lq + e;
        const float linv = __shfl(inv, 4 * lq + e);
        if (q < LSEQ) {
            #pragma unroll
            for (int dt = 0; dt < 16; ++dt)
                ob[(size_t)q * HD + dt * 16 + l15] = f2b(oacc[dt][e] * linv);
        }
    }
}

// ================= residual + LayerNorm: Out = LN(bf16 X + R) =================
template<typename TR, typename TO>
__global__ __launch_bounds__(256) void residual_ln(
    const ushort_t* __restrict__ X, const TR* __restrict__ R, TO* __restrict__ Out)
{
    const int row = blockIdx.x;
    const int t = threadIdx.x;
    const size_t base = (size_t)row * HID;
    float v = b2f(X[base + t]) + to_f32(R[base + t]);
    float s = v, q = v * v;
    #pragma unroll
    for (int o = 32; o > 0; o >>= 1) {
        s += __shfl_xor(s, o, 64);
        q += __shfl_xor(q, o, 64);
    }
    __shared__ float ss[4], sq[4];
    const int wave = t >> 6, lane = t & 63;
    if (lane == 0) { ss[wave] = s; sq[wave] = q; }
    __syncthreads();
    s = ss[0] + ss[1] + ss[2] + ss[3];
    q = sq[0] + sq[1] + sq[2] + sq[3];
    float mean = s * (1.f / HID);
    float var  = q * (1.f / HID) - mean * mean;
    store_val(&Out[base + t], (v - mean) * rsqrtf(var + EPS));
}

// ================= converts =================
__global__ __launch_bounds__(256) void cvt_f32_bf16(const float* __restrict__ in,
                                                    ushort_t* __restrict__ out) {
    const int i = (blockIdx.x * 256 + threadIdx.x) * 4;
    float4 v = *(const float4*)(in + i);
    ushort4 o;
    o.x = f2b(v.x); o.y = f2b(v.y); o.z = f2b(v.z); o.w = f2b(v.w);
    *(ushort4*)(out + i) = o;
}

// W[K,N] f32 -> Wt[N,K] bf16
__global__ __launch_bounds__(256) void wtrans(const float* __restrict__ W,
                                              ushort_t* __restrict__ Wt, int K, int N) {
    __shared__ float tile[32][33];
    const int t = threadIdx.x;
    const int tx = t & 31, ty = t >> 5;
    const int n0 = blockIdx.x * 32, k0 = blockIdx.y * 32;
    #pragma unroll
    for (int s = 0; s < 4; ++s)
        tile[ty + 8 * s][tx] = W[(size_t)(k0 + ty + 8 * s) * N + n0 + tx];
    __syncthreads();
    #pragma unroll
    for (int s = 0; s < 4; ++s)
        Wt[(size_t)(n0 + ty + 8 * s) * K + k0 + tx] = f2b(tile[tx][ty + 8 * s]);
}

// ================= launch =================
extern "C" void kernel_launch(void* const* d_in, const int* in_sizes, int n_in,
                              void* d_out, int out_size, void* d_ws, size_t ws_size,
                              hipStream_t stream) {
    const float* hidden = (const float*)d_in[1];
    const float* Wq = (const float*)d_in[2];  const float* bq = (const float*)d_in[3];
    const float* Wk = (const float*)d_in[4];  const float* bk = (const float*)d_in[5];
    const float* Wv = (const float*)d_in[6];  const float* bv = (const float*)d_in[7];
    const float* Wo = (const float*)d_in[8];  const float* bo = (const float*)d_in[9];
    const float* W1 = (const float*)d_in[10]; const float* b1 = (const float*)d_in[11];
    const float* W2 = (const float*)d_in[12]; const float* b2 = (const float*)d_in[13];
    float* out = (float*)d_out;

    constexpr size_t SZ_BF   = (size_t)MROWS * HD * 2;      // 52,428,800
    constexpr size_t SZ_HBF  = (size_t)MROWS * HID * 2;     // 6,553,600
    constexpr size_t SZ_WQKV = (size_t)HID * HD * 2;        // 1,048,576
    constexpr size_t SZ_W12  = (size_t)HID * 4 * HID * 2;   // 524,288
    char* ws = (char*)d_ws;
    size_t off = 0;
    ushort_t* kb   = (ushort_t*)(ws + off); off += SZ_BF;   // K head-major [b,h][l][d]
    ushort_t* vt   = (ushort_t*)(ws + off); off += SZ_BF;   // V transposed  [b,h][d][l]
    ushort_t* qo   = (ushort_t*)(ws + off); off += SZ_BF;   // q / attn-out / ffn1
    ushort_t* hb   = (ushort_t*)(ws + off); off += SZ_HBF;  // hidden bf16
    ushort_t* at1  = (ushort_t*)(ws + off); off += SZ_HBF;
    ushort_t* at2  = (ushort_t*)(ws + off); off += SZ_HBF;
    ushort_t* proj = (ushort_t*)(ws + off); off += SZ_HBF;
    ushort_t* WtQ  = (ushort_t*)(ws + off); off += SZ_WQKV;
    ushort_t* WtK  = (ushort_t*)(ws + off); off += SZ_WQKV;
    ushort_t* WtV  = (ushort_t*)(ws + off); off += SZ_WQKV;
    ushort_t* WtO  = (ushort_t*)(ws + off); off += SZ_WQKV;
    ushort_t* Wt1  = (ushort_t*)(ws + off); off += SZ_W12;
    ushort_t* Wt2  = (ushort_t*)(ws + off); off += SZ_W12;
    if (ws_size < off) return;  // total == 188,743,680 B (same as passing R3/R5-R11)
    ushort_t* ffn1 = qo;        // alias: qo free after out-proj2

    dim3 blk(256);
    cvt_f32_bf16<<<MROWS * HID / 1024, blk, 0, stream>>>(hidden, hb);
    wtrans<<<dim3(HD / 32, HID / 32), blk, 0, stream>>>(Wq, WtQ, HID, HD);
    wtrans<<<dim3(HD / 32, HID / 32), blk, 0, stream>>>(Wk, WtK, HID, HD);
    wtrans<<<dim3(HD / 32, HID / 32), blk, 0, stream>>>(Wv, WtV, HID, HD);
    wtrans<<<dim3(HID / 32, HD / 32), blk, 0, stream>>>(Wo, WtO, HD, HID);
    wtrans<<<dim3(4 * HID / 32, HID / 32), blk, 0, stream>>>(W1, Wt1, HID, 4 * HID);
    wtrans<<<dim3(HID / 32, 4 * HID / 32), blk, 0, stream>>>(W2, Wt2, 4 * HID, HID);

    const dim3 gProj(HD / 128, MROWS / 128);
    const dim3 gOut(HID / 128, MROWS / 128);
    const dim3 gF1(4 * HID / 128, MROWS / 128);

    // K head-major; V transposed head-major (shared by both MHAs)
    gemm_bt<false, 1, false><<<gProj, blk, 0, stream>>>(hb, WtK, bk, kb, MROWS, HD, HID);
    gemm_bt<false, 2, false><<<gProj, blk, 0, stream>>>(hb, WtV, bv, vt, MROWS, HD, HID);

    // MHA1 (Q pre-scaled by CSCALE)
    gemm_bt<false, 0, true><<<gProj, blk, 0, stream>>>(hb, WtQ, bq, qo, MROWS, HD, HID);
    attn_mfma21<<<2 * BATCH * NH, 512, 0, stream>>>(qo, kb, vt, qo);
    gemm_bt<false, 0, false><<<gOut, blk, 0, stream>>>(qo, WtO, bo, proj, MROWS, HID, HD);
    residual_ln<float, ushort_t><<<MROWS, blk, 0, stream>>>(proj, hidden, at1);

    // MHA2 (q from attn1; pooled K/V rebuilt from same kb/vt)
    gemm_bt<false, 0, true><<<gProj, blk, 0, stream>>>(at1, WtQ, bq, qo, MROWS, HD, HID);
    attn_mfma21<<<2 * BATCH * NH, 512, 0, stream>>>(qo, kb, vt, qo);
    gemm_bt<false, 0, false><<<gOut, blk, 0, stream>>>(qo, WtO, bo, proj, MROWS, HID, HD);
    residual_ln<ushort_t, ushort_t><<<MROWS, blk, 0, stream>>>(proj, at1, at2);

    // FFN
    gemm_bt<true, 0, false><<<gF1, blk, 0, stream>>>(at2, Wt1, b1, ffn1, MROWS, 4 * HID, HID);
    gemm_bt<false, 0, false><<<gOut, blk, 0, stream>>>(ffn1, Wt2, b2, proj, MROWS, HID, 4 * HID);
    residual_ln<ushort_t, float><<<MROWS, blk, 0, stream>>>(proj, at2, out);
}

// Round 12
// 895.978 us; speedup vs baseline: 1.3020x; 1.0092x over previous
//
#include <hip/hip_runtime.h>
#include <hip/hip_bf16.h>
#include <cstdint>
#include <cstddef>

// Problem constants
#define BATCH 64
#define LSEQ 200
#define HID 256
#define NH 8
#define DH 256            // per-head dim = HID
#define HD (NH*DH)        // 2048
#define MROWS (BATCH*LSEQ)   // 12800
#define EPS 1e-5f
#define CSCALE 0.09014195f   // (1/sqrt(256)) * log2(e), folded into Q projection

typedef unsigned short ushort_t;
typedef __attribute__((ext_vector_type(8))) short bf16x8;         // MFMA A/B frag (4 VGPR)
typedef __attribute__((ext_vector_type(8))) unsigned short u16x8; // 16B of bf16
typedef __attribute__((ext_vector_type(4))) float f32x4;          // MFMA C/D frag

__device__ __forceinline__ float b2f(ushort_t u) {
    union { unsigned int i; float f; } c; c.i = ((unsigned int)u) << 16; return c.f;
}
__device__ __forceinline__ ushort_t f2b(float f) {
    __hip_bfloat16 h = __float2bfloat16(f);
    union { __hip_bfloat16 h; ushort_t u; } c; c.h = h; return c.u;
}
__device__ __forceinline__ float to_f32(float x) { return x; }
__device__ __forceinline__ float to_f32(ushort_t x) { return b2f(x); }
__device__ __forceinline__ void store_val(float* p, float v) { *p = v; }
__device__ __forceinline__ void store_val(ushort_t* p, float v) { *p = f2b(v); }

// packed bf16 max on 8 elements
__device__ __forceinline__ u16x8 bmax8(u16x8 a, u16x8 b) {
    union U { u16x8 v; __hip_bfloat162 h[4]; };
    U ua, ub, r; ua.v = a; ub.v = b;
    #pragma unroll
    for (int i = 0; i < 4; ++i) r.h[i] = __hmax2(ua.h[i], ub.h[i]);
    return r.v;
}

// async global->LDS, 16 bytes per lane (LDS dest = wave-uniform base + lane*16)
__device__ __forceinline__ void gll16(const void* g, void* l) {
    __builtin_amdgcn_global_load_lds(
        (const __attribute__((address_space(1))) unsigned int*)g,
        (__attribute__((address_space(3))) unsigned int*)l, 16, 0, 0);
}

// ================= bf16 MFMA GEMM:  C[M,N] = A[M,K] @ Bt[N,K]^T + bias =================
// 128x128 tile, BK=64 (v22: was 32 -- halves barriers/block; 32 MFMA per barrier pair),
// 4 waves (2x2 of 64x64), global_load_lds staging, XOR-swizzled LDS (phys chunk =
// logical ^ (row&7) over 8 chunks; 16-lane frag reads are 2-way = free).
// OMODE: 0 = row-major [m][n]; 1 = head-major [b][h][l][d]; 2 = transposed head-major
// [b][h][d][l] (row length LSEQ=200, 8B packed stores). Modes 1/2 require N==2048.
// SCALEC: multiply (acc+bias) by CSCALE (folds softmax scale*log2e into Q projection).
template<bool RELU, int OMODE, bool SCALEC>
__global__ __launch_bounds__(256) void gemm_bt(
    const ushort_t* __restrict__ A, const ushort_t* __restrict__ Bt,
    const float* __restrict__ bias, ushort_t* __restrict__ C,
    int M, int N, int K)
{
    __shared__ ushort_t As[128 * 64];     // 16 KB
    __shared__ ushort_t Bs[128 * 64];     // 16 KB
    const int t = threadIdx.x;
    const int m0 = blockIdx.y * 128, n0 = blockIdx.x * 128;
    const int wave = t >> 6, lane = t & 63;
    const int l15 = lane & 15, lq = lane >> 4;
    const int wr = wave >> 1, wc = wave & 1;

    f32x4 acc[4][4];
    #pragma unroll
    for (int i = 0; i < 4; ++i)
        #pragma unroll
        for (int j = 0; j < 4; ++j) acc[i][j] = (f32x4){0.f, 0.f, 0.f, 0.f};

    for (int k0 = 0; k0 < K; k0 += 64) {
        __syncthreads();
        #pragma unroll
        for (int i = 0; i < 4; ++i) {      // stage A (4 x 16B per thread)
            int li = i * 256 + t;
            int ml = li >> 3, cp = li & 7;
            int cg = cp ^ (ml & 7);
            gll16(A + (size_t)(m0 + ml) * K + k0 + cg * 8, &As[li * 8]);
        }
        #pragma unroll
        for (int i = 0; i < 4; ++i) {      // stage B
            int li = i * 256 + t;
            int nl = li >> 3, cp = li & 7;
            int cg = cp ^ (nl & 7);
            gll16(Bt + (size_t)(n0 + nl) * K + k0 + cg * 8, &Bs[li * 8]);
        }
        __syncthreads();
        #pragma unroll
        for (int ks = 0; ks < 2; ++ks) {   // two K=32 sub-steps per staged tile
            bf16x8 af[4], bfr[4];
            #pragma unroll
            for (int i = 0; i < 4; ++i) {
                int r = wr * 64 + i * 16 + l15;
                int pc = (ks * 4 + lq) ^ (r & 7);
                af[i] = *(const bf16x8*)&As[r * 64 + pc * 8];
            }
            #pragma unroll
            for (int j = 0; j < 4; ++j) {
                int r = wc * 64 + j * 16 + l15;
                int pc = (ks * 4 + lq) ^ (r & 7);
                bfr[j] = *(const bf16x8*)&Bs[r * 64 + pc * 8];
            }
            #pragma unroll
            for (int i = 0; i < 4; ++i)
                #pragma unroll
                for (int j = 0; j < 4; ++j)
                    acc[i][j] = __builtin_amdgcn_mfma_f32_16x16x32_bf16(af[i], bfr[j], acc[i][j], 0, 0, 0);
        }
    }
    // epilogue: C layout col=lane&15, row=4*quad+e
    if (OMODE == 2) {
        #pragma unroll
        for (int i = 0; i < 4; ++i) {
            int mbase = m0 + wr * 64 + i * 16 + 4 * lq;         // 4-aligned; 200%4==0
            int bb = (int)(((unsigned)mbase * 5243u) >> 20);    // mbase/200
            int ll = mbase - bb * 200;
            #pragma unroll
            for (int j = 0; j < 4; ++j) {
                int n = n0 + wc * 64 + j * 16 + l15;
                float bsv = bias[n];
                ushort4 o4;
                o4.x = f2b(acc[i][j][0] + bsv); o4.y = f2b(acc[i][j][1] + bsv);
                o4.z = f2b(acc[i][j][2] + bsv); o4.w = f2b(acc[i][j][3] + bsv);
                size_t addr = ((size_t)(bb * NH + (n >> 8)) * 256 + (n & 255)) * LSEQ + ll;
                *(ushort4*)&C[addr] = o4;
            }
        }
    } else {
        #pragma unroll
        for (int i = 0; i < 4; ++i) {
            #pragma unroll
            for (int e = 0; e < 4; ++e) {
                int m = m0 + wr * 64 + i * 16 + 4 * lq + e;
                #pragma unroll
                for (int j = 0; j < 4; ++j) {
                    int n = n0 + wc * 64 + j * 16 + l15;
                    float v = acc[i][j][e] + bias[n];
                    if (RELU) v = fmaxf(v, 0.f);
                    if (SCALEC) v *= CSCALE;
                    if (OMODE == 1) {
                        int bb = (int)(((unsigned)m * 5243u) >> 20);
                        int ll = m - bb * 200;
                        size_t addr = ((((size_t)(bb * NH + (n >> 8))) * LSEQ + ll) << 8) + (n & 255);
                        C[addr] = f2b(v);
                    } else {
                        C[(size_t)m * N + n] = f2b(v);
                    }
                }
            }
        }
    }
}

// ================= fused area-attention v21 (v16 skeleton + sigma-swap slots) ========
// Proven at 275 us/dispatch. Raw-V PV via P aggregation, operand-swapped QK^T,
// in-register P, single Ks buffer, in-place K RMW, sigma-swap slot layout
// (start = lq*16+4*ms+e, shift1 = ONE shuffle, full-16B-chunk V stores).
__global__ __launch_bounds__(512, 2) void attn_mfma21(
    const ushort_t* __restrict__ Q, const ushort_t* __restrict__ Khm,
    const ushort_t* __restrict__ Vt, ushort_t* __restrict__ O)  // O may alias Q
{
    const int id = blockIdx.x;
    const int xcd = id & 7, slot_ = id >> 3;    // 1024 blocks: 8 xcd x 128 slots
    const int qt = slot_ & 1;
    const int bh = ((slot_ >> 1) << 3) + xcd;   // both q-blocks of bh share an XCD
    const int b = bh >> 3, h = bh & 7;
    const int q0 = qt * 128;
    const int t = threadIdx.x;
    const int wave = t >> 6, lane = t & 63;
    const int l15 = lane & 15, lq = lane >> 4;

    __shared__ ushort_t Ks[64 * 256];      // pooled K (sigma rows), chunk ^ (m&15), 32 KB
    __shared__ ushort_t Vs[256 * 64];      // V [d][kpos], chunk ^ (d&7), 32 KB

    const ushort_t* kbh = Khm + (size_t)bh * LSEQ * DH;
    const ushort_t* vtb = Vt + (size_t)bh * DH * LSEQ;   // [d][l]
    const ushort_t* qbh = Q + ((size_t)b * LSEQ) * HD + h * DH;
    const int qrow = q0 + wave * 16 + l15;

    // Q fragments (row=lane&15, k=8*quad+j); pre-scaled by CSCALE in GEMM.
    bf16x8 qf[8];
    if (qrow < LSEQ) {
        const ushort_t* qp = qbh + (size_t)qrow * HD + 8 * lq;
        #pragma unroll
        for (int g = 0; g < 8; ++g) qf[g] = *(const bf16x8*)(qp + 32 * g);
    } else {
        bf16x8 zf = {0,0,0,0,0,0,0,0};
        #pragma unroll
        for (int g = 0; g < 8; ++g) qf[g] = zf;
    }

    f32x4 oacc[16];
    #pragma unroll
    for (int i = 0; i < 16; ++i) oacc[i] = (f32x4){0.f, 0.f, 0.f, 0.f};
    float l4[4];
    #pragma unroll
    for (int e = 0; e < 4; ++e) l4[e] = 0.f;
    float carry[4];                        // Pagg spill into next tile's starts 0..3
    #pragma unroll
    for (int e = 0; e < 4; ++e) carry[e] = 0.f;
    float Pagg[4][4];

    // staging roles for 512 threads
    const int dc = t & 31, mb = t >> 5;      // K: lane->d-chunk, thread->4 positions
    const int vd = t >> 1, vh = t & 1;       // V: thread -> d row, half (4 chunks each)
    // sigma: physical position m = mb + 16*k4 holds pooled-K for start srow + 4*k4
    const int srow = ((mb >> 2) << 4) + (mb & 3);

    auto kOff = [&](int k4) {
        int m = mb + 16 * k4;
        return m * 256 + ((dc ^ (m & 15)) * 8);
    };
    auto storeVchunk = [&](int kc, u16x8 val) {   // full 16B, kpos chunk kc
        *(u16x8*)&Vs[vd * 64 + ((kc ^ (vd & 7)) * 8)] = val;
    };

    // QK on Ks -> sacc (swapped operands): sacc[ms][e] = S^T[phys row][q=l15]
    auto qk = [&](f32x4* sacc) {
        __builtin_amdgcn_s_setprio(1);
        #pragma unroll
        for (int ms = 0; ms < 4; ++ms) {
            f32x4 s = (f32x4){0.f, 0.f, 0.f, 0.f};
            const int row = ms * 16 + l15;
            #pragma unroll
            for (int g = 0; g < 8; ++g) {
                const int phys = (lq + 4 * g) ^ l15;
                s = __builtin_amdgcn_mfma_f32_16x16x32_bf16(
                        *(const bf16x8*)&Ks[row * 256 + phys * 8], qf[g], s, 0, 0, 0);
            }
            sacc[ms] = s;
        }
        __builtin_amdgcn_s_setprio(0);
    };

    // softmax for one class under start = lq*16 + 4*ms + e; shift1 = ONE shuffle
    auto smClass = [&](const f32x4* sacc, int cls) {
        float Pc[4][4];
        #pragma unroll
        for (int ms = 0; ms < 4; ++ms)
            #pragma unroll
            for (int e = 0; e < 4; ++e) {
                float pe = __builtin_exp2f(sacc[ms][e]);
                l4[e] += pe;
                Pc[ms][e] = pe;
                Pagg[ms][e] += pe;
            }
        if (cls >= 1) {
            float T[4][4];
            #pragma unroll
            for (int ms = 0; ms < 4; ++ms)
                #pragma unroll
                for (int e = 0; e < 4; ++e) T[ms][e] = Pc[ms][e];
            #pragma unroll
            for (int u = 1; u <= 4; ++u) {
                if (u <= cls) {
                    float up = __shfl(T[3][3], (lane - 16) & 63);
                    #pragma unroll
                    for (int ms = 3; ms >= 0; --ms) {
                        float nv = (ms > 0) ? T[ms - 1][3] : ((lq > 0) ? up : 0.f);
                        T[ms][3] = T[ms][2]; T[ms][2] = T[ms][1]; T[ms][1] = T[ms][0];
                        T[ms][0] = nv;
                    }
                    #pragma unroll
                    for (int ms = 0; ms < 4; ++ms)
                        #pragma unroll
                        for (int e = 0; e < 4; ++e) Pagg[ms][e] += T[ms][e];
                }
            }
        }
        // carry-out: starts 60..63 = (lq==3, ms==3, e)
        #pragma unroll
        for (int i = 0; i < 4; ++i)
            #pragma unroll
            for (int e = 0; e < 4; ++e)
                if (cls >= 4 + i - e) carry[i] += Pc[3][e];
    };

    // PV over Vs with A-frags from float P[4][4]
    auto pv32 = [&](const float P[4][4]) {
        unsigned int w[8];
        #pragma unroll
        for (int ms = 0; ms < 4; ++ms) {
            asm("v_cvt_pk_bf16_f32 %0, %1, %2" : "=v"(w[2*ms])   : "v"(P[ms][0]), "v"(P[ms][1]));
            asm("v_cvt_pk_bf16_f32 %0, %1, %2" : "=v"(w[2*ms+1]) : "v"(P[ms][2]), "v"(P[ms][3]));
        }
        union FR { unsigned int u[4]; bf16x8 v; };
        FR f0, f1;
        f0.u[0] = w[0]; f0.u[1] = w[1]; f0.u[2] = w[2]; f0.u[3] = w[3];
        f1.u[0] = w[4]; f1.u[1] = w[5]; f1.u[2] = w[6]; f1.u[3] = w[7];
        const bf16x8 pf0 = f0.v, pf1 = f1.v;
        __builtin_amdgcn_s_setprio(1);
        #pragma unroll
        for (int dt = 0; dt < 16; ++dt) {
            const int d = dt * 16 + l15;
            const int p0 = lq ^ (d & 7);
            const int p1 = (lq + 4) ^ (d & 7);
            oacc[dt] = __builtin_amdgcn_mfma_f32_16x16x32_bf16(
                           pf0, *(const bf16x8*)&Vs[d * 64 + p0 * 8], oacc[dt], 0, 0, 0);
            oacc[dt] = __builtin_amdgcn_mfma_f32_16x16x32_bf16(
                           pf1, *(const bf16x8*)&Vs[d * 64 + p1 * 8], oacc[dt], 0, 0, 0);
        }
        __builtin_amdgcn_s_setprio(0);
    };

    // ---- 3 full tiles x 5 QK classes + 1 PV each ----
    for (int ti = 0; ti < 3; ++ti) {
        const int st0 = ti * 64;
        // carry-in: prev tile's spill -> this tile's starts 0..3 (lq==0, ms==0)
        {
            float pin0 = __shfl(carry[0], (lane + 48) & 63);
            float pin1 = __shfl(carry[1], (lane + 48) & 63);
            float pin2 = __shfl(carry[2], (lane + 48) & 63);
            float pin3 = __shfl(carry[3], (lane + 48) & 63);
            #pragma unroll
            for (int ms = 0; ms < 4; ++ms)
                #pragma unroll
                for (int e = 0; e < 4; ++e) Pagg[ms][e] = 0.f;
            if (lq == 0) {
                Pagg[0][0] = pin0; Pagg[0][1] = pin1; Pagg[0][2] = pin2; Pagg[0][3] = pin3;
            }
            #pragma unroll
            for (int e = 0; e < 4; ++e) carry[e] = 0.f;
        }
        #pragma unroll
        for (int cls = 0; cls < 5; ++cls) {
            // prefetch sigma-swapped K rows (+cls); raw V rows at cls==0 (once/tile)
            u16x8 kf[4];
            #pragma unroll
            for (int k4 = 0; k4 < 4; ++k4)
                kf[k4] = *(const u16x8*)(kbh + (size_t)(st0 + srow + 4 * k4 + cls) * DH + dc * 8);
            u16x8 vc[4];
            if (cls == 0) {
                const ushort_t* vrow = vtb + (size_t)vd * LSEQ + st0 + vh * 32;
                #pragma unroll
                for (int c2 = 0; c2 < 4; ++c2) vc[c2] = *(const u16x8*)(vrow + c2 * 8);
            }
            __syncthreads();   // previous step's frag reads done

            // K pooled: running max in Ks (in-place RMW), 4 positions/thread
            #pragma unroll
            for (int k4 = 0; k4 < 4; ++k4) {
                ushort_t* kp = &Ks[kOff(k4)];
                *(u16x8*)kp = (cls == 0) ? kf[k4] : bmax8(*(const u16x8*)kp, kf[k4]);
            }
            // raw V staged once per tile: natural chunk cg -> kpos chunk (cg&1)*4+(cg>>1)
            if (cls == 0) {
                #pragma unroll
                for (int cl = 0; cl < 4; ++cl) {
                    const int cg = vh * 4 + cl;
                    storeVchunk((cg & 1) * 4 + (cg >> 1), vc[cl]);
                }
            }
            __syncthreads();

            f32x4 sacc[4];
            qk(sacc);
            smClass(sacc, cls);
            if (cls == 4) pv32(Pagg);   // one PV over raw V for the whole tile
        }
    }

    // ---- tail step: pooled tail K (PHYSICAL layout) + tail V via kpos table ----
    {
        __syncthreads();   // previous step's frag reads (incl. PV) done
        // K: threads with mb<8 cover physical slots k8*8+mb (cls=k8, off=mb)
        if (mb < 8) {
            u16x8 krun = *(const u16x8*)(kbh + (size_t)(192 + mb) * DH + dc * 8);
            const u16x8 kz = {0,0,0,0,0,0,0,0};
            #pragma unroll
            for (int k8 = 0; k8 < 8; ++k8) {
                const bool vv = (k8 <= 4) && (mb <= 7 - k8);
                if (k8 > 0 && vv)
                    krun = bmax8(krun, *(const u16x8*)(kbh + (size_t)(192 + mb + k8) * DH + dc * 8));
                int slot = k8 * 8 + mb;
                *(u16x8*)&Ks[slot * 256 + ((dc ^ (slot & 15)) * 8)] = vv ? krun : kz;
            }
        }
        // V: kpos chunk kc holds (cls,off) per derived map; kc==6 o<4 = raw V[192..195]
        {
            u16x8 v0 = *(const u16x8*)(vtb + (size_t)vd * LSEQ + 192);
            float f[8];
            #pragma unroll
            for (int e = 0; e < 8; ++e) f[e] = b2f(v0[e]);
            #pragma unroll
            for (int ck = 0; ck < 4; ++ck) {
                const int kc = vh * 4 + ck;
                const int cls_lo = 4 * (kc >> 2) + ((kc >> 1) & 1);
                const int offb = 4 * (kc & 1);
                u16x8 ov;
                #pragma unroll
                for (int o = 0; o < 8; ++o) {
                    const int cls = cls_lo + 2 * (o >> 2);
                    const int off = offb + (o & 3);
                    ushort_t val = 0;
                    if (cls <= 4 && off <= 7 - cls) {
                        float a = 0.f;
                        #pragma unroll
                        for (int u = 0; u <= 4; ++u)
                            if (u <= cls) a += f[off + u];
                        val = f2b(a);
                    }
                    if (kc == 6 && o < 4) val = v0[o];   // raw V for carry slots
                    ov[o] = val;
                }
                storeVchunk(kc, ov);
            }
        }
        __syncthreads();

        // tail compute: QK (physical slots), softmax + carry injection, PV
        f32x4 sacc[4];
        qk(sacc);
        float pullc[4];
        #pragma unroll
        for (int e = 0; e < 4; ++e) pullc[e] = __shfl(carry[e], (lane + 16) & 63);
        float Pt[4][4];
        #pragma unroll
        for (int ms = 0; ms < 4; ++ms)
            #pragma unroll
            for (int e = 0; e < 4; ++e) {
                const int slot = ms * 16 + 4 * lq + e;   // PHYSICAL slot = 8*cls + off
                const bool inval = ((slot & 7) > 7 - (slot >> 3)) || ((slot >> 3) > 4);
                float pe = __builtin_exp2f(inval ? -1e30f : sacc[ms][e]);
                l4[e] += pe;           // carry slots are invalid -> pe==0 here
                float pfrag = pe;
                if (ms == 2 && lq == 2) pfrag = pullc[e];   // pairs with raw V in kc 6
                Pt[ms][e] = pfrag;
            }
        pv32(Pt);
    }

    // epilogue: reduce l over the 4 lq groups, invert, redistribute
    float l_part = (l4[0] + l4[1]) + (l4[2] + l4[3]);
    l_part += __shfl_xor(l_part, 16);
    l_part += __shfl_xor(l_part, 32);
    const float inv = 1.f / l_part;

    ushort_t* ob = O + ((size_t)b * LSEQ) * HD + h * DH;
    #pragma unroll
    for (int e = 0; e < 4; ++e) {
        const int q = q0 + wave * 16 + 4 * lq + e;
        const float linv = __shfl(inv, 4 * lq + e);
        if (q < LSEQ) {
            #pragma unroll
            for (int dt = 0; dt < 16; ++dt)
                ob[(size_t)q * HD + dt * 16 + l15] = f2b(oacc[dt][e] * linv);
        }
    }
}

// ================= residual + LayerNorm: Out = LN(bf16 X + R) =================
template<typename TR, typename TO>
__global__ __launch_bounds__(256) void residual_ln(
    const ushort_t* __restrict__ X, const TR* __restrict__ R, TO* __restrict__ Out)
{
    const int row = blockIdx.x;
    const int t = threadIdx.x;
    const size_t base = (size_t)row * HID;
    float v = b2f(X[base + t]) + to_f32(R[base + t]);
    float s = v, q = v * v;
    #pragma unroll
    for (int o = 32; o > 0; o >>= 1) {
        s += __shfl_xor(s, o, 64);
        q += __shfl_xor(q, o, 64);
    }
    __shared__ float ss[4], sq[4];
    const int wave = t >> 6, lane = t & 63;
    if (lane == 0) { ss[wave] = s; sq[wave] = q; }
    __syncthreads();
    s = ss[0] + ss[1] + ss[2] + ss[3];
    q = sq[0] + sq[1] + sq[2] + sq[3];
    float mean = s * (1.f / HID);
    float var  = q * (1.f / HID) - mean * mean;
    store_val(&Out[base + t], (v - mean) * rsqrtf(var + EPS));
}

// ================= converts =================
__global__ __launch_bounds__(256) void cvt_f32_bf16(const float* __restrict__ in,
                                                    ushort_t* __restrict__ out) {
    const int i = (blockIdx.x * 256 + threadIdx.x) * 4;
    float4 v = *(const float4*)(in + i);
    ushort4 o;
    o.x = f2b(v.x); o.y = f2b(v.y); o.z = f2b(v.z); o.w = f2b(v.w);
    *(ushort4*)(out + i) = o;
}

// W[K,N] f32 -> Wt[N,K] bf16
__global__ __launch_bounds__(256) void wtrans(const float* __restrict__ W,
                                              ushort_t* __restrict__ Wt, int K, int N) {
    __shared__ float tile[32][33];
    const int t = threadIdx.x;
    const int tx = t & 31, ty = t >> 5;
    const int n0 = blockIdx.x * 32, k0 = blockIdx.y * 32;
    #pragma unroll
    for (int s = 0; s < 4; ++s)
        tile[ty + 8 * s][tx] = W[(size_t)(k0 + ty + 8 * s) * N + n0 + tx];
    __syncthreads();
    #pragma unroll
    for (int s = 0; s < 4; ++s)
        Wt[(size_t)(n0 + ty + 8 * s) * K + k0 + tx] = f2b(tile[tx][ty + 8 * s]);
}

// ================= launch =================
extern "C" void kernel_launch(void* const* d_in, const int* in_sizes, int n_in,
                              void* d_out, int out_size, void* d_ws, size_t ws_size,
                              hipStream_t stream) {
    const float* hidden = (const float*)d_in[1];
    const float* Wq = (const float*)d_in[2];  const float* bq = (const float*)d_in[3];
    const float* Wk = (const float*)d_in[4];  const float* bk = (const float*)d_in[5];
    const float* Wv = (const float*)d_in[6];  const float* bv = (const float*)d_in[7];
    const float* Wo = (const float*)d_in[8];  const float* bo = (const float*)d_in[9];
    const float* W1 = (const float*)d_in[10]; const float* b1 = (const float*)d_in[11];
    const float* W2 = (const float*)d_in[12]; const float* b2 = (const float*)d_in[13];
    float* out = (float*)d_out;

    constexpr size_t SZ_BF   = (size_t)MROWS * HD * 2;      // 52,428,800
    constexpr size_t SZ_HBF  = (size_t)MROWS * HID * 2;     // 6,553,600
    constexpr size_t SZ_WQKV = (size_t)HID * HD * 2;        // 1,048,576
    constexpr size_t SZ_W12  = (size_t)HID * 4 * HID * 2;   // 524,288
    char* ws = (char*)d_ws;
    size_t off = 0;
    ushort_t* kb   = (ushort_t*)(ws + off); off += SZ_BF;   // K head-major [b,h][l][d]
    ushort_t* vt   = (ushort_t*)(ws + off); off += SZ_BF;   // V transposed  [b,h][d][l]
    ushort_t* qo   = (ushort_t*)(ws + off); off += SZ_BF;   // q / attn-out / ffn1
    ushort_t* hb   = (ushort_t*)(ws + off); off += SZ_HBF;  // hidden bf16
    ushort_t* at1  = (ushort_t*)(ws + off); off += SZ_HBF;
    ushort_t* at2  = (ushort_t*)(ws + off); off += SZ_HBF;
    ushort_t* proj = (ushort_t*)(ws + off); off += SZ_HBF;
    ushort_t* WtQ  = (ushort_t*)(ws + off); off += SZ_WQKV;
    ushort_t* WtK  = (ushort_t*)(ws + off); off += SZ_WQKV;
    ushort_t* WtV  = (ushort_t*)(ws + off); off += SZ_WQKV;
    ushort_t* WtO  = (ushort_t*)(ws + off); off += SZ_WQKV;
    ushort_t* Wt1  = (ushort_t*)(ws + off); off += SZ_W12;
    ushort_t* Wt2  = (ushort_t*)(ws + off); off += SZ_W12;
    if (ws_size < off) return;  // total == 188,743,680 B (same as passing R3/R5-R11)
    ushort_t* ffn1 = qo;        // alias: qo free after out-proj2

    dim3 blk(256);
    cvt_f32_bf16<<<MROWS * HID / 1024, blk, 0, stream>>>(hidden, hb);
    wtrans<<<dim3(HD / 32, HID / 32), blk, 0, stream>>>(Wq, WtQ, HID, HD);
    wtrans<<<dim3(HD / 32, HID / 32), blk, 0, stream>>>(Wk, WtK, HID, HD);
    wtrans<<<dim3(HD / 32, HID / 32), blk, 0, stream>>>(Wv, WtV, HID, HD);
    wtrans<<<dim3(HID / 32, HD / 32), blk, 0, stream>>>(Wo, WtO, HD, HID);
    wtrans<<<dim3(4 * HID / 32, HID / 32), blk, 0, stream>>>(W1, Wt1, HID, 4 * HID);
    wtrans<<<dim3(HID / 32, 4 * HID / 32), blk, 0, stream>>>(W2, Wt2, 4 * HID, HID);

    const dim3 gProj(HD / 128, MROWS / 128);
    const dim3 gOut(HID / 128, MROWS / 128);
    const dim3 gF1(4 * HID / 128, MROWS / 128);

    // K head-major; V transposed head-major (shared by both MHAs)
    gemm_bt<false, 1, false><<<gProj, blk, 0, stream>>>(hb, WtK, bk, kb, MROWS, HD, HID);
    gemm_bt<false, 2, false><<<gProj, blk, 0, stream>>>(hb, WtV, bv, vt, MROWS, HD, HID);

    // MHA1 (Q pre-scaled by CSCALE)
    gemm_bt<false, 0, true><<<gProj, blk, 0, stream>>>(hb, WtQ, bq, qo, MROWS, HD, HID);
    attn_mfma21<<<2 * BATCH * NH, 512, 0, stream>>>(qo, kb, vt, qo);
    gemm_bt<false, 0, false><<<gOut, blk, 0, stream>>>(qo, WtO, bo, proj, MROWS, HID, HD);
    residual_ln<float, ushort_t><<<MROWS, blk, 0, stream>>>(proj, hidden, at1);

    // MHA2 (q from attn1; pooled K/V rebuilt from same kb/vt)
    gemm_bt<false, 0, true><<<gProj, blk, 0, stream>>>(at1, WtQ, bq, qo, MROWS, HD, HID);
    attn_mfma21<<<2 * BATCH * NH, 512, 0, stream>>>(qo, kb, vt, qo);
    gemm_bt<false, 0, false><<<gOut, blk, 0, stream>>>(qo, WtO, bo, proj, MROWS, HID, HD);
    residual_ln<ushort_t, ushort_t><<<MROWS, blk, 0, stream>>>(proj, at1, at2);

    // FFN
    gemm_bt<true, 0, false><<<gF1, blk, 0, stream>>>(at2, Wt1, b1, ffn1, MROWS, 4 * HID, HID);
    gemm_bt<false, 0, false><<<gOut, blk, 0, stream>>>(ffn1, Wt2, b2, proj, MROWS, HID, 4 * HID);
    residual_ln<ushort_t, float><<<MROWS, blk, 0, stream>>>(proj, at2, out);
}

// Round 13
// 833.877 us; speedup vs baseline: 1.3990x; 1.0745x over previous
//
#include <hip/hip_runtime.h>
#include <hip/hip_bf16.h>
#include <cstdint>
#include <cstddef>

// Problem constants
#define BATCH 64
#define LSEQ 200
#define HID 256
#define NH 8
#define DH 256            // per-head dim = HID
#define HD (NH*DH)        // 2048
#define MROWS (BATCH*LSEQ)   // 12800
#define EPS 1e-5f
#define CSCALE 0.09014195f   // (1/sqrt(256)) * log2(e), folded into Q projection

typedef unsigned short ushort_t;
typedef __attribute__((ext_vector_type(8))) short bf16x8;         // MFMA A/B frag (4 VGPR)
typedef __attribute__((ext_vector_type(8))) unsigned short u16x8; // 16B of bf16
typedef __attribute__((ext_vector_type(4))) float f32x4;          // MFMA C/D frag

__device__ __forceinline__ float b2f(ushort_t u) {
    union { unsigned int i; float f; } c; c.i = ((unsigned int)u) << 16; return c.f;
}
__device__ __forceinline__ ushort_t f2b(float f) {
    __hip_bfloat16 h = __float2bfloat16(f);
    union { __hip_bfloat16 h; ushort_t u; } c; c.h = h; return c.u;
}
__device__ __forceinline__ float to_f32(float x) { return x; }
__device__ __forceinline__ float to_f32(ushort_t x) { return b2f(x); }
__device__ __forceinline__ void store_val(float* p, float v) { *p = v; }
__device__ __forceinline__ void store_val(ushort_t* p, float v) { *p = f2b(v); }

// packed bf16 max on 8 elements
__device__ __forceinline__ u16x8 bmax8(u16x8 a, u16x8 b) {
    union U { u16x8 v; __hip_bfloat162 h[4]; };
    U ua, ub, r; ua.v = a; ub.v = b;
    #pragma unroll
    for (int i = 0; i < 4; ++i) r.h[i] = __hmax2(ua.h[i], ub.h[i]);
    return r.v;
}

// async global->LDS, 16 bytes per lane (LDS dest = wave-uniform base + lane*16)
__device__ __forceinline__ void gll16(const void* g, void* l) {
    __builtin_amdgcn_global_load_lds(
        (const __attribute__((address_space(1))) unsigned int*)g,
        (__attribute__((address_space(3))) unsigned int*)l, 16, 0, 0);
}

// ================= bf16 MFMA GEMM:  C[M,N] = A[M,K] @ Bt[N,K]^T + bias =================
// 128x128 tile, BK=64, 4 waves (2x2 of 64x64), global_load_lds staging, XOR-swizzled
// LDS (phys chunk = logical ^ (row&7)). Row-major output only (OMODE folded away; the
// head-major/transposed outputs moved to gemm_qkv).
template<bool RELU, bool SCALEC>
__global__ __launch_bounds__(256) void gemm_bt(
    const ushort_t* __restrict__ A, const ushort_t* __restrict__ Bt,
    const float* __restrict__ bias, ushort_t* __restrict__ C,
    int M, int N, int K)
{
    __shared__ ushort_t As[128 * 64];
    __shared__ ushort_t Bs[128 * 64];
    const int t = threadIdx.x;
    const int m0 = blockIdx.y * 128, n0 = blockIdx.x * 128;
    const int wave = t >> 6, lane = t & 63;
    const int l15 = lane & 15, lq = lane >> 4;
    const int wr = wave >> 1, wc = wave & 1;

    f32x4 acc[4][4];
    #pragma unroll
    for (int i = 0; i < 4; ++i)
        #pragma unroll
        for (int j = 0; j < 4; ++j) acc[i][j] = (f32x4){0.f, 0.f, 0.f, 0.f};

    for (int k0 = 0; k0 < K; k0 += 64) {
        __syncthreads();
        #pragma unroll
        for (int i = 0; i < 4; ++i) {      // stage A (4 x 16B per thread)
            int li = i * 256 + t;
            int ml = li >> 3, cp = li & 7;
            int cg = cp ^ (ml & 7);
            gll16(A + (size_t)(m0 + ml) * K + k0 + cg * 8, &As[li * 8]);
        }
        #pragma unroll
        for (int i = 0; i < 4; ++i) {      // stage B
            int li = i * 256 + t;
            int nl = li >> 3, cp = li & 7;
            int cg = cp ^ (nl & 7);
            gll16(Bt + (size_t)(n0 + nl) * K + k0 + cg * 8, &Bs[li * 8]);
        }
        __syncthreads();
        #pragma unroll
        for (int ks = 0; ks < 2; ++ks) {   // two K=32 sub-steps per staged tile
            bf16x8 af[4], bfr[4];
            #pragma unroll
            for (int i = 0; i < 4; ++i) {
                int r = wr * 64 + i * 16 + l15;
                int pc = (ks * 4 + lq) ^ (r & 7);
                af[i] = *(const bf16x8*)&As[r * 64 + pc * 8];
            }
            #pragma unroll
            for (int j = 0; j < 4; ++j) {
                int r = wc * 64 + j * 16 + l15;
                int pc = (ks * 4 + lq) ^ (r & 7);
                bfr[j] = *(const bf16x8*)&Bs[r * 64 + pc * 8];
            }
            #pragma unroll
            for (int i = 0; i < 4; ++i)
                #pragma unroll
                for (int j = 0; j < 4; ++j)
                    acc[i][j] = __builtin_amdgcn_mfma_f32_16x16x32_bf16(af[i], bfr[j], acc[i][j], 0, 0, 0);
        }
    }
    #pragma unroll
    for (int i = 0; i < 4; ++i) {
        #pragma unroll
        for (int e = 0; e < 4; ++e) {
            int m = m0 + wr * 64 + i * 16 + 4 * lq + e;
            #pragma unroll
            for (int j = 0; j < 4; ++j) {
                int n = n0 + wc * 64 + j * 16 + l15;
                float v = acc[i][j][e] + bias[n];
                if (RELU) v = fmaxf(v, 0.f);
                if (SCALEC) v *= CSCALE;
                C[(size_t)m * N + n] = f2b(v);
            }
        }
    }
}

// ================= fused QKV projection (v23) =================
// One GEMM over N = 3*2048: Bt = [WtQ; WtK; WtV] (contiguous in ws). Segment
// (block-uniform, seg = n0>>11) selects the validated epilogue path:
//   seg0: Q row-major * CSCALE -> Cq; seg1: K head-major -> Ck;
//   seg2: V transposed head-major -> Cv (8B packed stores).
__global__ __launch_bounds__(256) void gemm_qkv(
    const ushort_t* __restrict__ A, const ushort_t* __restrict__ Bt,
    const float* __restrict__ bq, const float* __restrict__ bk,
    const float* __restrict__ bv,
    ushort_t* __restrict__ Cq, ushort_t* __restrict__ Ck, ushort_t* __restrict__ Cv)
{
    constexpr int K = HID;                 // 256
    __shared__ ushort_t As[128 * 64];
    __shared__ ushort_t Bs[128 * 64];
    const int t = threadIdx.x;
    const int m0 = blockIdx.y * 128, n0 = blockIdx.x * 128;
    const int wave = t >> 6, lane = t & 63;
    const int l15 = lane & 15, lq = lane >> 4;
    const int wr = wave >> 1, wc = wave & 1;

    f32x4 acc[4][4];
    #pragma unroll
    for (int i = 0; i < 4; ++i)
        #pragma unroll
        for (int j = 0; j < 4; ++j) acc[i][j] = (f32x4){0.f, 0.f, 0.f, 0.f};

    for (int k0 = 0; k0 < K; k0 += 64) {
        __syncthreads();
        #pragma unroll
        for (int i = 0; i < 4; ++i) {
            int li = i * 256 + t;
            int ml = li >> 3, cp = li & 7;
            int cg = cp ^ (ml & 7);
            gll16(A + (size_t)(m0 + ml) * K + k0 + cg * 8, &As[li * 8]);
        }
        #pragma unroll
        for (int i = 0; i < 4; ++i) {
            int li = i * 256 + t;
            int nl = li >> 3, cp = li & 7;
            int cg = cp ^ (nl & 7);
            gll16(Bt + (size_t)(n0 + nl) * K + k0 + cg * 8, &Bs[li * 8]);
        }
        __syncthreads();
        #pragma unroll
        for (int ks = 0; ks < 2; ++ks) {
            bf16x8 af[4], bfr[4];
            #pragma unroll
            for (int i = 0; i < 4; ++i) {
                int r = wr * 64 + i * 16 + l15;
                int pc = (ks * 4 + lq) ^ (r & 7);
                af[i] = *(const bf16x8*)&As[r * 64 + pc * 8];
            }
            #pragma unroll
            for (int j = 0; j < 4; ++j) {
                int r = wc * 64 + j * 16 + l15;
                int pc = (ks * 4 + lq) ^ (r & 7);
                bfr[j] = *(const bf16x8*)&Bs[r * 64 + pc * 8];
            }
            #pragma unroll
            for (int i = 0; i < 4; ++i)
                #pragma unroll
                for (int j = 0; j < 4; ++j)
                    acc[i][j] = __builtin_amdgcn_mfma_f32_16x16x32_bf16(af[i], bfr[j], acc[i][j], 0, 0, 0);
        }
    }

    const int seg = n0 >> 11;              // 0=Q, 1=K, 2=V (block-uniform)
    const int nb = n0 & 2047;              // segment-local n0
    if (seg == 2) {
        // V transposed head-major [b,h][d][l]; 200%4==0 so mbase 4-aligned rows pack
        #pragma unroll
        for (int i = 0; i < 4; ++i) {
            int mbase = m0 + wr * 64 + i * 16 + 4 * lq;
            int bb = (int)(((unsigned)mbase * 5243u) >> 20);    // mbase/200
            int ll = mbase - bb * 200;
            #pragma unroll
            for (int j = 0; j < 4; ++j) {
                int nn = nb + wc * 64 + j * 16 + l15;
                float bsv = bv[nn];
                ushort4 o4;
                o4.x = f2b(acc[i][j][0] + bsv); o4.y = f2b(acc[i][j][1] + bsv);
                o4.z = f2b(acc[i][j][2] + bsv); o4.w = f2b(acc[i][j][3] + bsv);
                size_t addr = ((size_t)(bb * NH + (nn >> 8)) * 256 + (nn & 255)) * LSEQ + ll;
                *(ushort4*)&Cv[addr] = o4;
            }
        }
    } else if (seg == 1) {
        // K head-major [b,h][l][d]
        #pragma unroll
        for (int i = 0; i < 4; ++i) {
            #pragma unroll
            for (int e = 0; e < 4; ++e) {
                int m = m0 + wr * 64 + i * 16 + 4 * lq + e;
                int bb = (int)(((unsigned)m * 5243u) >> 20);
                int ll = m - bb * 200;
                #pragma unroll
                for (int j = 0; j < 4; ++j) {
                    int nn = nb + wc * 64 + j * 16 + l15;
                    float v = acc[i][j][e] + bk[nn];
                    size_t addr = ((((size_t)(bb * NH + (nn >> 8))) * LSEQ + ll) << 8) + (nn & 255);
                    Ck[addr] = f2b(v);
                }
            }
        }
    } else {
        // Q row-major [m][2048], pre-scaled by CSCALE
        #pragma unroll
        for (int i = 0; i < 4; ++i) {
            #pragma unroll
            for (int e = 0; e < 4; ++e) {
                int m = m0 + wr * 64 + i * 16 + 4 * lq + e;
                #pragma unroll
                for (int j = 0; j < 4; ++j) {
                    int nn = nb + wc * 64 + j * 16 + l15;
                    float v = (acc[i][j][e] + bq[nn]) * CSCALE;
                    Cq[(size_t)m * HD + nn] = f2b(v);
                }
            }
        }
    }
}

// ================= 64-row GEMM for N=256 outputs (v23) =================
// BM=64, BN=128, BK=64; 4 waves as 2x2 of 32x64. Doubles the grid for the
// undersubscribed out-proj/FFN2 dispatches (200 -> 400 blocks). Row-major out.
__global__ __launch_bounds__(256) void gemm_bt64(
    const ushort_t* __restrict__ A, const ushort_t* __restrict__ Bt,
    const float* __restrict__ bias, ushort_t* __restrict__ C,
    int M, int N, int K)
{
    __shared__ ushort_t As[64 * 64];       // 8 KB
    __shared__ ushort_t Bs[128 * 64];      // 16 KB
    const int t = threadIdx.x;
    const int m0 = blockIdx.y * 64, n0 = blockIdx.x * 128;
    const int wave = t >> 6, lane = t & 63;
    const int l15 = lane & 15, lq = lane >> 4;
    const int wr = wave >> 1, wc = wave & 1;

    f32x4 acc[2][4];
    #pragma unroll
    for (int i = 0; i < 2; ++i)
        #pragma unroll
        for (int j = 0; j < 4; ++j) acc[i][j] = (f32x4){0.f, 0.f, 0.f, 0.f};

    for (int k0 = 0; k0 < K; k0 += 64) {
        __syncthreads();
        #pragma unroll
        for (int i = 0; i < 2; ++i) {      // stage A (2 x 16B per thread; 64 rows)
            int li = i * 256 + t;
            int ml = li >> 3, cp = li & 7;
            int cg = cp ^ (ml & 7);
            gll16(A + (size_t)(m0 + ml) * K + k0 + cg * 8, &As[li * 8]);
        }
        #pragma unroll
        for (int i = 0; i < 4; ++i) {      // stage B (4 x 16B per thread; 128 rows)
            int li = i * 256 + t;
            int nl = li >> 3, cp = li & 7;
            int cg = cp ^ (nl & 7);
            gll16(Bt + (size_t)(n0 + nl) * K + k0 + cg * 8, &Bs[li * 8]);
        }
        __syncthreads();
        #pragma unroll
        for (int ks = 0; ks < 2; ++ks) {
            bf16x8 af[2], bfr[4];
            #pragma unroll
            for (int i = 0; i < 2; ++i) {
                int r = wr * 32 + i * 16 + l15;
                int pc = (ks * 4 + lq) ^ (r & 7);
                af[i] = *(const bf16x8*)&As[r * 64 + pc * 8];
            }
            #pragma unroll
            for (int j = 0; j < 4; ++j) {
                int r = wc * 64 + j * 16 + l15;
                int pc = (ks * 4 + lq) ^ (r & 7);
                bfr[j] = *(const bf16x8*)&Bs[r * 64 + pc * 8];
            }
            #pragma unroll
            for (int i = 0; i < 2; ++i)
                #pragma unroll
                for (int j = 0; j < 4; ++j)
                    acc[i][j] = __builtin_amdgcn_mfma_f32_16x16x32_bf16(af[i], bfr[j], acc[i][j], 0, 0, 0);
        }
    }
    #pragma unroll
    for (int i = 0; i < 2; ++i) {
        #pragma unroll
        for (int e = 0; e < 4; ++e) {
            int m = m0 + wr * 32 + i * 16 + 4 * lq + e;
            #pragma unroll
            for (int j = 0; j < 4; ++j) {
                int n = n0 + wc * 64 + j * 16 + l15;
                C[(size_t)m * N + n] = f2b(acc[i][j][e] + bias[n]);
            }
        }
    }
}

// ================= fused area-attention v21 (proven 275 us/dispatch) =================
__global__ __launch_bounds__(512, 2) void attn_mfma21(
    const ushort_t* __restrict__ Q, const ushort_t* __restrict__ Khm,
    const ushort_t* __restrict__ Vt, ushort_t* __restrict__ O)  // O may alias Q
{
    const int id = blockIdx.x;
    const int xcd = id & 7, slot_ = id >> 3;    // 1024 blocks: 8 xcd x 128 slots
    const int qt = slot_ & 1;
    const int bh = ((slot_ >> 1) << 3) + xcd;   // both q-blocks of bh share an XCD
    const int b = bh >> 3, h = bh & 7;
    const int q0 = qt * 128;
    const int t = threadIdx.x;
    const int wave = t >> 6, lane = t & 63;
    const int l15 = lane & 15, lq = lane >> 4;

    __shared__ ushort_t Ks[64 * 256];      // pooled K (sigma rows), chunk ^ (m&15), 32 KB
    __shared__ ushort_t Vs[256 * 64];      // V [d][kpos], chunk ^ (d&7), 32 KB

    const ushort_t* kbh = Khm + (size_t)bh * LSEQ * DH;
    const ushort_t* vtb = Vt + (size_t)bh * DH * LSEQ;   // [d][l]
    const ushort_t* qbh = Q + ((size_t)b * LSEQ) * HD + h * DH;
    const int qrow = q0 + wave * 16 + l15;

    // Q fragments (row=lane&15, k=8*quad+j); pre-scaled by CSCALE in GEMM.
    bf16x8 qf[8];
    if (qrow < LSEQ) {
        const ushort_t* qp = qbh + (size_t)qrow * HD + 8 * lq;
        #pragma unroll
        for (int g = 0; g < 8; ++g) qf[g] = *(const bf16x8*)(qp + 32 * g);
    } else {
        bf16x8 zf = {0,0,0,0,0,0,0,0};
        #pragma unroll
        for (int g = 0; g < 8; ++g) qf[g] = zf;
    }

    f32x4 oacc[16];
    #pragma unroll
    for (int i = 0; i < 16; ++i) oacc[i] = (f32x4){0.f, 0.f, 0.f, 0.f};
    float l4[4];
    #pragma unroll
    for (int e = 0; e < 4; ++e) l4[e] = 0.f;
    float carry[4];                        // Pagg spill into next tile's starts 0..3
    #pragma unroll
    for (int e = 0; e < 4; ++e) carry[e] = 0.f;
    float Pagg[4][4];

    // staging roles for 512 threads
    const int dc = t & 31, mb = t >> 5;      // K: lane->d-chunk, thread->4 positions
    const int vd = t >> 1, vh = t & 1;       // V: thread -> d row, half (4 chunks each)
    // sigma: physical position m = mb + 16*k4 holds pooled-K for start srow + 4*k4
    const int srow = ((mb >> 2) << 4) + (mb & 3);

    auto kOff = [&](int k4) {
        int m = mb + 16 * k4;
        return m * 256 + ((dc ^ (m & 15)) * 8);
    };
    auto storeVchunk = [&](int kc, u16x8 val) {   // full 16B, kpos chunk kc
        *(u16x8*)&Vs[vd * 64 + ((kc ^ (vd & 7)) * 8)] = val;
    };

    // QK on Ks -> sacc (swapped operands): sacc[ms][e] = S^T[phys row][q=l15]
    auto qk = [&](f32x4* sacc) {
        __builtin_amdgcn_s_setprio(1);
        #pragma unroll
        for (int ms = 0; ms < 4; ++ms) {
            f32x4 s = (f32x4){0.f, 0.f, 0.f, 0.f};
            const int row = ms * 16 + l15;
            #pragma unroll
            for (int g = 0; g < 8; ++g) {
                const int phys = (lq + 4 * g) ^ l15;
                s = __builtin_amdgcn_mfma_f32_16x16x32_bf16(
                        *(const bf16x8*)&Ks[row * 256 + phys * 8], qf[g], s, 0, 0, 0);
            }
            sacc[ms] = s;
        }
        __builtin_amdgcn_s_setprio(0);
    };

    // softmax for one class under start = lq*16 + 4*ms + e; shift1 = ONE shuffle
    auto smClass = [&](const f32x4* sacc, int cls) {
        float Pc[4][4];
        #pragma unroll
        for (int ms = 0; ms < 4; ++ms)
            #pragma unroll
            for (int e = 0; e < 4; ++e) {
                float pe = __builtin_exp2f(sacc[ms][e]);
                l4[e] += pe;
                Pc[ms][e] = pe;
                Pagg[ms][e] += pe;
            }
        if (cls >= 1) {
            float T[4][4];
            #pragma unroll
            for (int ms = 0; ms < 4; ++ms)
                #pragma unroll
                for (int e = 0; e < 4; ++e) T[ms][e] = Pc[ms][e];
            #pragma unroll
            for (int u = 1; u <= 4; ++u) {
                if (u <= cls) {
                    float up = __shfl(T[3][3], (lane - 16) & 63);
                    #pragma unroll
                    for (int ms = 3; ms >= 0; --ms) {
                        float nv = (ms > 0) ? T[ms - 1][3] : ((lq > 0) ? up : 0.f);
                        T[ms][3] = T[ms][2]; T[ms][2] = T[ms][1]; T[ms][1] = T[ms][0];
                        T[ms][0] = nv;
                    }
                    #pragma unroll
                    for (int ms = 0; ms < 4; ++ms)
                        #pragma unroll
                        for (int e = 0; e < 4; ++e) Pagg[ms][e] += T[ms][e];
                }
            }
        }
        // carry-out: starts 60..63 = (lq==3, ms==3, e)
        #pragma unroll
        for (int i = 0; i < 4; ++i)
            #pragma unroll
            for (int e = 0; e < 4; ++e)
                if (cls >= 4 + i - e) carry[i] += Pc[3][e];
    };

    // PV over Vs with A-frags from float P[4][4]
    auto pv32 = [&](const float P[4][4]) {
        unsigned int w[8];
        #pragma unroll
        for (int ms = 0; ms < 4; ++ms) {
            asm("v_cvt_pk_bf16_f32 %0, %1, %2" : "=v"(w[2*ms])   : "v"(P[ms][0]), "v"(P[ms][1]));
            asm("v_cvt_pk_bf16_f32 %0, %1, %2" : "=v"(w[2*ms+1]) : "v"(P[ms][2]), "v"(P[ms][3]));
        }
        union FR { unsigned int u[4]; bf16x8 v; };
        FR f0, f1;
        f0.u[0] = w[0]; f0.u[1] = w[1]; f0.u[2] = w[2]; f0.u[3] = w[3];
        f1.u[0] = w[4]; f1.u[1] = w[5]; f1.u[2] = w[6]; f1.u[3] = w[7];
        const bf16x8 pf0 = f0.v, pf1 = f1.v;
        __builtin_amdgcn_s_setprio(1);
        #pragma unroll
        for (int dt = 0; dt < 16; ++dt) {
            const int d = dt * 16 + l15;
            const int p0 = lq ^ (d & 7);
            const int p1 = (lq + 4) ^ (d & 7);
            oacc[dt] = __builtin_amdgcn_mfma_f32_16x16x32_bf16(
                           pf0, *(const bf16x8*)&Vs[d * 64 + p0 * 8], oacc[dt], 0, 0, 0);
            oacc[dt] = __builtin_amdgcn_mfma_f32_16x16x32_bf16(
                           pf1, *(const bf16x8*)&Vs[d * 64 + p1 * 8], oacc[dt], 0, 0, 0);
        }
        __builtin_amdgcn_s_setprio(0);
    };

    // ---- 3 full tiles x 5 QK classes + 1 PV each ----
    for (int ti = 0; ti < 3; ++ti) {
        const int st0 = ti * 64;
        // carry-in: prev tile's spill -> this tile's starts 0..3 (lq==0, ms==0)
        {
            float pin0 = __shfl(carry[0], (lane + 48) & 63);
            float pin1 = __shfl(carry[1], (lane + 48) & 63);
            float pin2 = __shfl(carry[2], (lane + 48) & 63);
            float pin3 = __shfl(carry[3], (lane + 48) & 63);
            #pragma unroll
            for (int ms = 0; ms < 4; ++ms)
                #pragma unroll
                for (int e = 0; e < 4; ++e) Pagg[ms][e] = 0.f;
            if (lq == 0) {
                Pagg[0][0] = pin0; Pagg[0][1] = pin1; Pagg[0][2] = pin2; Pagg[0][3] = pin3;
            }
            #pragma unroll
            for (int e = 0; e < 4; ++e) carry[e] = 0.f;
        }
        #pragma unroll
        for (int cls = 0; cls < 5; ++cls) {
            // prefetch sigma-swapped K rows (+cls); raw V rows at cls==0 (once/tile)
            u16x8 kf[4];
            #pragma unroll
            for (int k4 = 0; k4 < 4; ++k4)
                kf[k4] = *(const u16x8*)(kbh + (size_t)(st0 + srow + 4 * k4 + cls) * DH + dc * 8);
            u16x8 vc[4];
            if (cls == 0) {
                const ushort_t* vrow = vtb + (size_t)vd * LSEQ + st0 + vh * 32;
                #pragma unroll
                for (int c2 = 0; c2 < 4; ++c2) vc[c2] = *(const u16x8*)(vrow + c2 * 8);
            }
            __syncthreads();   // previous step's frag reads done

            // K pooled: running max in Ks (in-place RMW), 4 positions/thread
            #pragma unroll
            for (int k4 = 0; k4 < 4; ++k4) {
                ushort_t* kp = &Ks[kOff(k4)];
                *(u16x8*)kp = (cls == 0) ? kf[k4] : bmax8(*(const u16x8*)kp, kf[k4]);
            }
            // raw V staged once per tile: natural chunk cg -> kpos chunk (cg&1)*4+(cg>>1)
            if (cls == 0) {
                #pragma unroll
                for (int cl = 0; cl < 4; ++cl) {
                    const int cg = vh * 4 + cl;
                    storeVchunk((cg & 1) * 4 + (cg >> 1), vc[cl]);
                }
            }
            __syncthreads();

            f32x4 sacc[4];
            qk(sacc);
            smClass(sacc, cls);
            if (cls == 4) pv32(Pagg);   // one PV over raw V for the whole tile
        }
    }

    // ---- tail step: pooled tail K (PHYSICAL layout) + tail V via kpos table ----
    {
        __syncthreads();   // previous step's frag reads (incl. PV) done
        // K: threads with mb<8 cover physical slots k8*8+mb (cls=k8, off=mb)
        if (mb < 8) {
            u16x8 krun = *(const u16x8*)(kbh + (size_t)(192 + mb) * DH + dc * 8);
            const u16x8 kz = {0,0,0,0,0,0,0,0};
            #pragma unroll
            for (int k8 = 0; k8 < 8; ++k8) {
                const bool vv = (k8 <= 4) && (mb <= 7 - k8);
                if (k8 > 0 && vv)
                    krun = bmax8(krun, *(const u16x8*)(kbh + (size_t)(192 + mb + k8) * DH + dc * 8));
                int slot = k8 * 8 + mb;
                *(u16x8*)&Ks[slot * 256 + ((dc ^ (slot & 15)) * 8)] = vv ? krun : kz;
            }
        }
        // V: kpos chunk kc holds (cls,off) per derived map; kc==6 o<4 = raw V[192..195]
        {
            u16x8 v0 = *(const u16x8*)(vtb + (size_t)vd * LSEQ + 192);
            float f[8];
            #pragma unroll
            for (int e = 0; e < 8; ++e) f[e] = b2f(v0[e]);
            #pragma unroll
            for (int ck = 0; ck < 4; ++ck) {
                const int kc = vh * 4 + ck;
                const int cls_lo = 4 * (kc >> 2) + ((kc >> 1) & 1);
                const int offb = 4 * (kc & 1);
                u16x8 ov;
                #pragma unroll
                for (int o = 0; o < 8; ++o) {
                    const int cls = cls_lo + 2 * (o >> 2);
                    const int off = offb + (o & 3);
                    ushort_t val = 0;
                    if (cls <= 4 && off <= 7 - cls) {
                        float a = 0.f;
                        #pragma unroll
                        for (int u = 0; u <= 4; ++u)
                            if (u <= cls) a += f[off + u];
                        val = f2b(a);
                    }
                    if (kc == 6 && o < 4) val = v0[o];   // raw V for carry slots
                    ov[o] = val;
                }
                storeVchunk(kc, ov);
            }
        }
        __syncthreads();

        // tail compute: QK (physical slots), softmax + carry injection, PV
        f32x4 sacc[4];
        qk(sacc);
        float pullc[4];
        #pragma unroll
        for (int e = 0; e < 4; ++e) pullc[e] = __shfl(carry[e], (lane + 16) & 63);
        float Pt[4][4];
        #pragma unroll
        for (int ms = 0; ms < 4; ++ms)
            #pragma unroll
            for (int e = 0; e < 4; ++e) {
                const int slot = ms * 16 + 4 * lq + e;   // PHYSICAL slot = 8*cls + off
                const bool inval = ((slot & 7) > 7 - (slot >> 3)) || ((slot >> 3) > 4);
                float pe = __builtin_exp2f(inval ? -1e30f : sacc[ms][e]);
                l4[e] += pe;           // carry slots are invalid -> pe==0 here
                float pfrag = pe;
                if (ms == 2 && lq == 2) pfrag = pullc[e];   // pairs with raw V in kc 6
                Pt[ms][e] = pfrag;
            }
        pv32(Pt);
    }

    // epilogue: reduce l over the 4 lq groups, invert, redistribute
    float l_part = (l4[0] + l4[1]) + (l4[2] + l4[3]);
    l_part += __shfl_xor(l_part, 16);
    l_part += __shfl_xor(l_part, 32);
    const float inv = 1.f / l_part;

    ushort_t* ob = O + ((size_t)b * LSEQ) * HD + h * DH;
    #pragma unroll
    for (int e = 0; e < 4; ++e) {
        const int q = q0 + wave * 16 + 4 * lq + e;
        const float linv = __shfl(inv, 4 * lq + e);
        if (q < LSEQ) {
            #pragma unroll
            for (int dt = 0; dt < 16; ++dt)
                ob[(size_t)q * HD + dt * 16 + l15] = f2b(oacc[dt][e] * linv);
        }
    }
}

// ================= residual + LayerNorm: Out = LN(bf16 X + R) =================
template<typename TR, typename TO>
__global__ __launch_bounds__(256) void residual_ln(
    const ushort_t* __restrict__ X, const TR* __restrict__ R, TO* __restrict__ Out)
{
    const int row = blockIdx.x;
    const int t = threadIdx.x;
    const size_t base = (size_t)row * HID;
    float v = b2f(X[base + t]) + to_f32(R[base + t]);
    float s = v, q = v * v;
    #pragma unroll
    for (int o = 32; o > 0; o >>= 1) {
        s += __shfl_xor(s, o, 64);
        q += __shfl_xor(q, o, 64);
    }
    __shared__ float ss[4], sq[4];
    const int wave = t >> 6, lane = t & 63;
    if (lane == 0) { ss[wave] = s; sq[wave] = q; }
    __syncthreads();
    s = ss[0] + ss[1] + ss[2] + ss[3];
    q = sq[0] + sq[1] + sq[2] + sq[3];
    float mean = s * (1.f / HID);
    float var  = q * (1.f / HID) - mean * mean;
    store_val(&Out[base + t], (v - mean) * rsqrtf(var + EPS));
}

// ================= fused prep: hidden f32->bf16 + 6 weight transposes (v23) ==========
// Grid layout (block-uniform jobs): [0,3200) cvt hidden; then wtrans tiles:
// Wq 512, Wk 512, Wv 512, Wo 512, W1 256, W2 256. Total 5760 blocks.
__global__ __launch_bounds__(256) void prep_all(
    const float* __restrict__ hidden, ushort_t* __restrict__ hb,
    const float* __restrict__ Wq, ushort_t* __restrict__ WtQ,
    const float* __restrict__ Wk, ushort_t* __restrict__ WtK,
    const float* __restrict__ Wv, ushort_t* __restrict__ WtV,
    const float* __restrict__ Wo, ushort_t* __restrict__ WtO,
    const float* __restrict__ W1, ushort_t* __restrict__ Wt1,
    const float* __restrict__ W2, ushort_t* __restrict__ Wt2)
{
    __shared__ float tile[32][33];
    int bid = blockIdx.x;
    const int t = threadIdx.x;
    if (bid < 3200) {                      // cvt hidden
        const int i = (bid * 256 + t) * 4;
        float4 v = *(const float4*)(hidden + i);
        ushort4 o;
        o.x = f2b(v.x); o.y = f2b(v.y); o.z = f2b(v.z); o.w = f2b(v.w);
        *(ushort4*)(hb + i) = o;
        return;
    }
    bid -= 3200;
    const float* W; ushort_t* Wt; int K, N;
    if (bid < 512)       {             W = Wq; Wt = WtQ; K = HID;     N = HD;      }
    else if (bid < 1024) { bid -= 512; W = Wk; Wt = WtK; K = HID;     N = HD;      }
    else if (bid < 1536) { bid -= 1024; W = Wv; Wt = WtV; K = HID;    N = HD;      }
    else if (bid < 2048) { bid -= 1536; W = Wo; Wt = WtO; K = HD;     N = HID;     }
    else if (bid < 2304) { bid -= 2048; W = W1; Wt = Wt1; K = HID;    N = 4 * HID; }
    else                 { bid -= 2304; W = W2; Wt = Wt2; K = 4 * HID; N = HID;    }
    const int ntx = N / 32;
    const int n0 = (bid % ntx) * 32, k0 = (bid / ntx) * 32;
    const int tx = t & 31, ty = t >> 5;
    #pragma unroll
    for (int s = 0; s < 4; ++s)
        tile[ty + 8 * s][tx] = W[(size_t)(k0 + ty + 8 * s) * N + n0 + tx];
    __syncthreads();
    #pragma unroll
    for (int s = 0; s < 4; ++s)
        Wt[(size_t)(n0 + ty + 8 * s) * K + k0 + tx] = f2b(tile[tx][ty + 8 * s]);
}

// ================= launch =================
extern "C" void kernel_launch(void* const* d_in, const int* in_sizes, int n_in,
                              void* d_out, int out_size, void* d_ws, size_t ws_size,
                              hipStream_t stream) {
    const float* hidden = (const float*)d_in[1];
    const float* Wq = (const float*)d_in[2];  const float* bq = (const float*)d_in[3];
    const float* Wk = (const float*)d_in[4];  const float* bk = (const float*)d_in[5];
    const float* Wv = (const float*)d_in[6];  const float* bv = (const float*)d_in[7];
    const float* Wo = (const float*)d_in[8];  const float* bo = (const float*)d_in[9];
    const float* W1 = (const float*)d_in[10]; const float* b1 = (const float*)d_in[11];
    const float* W2 = (const float*)d_in[12]; const float* b2 = (const float*)d_in[13];
    float* out = (float*)d_out;

    constexpr size_t SZ_BF   = (size_t)MROWS * HD * 2;      // 52,428,800
    constexpr size_t SZ_HBF  = (size_t)MROWS * HID * 2;     // 6,553,600
    constexpr size_t SZ_WQKV = (size_t)HID * HD * 2;        // 1,048,576
    constexpr size_t SZ_W12  = (size_t)HID * 4 * HID * 2;   // 524,288
    char* ws = (char*)d_ws;
    size_t off = 0;
    ushort_t* kb   = (ushort_t*)(ws + off); off += SZ_BF;   // K head-major [b,h][l][d]
    ushort_t* vt   = (ushort_t*)(ws + off); off += SZ_BF;   // V transposed  [b,h][d][l]
    ushort_t* qo   = (ushort_t*)(ws + off); off += SZ_BF;   // q / attn-out / ffn1
    ushort_t* hb   = (ushort_t*)(ws + off); off += SZ_HBF;  // hidden bf16
    ushort_t* at1  = (ushort_t*)(ws + off); off += SZ_HBF;
    ushort_t* at2  = (ushort_t*)(ws + off); off += SZ_HBF;
    ushort_t* proj = (ushort_t*)(ws + off); off += SZ_HBF;
    ushort_t* WtQ  = (ushort_t*)(ws + off); off += SZ_WQKV; // WtQ/WtK/WtV contiguous!
    ushort_t* WtK  = (ushort_t*)(ws + off); off += SZ_WQKV;
    ushort_t* WtV  = (ushort_t*)(ws + off); off += SZ_WQKV;
    ushort_t* WtO  = (ushort_t*)(ws + off); off += SZ_WQKV;
    ushort_t* Wt1  = (ushort_t*)(ws + off); off += SZ_W12;
    ushort_t* Wt2  = (ushort_t*)(ws + off); off += SZ_W12;
    if (ws_size < off) return;  // total == 188,743,680 B (same as passing R3/R5-R11)
    ushort_t* ffn1 = qo;        // alias: qo free after out-proj2

    dim3 blk(256);
    prep_all<<<5760, blk, 0, stream>>>(hidden, hb, Wq, WtQ, Wk, WtK, Wv, WtV,
                                       Wo, WtO, W1, Wt1, W2, Wt2);

    const dim3 gQKV(3 * HD / 128, MROWS / 128);     // 48 x 100
    const dim3 gProj(HD / 128, MROWS / 128);        // 16 x 100
    const dim3 gOut64(HID / 128, MROWS / 64);       // 2 x 200
    const dim3 gF1(4 * HID / 128, MROWS / 128);     // 8 x 100

    // fused Q/K/V projection (Q pre-scaled; K head-major; V transposed head-major)
    gemm_qkv<<<gQKV, blk, 0, stream>>>(hb, WtQ, bq, bk, bv, qo, kb, vt);

    // MHA1
    attn_mfma21<<<2 * BATCH * NH, 512, 0, stream>>>(qo, kb, vt, qo);
    gemm_bt64<<<gOut64, blk, 0, stream>>>(qo, WtO, bo, proj, MROWS, HID, HD);
    residual_ln<float, ushort_t><<<MROWS, blk, 0, stream>>>(proj, hidden, at1);

    // MHA2 (q from attn1; pooled K/V rebuilt from same kb/vt)
    gemm_bt<false, true><<<gProj, blk, 0, stream>>>(at1, WtQ, bq, qo, MROWS, HD, HID);
    attn_mfma21<<<2 * BATCH * NH, 512, 0, stream>>>(qo, kb, vt, qo);
    gemm_bt64<<<gOut64, blk, 0, stream>>>(qo, WtO, bo, proj, MROWS, HID, HD);
    residual_ln<ushort_t, ushort_t><<<MROWS, blk, 0, stream>>>(proj, at1, at2);

    // FFN
    gemm_bt<true, false><<<gF1, blk, 0, stream>>>(at2, Wt1, b1, ffn1, MROWS, 4 * HID, HID);
    gemm_bt64<<<gOut64, blk, 0, stream>>>(ffn1, Wt2, b2, proj, MROWS, HID, 4 * HID);
    residual_ln<ushort_t, float><<<MROWS, blk, 0, stream>>>(proj, at2, out);
}

// Round 14
// 814.535 us; speedup vs baseline: 1.4322x; 1.0237x over previous
//
#include <hip/hip_runtime.h>
#include <hip/hip_bf16.h>
#include <cstdint>
#include <cstddef>

// Problem constants
#define BATCH 64
#define LSEQ 200
#define HID 256
#define NH 8
#define DH 256            // per-head dim = HID
#define HD (NH*DH)        // 2048
#define MROWS (BATCH*LSEQ)   // 12800
#define EPS 1e-5f
#define CSCALE 0.09014195f   // (1/sqrt(256)) * log2(e), folded into Q projection

typedef unsigned short ushort_t;
typedef __attribute__((ext_vector_type(8))) short bf16x8;         // MFMA A/B frag (4 VGPR)
typedef __attribute__((ext_vector_type(8))) unsigned short u16x8; // 16B of bf16
typedef __attribute__((ext_vector_type(4))) float f32x4;          // MFMA C/D frag

__device__ __forceinline__ float b2f(ushort_t u) {
    union { unsigned int i; float f; } c; c.i = ((unsigned int)u) << 16; return c.f;
}
__device__ __forceinline__ ushort_t f2b(float f) {
    __hip_bfloat16 h = __float2bfloat16(f);
    union { __hip_bfloat16 h; ushort_t u; } c; c.h = h; return c.u;
}
__device__ __forceinline__ float to_f32(float x) { return x; }
__device__ __forceinline__ float to_f32(ushort_t x) { return b2f(x); }
__device__ __forceinline__ void store_val(float* p, float v) { *p = v; }
__device__ __forceinline__ void store_val(ushort_t* p, float v) { *p = f2b(v); }

// packed bf16 max on 8 elements
__device__ __forceinline__ u16x8 bmax8(u16x8 a, u16x8 b) {
    union U { u16x8 v; __hip_bfloat162 h[4]; };
    U ua, ub, r; ua.v = a; ub.v = b;
    #pragma unroll
    for (int i = 0; i < 4; ++i) r.h[i] = __hmax2(ua.h[i], ub.h[i]);
    return r.v;
}

// async global->LDS, 16 bytes per lane (LDS dest = wave-uniform base + lane*16)
__device__ __forceinline__ void gll16(const void* g, void* l) {
    __builtin_amdgcn_global_load_lds(
        (const __attribute__((address_space(1))) unsigned int*)g,
        (__attribute__((address_space(3))) unsigned int*)l, 16, 0, 0);
}

// ================= bf16 MFMA GEMM:  C[M,N] = A[M,K] @ Bt[N,K]^T + bias =================
// 128x128 tile, BK=64, 4 waves (2x2 of 64x64), global_load_lds staging, XOR-swizzled
// LDS (phys chunk = logical ^ (row&7)). Row-major output only.
template<bool RELU, bool SCALEC>
__global__ __launch_bounds__(256) void gemm_bt(
    const ushort_t* __restrict__ A, const ushort_t* __restrict__ Bt,
    const float* __restrict__ bias, ushort_t* __restrict__ C,
    int M, int N, int K)
{
    __shared__ ushort_t As[128 * 64];
    __shared__ ushort_t Bs[128 * 64];
    const int t = threadIdx.x;
    const int m0 = blockIdx.y * 128, n0 = blockIdx.x * 128;
    const int wave = t >> 6, lane = t & 63;
    const int l15 = lane & 15, lq = lane >> 4;
    const int wr = wave >> 1, wc = wave & 1;

    f32x4 acc[4][4];
    #pragma unroll
    for (int i = 0; i < 4; ++i)
        #pragma unroll
        for (int j = 0; j < 4; ++j) acc[i][j] = (f32x4){0.f, 0.f, 0.f, 0.f};

    for (int k0 = 0; k0 < K; k0 += 64) {
        __syncthreads();
        #pragma unroll
        for (int i = 0; i < 4; ++i) {      // stage A (4 x 16B per thread)
            int li = i * 256 + t;
            int ml = li >> 3, cp = li & 7;
            int cg = cp ^ (ml & 7);
            gll16(A + (size_t)(m0 + ml) * K + k0 + cg * 8, &As[li * 8]);
        }
        #pragma unroll
        for (int i = 0; i < 4; ++i) {      // stage B
            int li = i * 256 + t;
            int nl = li >> 3, cp = li & 7;
            int cg = cp ^ (nl & 7);
            gll16(Bt + (size_t)(n0 + nl) * K + k0 + cg * 8, &Bs[li * 8]);
        }
        __syncthreads();
        #pragma unroll
        for (int ks = 0; ks < 2; ++ks) {   // two K=32 sub-steps per staged tile
            bf16x8 af[4], bfr[4];
            #pragma unroll
            for (int i = 0; i < 4; ++i) {
                int r = wr * 64 + i * 16 + l15;
                int pc = (ks * 4 + lq) ^ (r & 7);
                af[i] = *(const bf16x8*)&As[r * 64 + pc * 8];
            }
            #pragma unroll
            for (int j = 0; j < 4; ++j) {
                int r = wc * 64 + j * 16 + l15;
                int pc = (ks * 4 + lq) ^ (r & 7);
                bfr[j] = *(const bf16x8*)&Bs[r * 64 + pc * 8];
            }
            #pragma unroll
            for (int i = 0; i < 4; ++i)
                #pragma unroll
                for (int j = 0; j < 4; ++j)
                    acc[i][j] = __builtin_amdgcn_mfma_f32_16x16x32_bf16(af[i], bfr[j], acc[i][j], 0, 0, 0);
        }
    }
    #pragma unroll
    for (int i = 0; i < 4; ++i) {
        #pragma unroll
        for (int e = 0; e < 4; ++e) {
            int m = m0 + wr * 64 + i * 16 + 4 * lq + e;
            #pragma unroll
            for (int j = 0; j < 4; ++j) {
                int n = n0 + wc * 64 + j * 16 + l15;
                float v = acc[i][j][e] + bias[n];
                if (RELU) v = fmaxf(v, 0.f);
                if (SCALEC) v *= CSCALE;
                C[(size_t)m * N + n] = f2b(v);
            }
        }
    }
}

// ================= fused QKV projection =================
// One GEMM over N = 3*2048: Bt = [WtQ; WtK; WtV] (contiguous in ws). Segment
// (block-uniform, seg = n0>>11) selects the validated epilogue path.
__global__ __launch_bounds__(256) void gemm_qkv(
    const ushort_t* __restrict__ A, const ushort_t* __restrict__ Bt,
    const float* __restrict__ bq, const float* __restrict__ bk,
    const float* __restrict__ bv,
    ushort_t* __restrict__ Cq, ushort_t* __restrict__ Ck, ushort_t* __restrict__ Cv)
{
    constexpr int K = HID;                 // 256
    __shared__ ushort_t As[128 * 64];
    __shared__ ushort_t Bs[128 * 64];
    const int t = threadIdx.x;
    const int m0 = blockIdx.y * 128, n0 = blockIdx.x * 128;
    const int wave = t >> 6, lane = t & 63;
    const int l15 = lane & 15, lq = lane >> 4;
    const int wr = wave >> 1, wc = wave & 1;

    f32x4 acc[4][4];
    #pragma unroll
    for (int i = 0; i < 4; ++i)
        #pragma unroll
        for (int j = 0; j < 4; ++j) acc[i][j] = (f32x4){0.f, 0.f, 0.f, 0.f};

    for (int k0 = 0; k0 < K; k0 += 64) {
        __syncthreads();
        #pragma unroll
        for (int i = 0; i < 4; ++i) {
            int li = i * 256 + t;
            int ml = li >> 3, cp = li & 7;
            int cg = cp ^ (ml & 7);
            gll16(A + (size_t)(m0 + ml) * K + k0 + cg * 8, &As[li * 8]);
        }
        #pragma unroll
        for (int i = 0; i < 4; ++i) {
            int li = i * 256 + t;
            int nl = li >> 3, cp = li & 7;
            int cg = cp ^ (nl & 7);
            gll16(Bt + (size_t)(n0 + nl) * K + k0 + cg * 8, &Bs[li * 8]);
        }
        __syncthreads();
        #pragma unroll
        for (int ks = 0; ks < 2; ++ks) {
            bf16x8 af[4], bfr[4];
            #pragma unroll
            for (int i = 0; i < 4; ++i) {
                int r = wr * 64 + i * 16 + l15;
                int pc = (ks * 4 + lq) ^ (r & 7);
                af[i] = *(const bf16x8*)&As[r * 64 + pc * 8];
            }
            #pragma unroll
            for (int j = 0; j < 4; ++j) {
                int r = wc * 64 + j * 16 + l15;
                int pc = (ks * 4 + lq) ^ (r & 7);
                bfr[j] = *(const bf16x8*)&Bs[r * 64 + pc * 8];
            }
            #pragma unroll
            for (int i = 0; i < 4; ++i)
                #pragma unroll
                for (int j = 0; j < 4; ++j)
                    acc[i][j] = __builtin_amdgcn_mfma_f32_16x16x32_bf16(af[i], bfr[j], acc[i][j], 0, 0, 0);
        }
    }

    const int seg = n0 >> 11;              // 0=Q, 1=K, 2=V (block-uniform)
    const int nb = n0 & 2047;              // segment-local n0
    if (seg == 2) {
        // V transposed head-major [b,h][d][l]; 200%4==0 so mbase 4-aligned rows pack
        #pragma unroll
        for (int i = 0; i < 4; ++i) {
            int mbase = m0 + wr * 64 + i * 16 + 4 * lq;
            int bb = (int)(((unsigned)mbase * 5243u) >> 20);    // mbase/200
            int ll = mbase - bb * 200;
            #pragma unroll
            for (int j = 0; j < 4; ++j) {
                int nn = nb + wc * 64 + j * 16 + l15;
                float bsv = bv[nn];
                ushort4 o4;
                o4.x = f2b(acc[i][j][0] + bsv); o4.y = f2b(acc[i][j][1] + bsv);
                o4.z = f2b(acc[i][j][2] + bsv); o4.w = f2b(acc[i][j][3] + bsv);
                size_t addr = ((size_t)(bb * NH + (nn >> 8)) * 256 + (nn & 255)) * LSEQ + ll;
                *(ushort4*)&Cv[addr] = o4;
            }
        }
    } else if (seg == 1) {
        // K head-major [b,h][l][d]
        #pragma unroll
        for (int i = 0; i < 4; ++i) {
            #pragma unroll
            for (int e = 0; e < 4; ++e) {
                int m = m0 + wr * 64 + i * 16 + 4 * lq + e;
                int bb = (int)(((unsigned)m * 5243u) >> 20);
                int ll = m - bb * 200;
                #pragma unroll
                for (int j = 0; j < 4; ++j) {
                    int nn = nb + wc * 64 + j * 16 + l15;
                    float v = acc[i][j][e] + bk[nn];
                    size_t addr = ((((size_t)(bb * NH + (nn >> 8))) * LSEQ + ll) << 8) + (nn & 255);
                    Ck[addr] = f2b(v);
                }
            }
        }
    } else {
        // Q row-major [m][2048], pre-scaled by CSCALE
        #pragma unroll
        for (int i = 0; i < 4; ++i) {
            #pragma unroll
            for (int e = 0; e < 4; ++e) {
                int m = m0 + wr * 64 + i * 16 + 4 * lq + e;
                #pragma unroll
                for (int j = 0; j < 4; ++j) {
                    int nn = nb + wc * 64 + j * 16 + l15;
                    float v = (acc[i][j][e] + bq[nn]) * CSCALE;
                    Cq[(size_t)m * HD + nn] = f2b(v);
                }
            }
        }
    }
}

// ================= fused N=256 GEMM + residual + LayerNorm (v24) =================
// BM=64, BN=256 (full N -> complete rows per block), 512 threads / 8 waves (2m x 4n),
// grid 200. Epilogue: v = acc + bias + R; per-row stats via 4 l15-shuffles + 2 KB LDS
// cross-wave table; Out = (v-mean)*rsqrt(var+EPS). Replaces gemm_bt64 + residual_ln.
template<typename TR, typename TO>
__global__ __launch_bounds__(512, 2) void gemm_out_ln(
    const ushort_t* __restrict__ A, const ushort_t* __restrict__ Bt,
    const float* __restrict__ bias, const TR* __restrict__ R,
    TO* __restrict__ Out, int K)
{
    __shared__ ushort_t As[64 * 64];       // 8 KB
    __shared__ ushort_t Bs[256 * 64];      // 32 KB
    __shared__ float rs[64][4], rq[64][4]; // 2 KB row-stat partials (per wc)
    const int t = threadIdx.x;
    const int m0 = blockIdx.x * 64;
    const int wave = t >> 6, lane = t & 63;
    const int l15 = lane & 15, lq = lane >> 4;
    const int wr = wave >> 2, wc = wave & 3;   // 2m x 4n

    f32x4 acc[2][4];
    #pragma unroll
    for (int i = 0; i < 2; ++i)
        #pragma unroll
        for (int j = 0; j < 4; ++j) acc[i][j] = (f32x4){0.f, 0.f, 0.f, 0.f};

    for (int k0 = 0; k0 < K; k0 += 64) {
        __syncthreads();
        {                                   // stage A (1 x 16B per thread; 64 rows)
            int ml = t >> 3, cp = t & 7;
            int cg = cp ^ (ml & 7);
            gll16(A + (size_t)(m0 + ml) * K + k0 + cg * 8, &As[t * 8]);
        }
        #pragma unroll
        for (int i = 0; i < 4; ++i) {       // stage B (4 x 16B per thread; 256 rows)
            int li = i * 512 + t;
            int nl = li >> 3, cp = li & 7;
            int cg = cp ^ (nl & 7);
            gll16(Bt + (size_t)nl * K + k0 + cg * 8, &Bs[li * 8]);
        }
        __syncthreads();
        #pragma unroll
        for (int ks = 0; ks < 2; ++ks) {
            bf16x8 af[2], bfr[4];
            #pragma unroll
            for (int i = 0; i < 2; ++i) {
                int r = wr * 32 + i * 16 + l15;
                int pc = (ks * 4 + lq) ^ (r & 7);
                af[i] = *(const bf16x8*)&As[r * 64 + pc * 8];
            }
            #pragma unroll
            for (int j = 0; j < 4; ++j) {
                int r = wc * 64 + j * 16 + l15;
                int pc = (ks * 4 + lq) ^ (r & 7);
                bfr[j] = *(const bf16x8*)&Bs[r * 64 + pc * 8];
            }
            #pragma unroll
            for (int i = 0; i < 2; ++i)
                #pragma unroll
                for (int j = 0; j < 4; ++j)
                    acc[i][j] = __builtin_amdgcn_mfma_f32_16x16x32_bf16(af[i], bfr[j], acc[i][j], 0, 0, 0);
        }
    }

    // epilogue: v = acc + bias + R (rows m = m0 + wr*32 + i*16 + 4*lq + e)
    float v[2][4][4];
    #pragma unroll
    for (int i = 0; i < 2; ++i)
        #pragma unroll
        for (int e = 0; e < 4; ++e) {
            const int m = m0 + wr * 32 + i * 16 + 4 * lq + e;
            #pragma unroll
            for (int j = 0; j < 4; ++j) {
                const int n = wc * 64 + j * 16 + l15;
                v[i][j][e] = acc[i][j][e] + bias[n] + to_f32(R[(size_t)m * HID + n]);
            }
        }
    // per-row partial sums over this wave's 64 cols -> reduce across the 16 l15 lanes
    #pragma unroll
    for (int i = 0; i < 2; ++i)
        #pragma unroll
        for (int e = 0; e < 4; ++e) {
            float s = (v[i][0][e] + v[i][1][e]) + (v[i][2][e] + v[i][3][e]);
            float q = (v[i][0][e] * v[i][0][e] + v[i][1][e] * v[i][1][e])
                    + (v[i][2][e] * v[i][2][e] + v[i][3][e] * v[i][3][e]);
            #pragma unroll
            for (int o = 1; o < 16; o <<= 1) {
                s += __shfl_xor(s, o);
                q += __shfl_xor(q, o);
            }
            if (l15 == 0) {
                const int row = wr * 32 + i * 16 + 4 * lq + e;
                rs[row][wc] = s; rq[row][wc] = q;
            }
        }
    __syncthreads();
    #pragma unroll
    for (int i = 0; i < 2; ++i)
        #pragma unroll
        for (int e = 0; e < 4; ++e) {
            const int row = wr * 32 + i * 16 + 4 * lq + e;
            const float s = (rs[row][0] + rs[row][1]) + (rs[row][2] + rs[row][3]);
            const float q = (rq[row][0] + rq[row][1]) + (rq[row][2] + rq[row][3]);
            const float mean = s * (1.f / HID);
            const float var  = q * (1.f / HID) - mean * mean;
            const float rstd = rsqrtf(var + EPS);
            const int m = m0 + row;
            #pragma unroll
            for (int j = 0; j < 4; ++j) {
                const int n = wc * 64 + j * 16 + l15;
                store_val(&Out[(size_t)m * HID + n], (v[i][j][e] - mean) * rstd);
            }
        }
}

// ================= fused area-attention v21 (proven 275 us/dispatch) =================
__global__ __launch_bounds__(512, 2) void attn_mfma21(
    const ushort_t* __restrict__ Q, const ushort_t* __restrict__ Khm,
    const ushort_t* __restrict__ Vt, ushort_t* __restrict__ O)  // O may alias Q
{
    const int id = blockIdx.x;
    const int xcd = id & 7, slot_ = id >> 3;    // 1024 blocks: 8 xcd x 128 slots
    const int qt = slot_ & 1;
    const int bh = ((slot_ >> 1) << 3) + xcd;   // both q-blocks of bh share an XCD
    const int b = bh >> 3, h = bh & 7;
    const int q0 = qt * 128;
    const int t = threadIdx.x;
    const int wave = t >> 6, lane = t & 63;
    const int l15 = lane & 15, lq = lane >> 4;

    __shared__ ushort_t Ks[64 * 256];      // pooled K (sigma rows), chunk ^ (m&15), 32 KB
    __shared__ ushort_t Vs[256 * 64];      // V [d][kpos], chunk ^ (d&7), 32 KB

    const ushort_t* kbh = Khm + (size_t)bh * LSEQ * DH;
    const ushort_t* vtb = Vt + (size_t)bh * DH * LSEQ;   // [d][l]
    const ushort_t* qbh = Q + ((size_t)b * LSEQ) * HD + h * DH;
    const int qrow = q0 + wave * 16 + l15;

    // Q fragments (row=lane&15, k=8*quad+j); pre-scaled by CSCALE in GEMM.
    bf16x8 qf[8];
    if (qrow < LSEQ) {
        const ushort_t* qp = qbh + (size_t)qrow * HD + 8 * lq;
        #pragma unroll
        for (int g = 0; g < 8; ++g) qf[g] = *(const bf16x8*)(qp + 32 * g);
    } else {
        bf16x8 zf = {0,0,0,0,0,0,0,0};
        #pragma unroll
        for (int g = 0; g < 8; ++g) qf[g] = zf;
    }

    f32x4 oacc[16];
    #pragma unroll
    for (int i = 0; i < 16; ++i) oacc[i] = (f32x4){0.f, 0.f, 0.f, 0.f};
    float l4[4];
    #pragma unroll
    for (int e = 0; e < 4; ++e) l4[e] = 0.f;
    float carry[4];                        // Pagg spill into next tile's starts 0..3
    #pragma unroll
    for (int e = 0; e < 4; ++e) carry[e] = 0.f;
    float Pagg[4][4];

    // staging roles for 512 threads
    const int dc = t & 31, mb = t >> 5;      // K: lane->d-chunk, thread->4 positions
    const int vd = t >> 1, vh = t & 1;       // V: thread -> d row, half (4 chunks each)
    // sigma: physical position m = mb + 16*k4 holds pooled-K for start srow + 4*k4
    const int srow = ((mb >> 2) << 4) + (mb & 3);

    auto kOff = [&](int k4) {
        int m = mb + 16 * k4;
        return m * 256 + ((dc ^ (m & 15)) * 8);
    };
    auto storeVchunk = [&](int kc, u16x8 val) {   // full 16B, kpos chunk kc
        *(u16x8*)&Vs[vd * 64 + ((kc ^ (vd & 7)) * 8)] = val;
    };

    // QK on Ks -> sacc (swapped operands): sacc[ms][e] = S^T[phys row][q=l15]
    auto qk = [&](f32x4* sacc) {
        __builtin_amdgcn_s_setprio(1);
        #pragma unroll
        for (int ms = 0; ms < 4; ++ms) {
            f32x4 s = (f32x4){0.f, 0.f, 0.f, 0.f};
            const int row = ms * 16 + l15;
            #pragma unroll
            for (int g = 0; g < 8; ++g) {
                const int phys = (lq + 4 * g) ^ l15;
                s = __builtin_amdgcn_mfma_f32_16x16x32_bf16(
                        *(const bf16x8*)&Ks[row * 256 + phys * 8], qf[g], s, 0, 0, 0);
            }
            sacc[ms] = s;
        }
        __builtin_amdgcn_s_setprio(0);
    };

    // softmax for one class under start = lq*16 + 4*ms + e; shift1 = ONE shuffle
    auto smClass = [&](const f32x4* sacc, int cls) {
        float Pc[4][4];
        #pragma unroll
        for (int ms = 0; ms < 4; ++ms)
            #pragma unroll
            for (int e = 0; e < 4; ++e) {
                float pe = __builtin_exp2f(sacc[ms][e]);
                l4[e] += pe;
                Pc[ms][e] = pe;
                Pagg[ms][e] += pe;
            }
        if (cls >= 1) {
            float T[4][4];
            #pragma unroll
            for (int ms = 0; ms < 4; ++ms)
                #pragma unroll
                for (int e = 0; e < 4; ++e) T[ms][e] = Pc[ms][e];
            #pragma unroll
            for (int u = 1; u <= 4; ++u) {
                if (u <= cls) {
                    float up = __shfl(T[3][3], (lane - 16) & 63);
                    #pragma unroll
                    for (int ms = 3; ms >= 0; --ms) {
                        float nv = (ms > 0) ? T[ms - 1][3] : ((lq > 0) ? up : 0.f);
                        T[ms][3] = T[ms][2]; T[ms][2] = T[ms][1]; T[ms][1] = T[ms][0];
                        T[ms][0] = nv;
                    }
                    #pragma unroll
                    for (int ms = 0; ms < 4; ++ms)
                        #pragma unroll
                        for (int e = 0; e < 4; ++e) Pagg[ms][e] += T[ms][e];
                }
            }
        }
        // carry-out: starts 60..63 = (lq==3, ms==3, e)
        #pragma unroll
        for (int i = 0; i < 4; ++i)
            #pragma unroll
            for (int e = 0; e < 4; ++e)
                if (cls >= 4 + i - e) carry[i] += Pc[3][e];
    };

    // PV over Vs with A-frags from float P[4][4]
    auto pv32 = [&](const float P[4][4]) {
        unsigned int w[8];
        #pragma unroll
        for (int ms = 0; ms < 4; ++ms) {
            asm("v_cvt_pk_bf16_f32 %0, %1, %2" : "=v"(w[2*ms])   : "v"(P[ms][0]), "v"(P[ms][1]));
            asm("v_cvt_pk_bf16_f32 %0, %1, %2" : "=v"(w[2*ms+1]) : "v"(P[ms][2]), "v"(P[ms][3]));
        }
        union FR { unsigned int u[4]; bf16x8 v; };
        FR f0, f1;
        f0.u[0] = w[0]; f0.u[1] = w[1]; f0.u[2] = w[2]; f0.u[3] = w[3];
        f1.u[0] = w[4]; f1.u[1] = w[5]; f1.u[2] = w[6]; f1.u[3] = w[7];
        const bf16x8 pf0 = f0.v, pf1 = f1.v;
        __builtin_amdgcn_s_setprio(1);
        #pragma unroll
        for (int dt = 0; dt < 16; ++dt) {
            const int d = dt * 16 + l15;
            const int p0 = lq ^ (d & 7);
            const int p1 = (lq + 4) ^ (d & 7);
            oacc[dt] = __builtin_amdgcn_mfma_f32_16x16x32_bf16(
                           pf0, *(const bf16x8*)&Vs[d * 64 + p0 * 8], oacc[dt], 0, 0, 0);
            oacc[dt] = __builtin_amdgcn_mfma_f32_16x16x32_bf16(
                           pf1, *(const bf16x8*)&Vs[d * 64 + p1 * 8], oacc[dt], 0, 0, 0);
        }
        __builtin_amdgcn_s_setprio(0);
    };

    // ---- 3 full tiles x 5 QK classes + 1 PV each ----
    for (int ti = 0; ti < 3; ++ti) {
        const int st0 = ti * 64;
        // carry-in: prev tile's spill -> this tile's starts 0..3 (lq==0, ms==0)
        {
            float pin0 = __shfl(carry[0], (lane + 48) & 63);
            float pin1 = __shfl(carry[1], (lane + 48) & 63);
            float pin2 = __shfl(carry[2], (lane + 48) & 63);
            float pin3 = __shfl(carry[3], (lane + 48) & 63);
            #pragma unroll
            for (int ms = 0; ms < 4; ++ms)
                #pragma unroll
                for (int e = 0; e < 4; ++e) Pagg[ms][e] = 0.f;
            if (lq == 0) {
                Pagg[0][0] = pin0; Pagg[0][1] = pin1; Pagg[0][2] = pin2; Pagg[0][3] = pin3;
            }
            #pragma unroll
            for (int e = 0; e < 4; ++e) carry[e] = 0.f;
        }
        #pragma unroll
        for (int cls = 0; cls < 5; ++cls) {
            // prefetch sigma-swapped K rows (+cls); raw V rows at cls==0 (once/tile)
            u16x8 kf[4];
            #pragma unroll
            for (int k4 = 0; k4 < 4; ++k4)
                kf[k4] = *(const u16x8*)(kbh + (size_t)(st0 + srow + 4 * k4 + cls) * DH + dc * 8);
            u16x8 vc[4];
            if (cls == 0) {
                const ushort_t* vrow = vtb + (size_t)vd * LSEQ + st0 + vh * 32;
                #pragma unroll
                for (int c2 = 0; c2 < 4; ++c2) vc[c2] = *(const u16x8*)(vrow + c2 * 8);
            }
            __syncthreads();   // previous step's frag reads done

            // K pooled: running max in Ks (in-place RMW), 4 positions/thread
            #pragma unroll
            for (int k4 = 0; k4 < 4; ++k4) {
                ushort_t* kp = &Ks[kOff(k4)];
                *(u16x8*)kp = (cls == 0) ? kf[k4] : bmax8(*(const u16x8*)kp, kf[k4]);
            }
            // raw V staged once per tile: natural chunk cg -> kpos chunk (cg&1)*4+(cg>>1)
            if (cls == 0) {
                #pragma unroll
                for (int cl = 0; cl < 4; ++cl) {
                    const int cg = vh * 4 + cl;
                    storeVchunk((cg & 1) * 4 + (cg >> 1), vc[cl]);
                }
            }
            __syncthreads();

            f32x4 sacc[4];
            qk(sacc);
            smClass(sacc, cls);
            if (cls == 4) pv32(Pagg);   // one PV over raw V for the whole tile
        }
    }

    // ---- tail step: pooled tail K (PHYSICAL layout) + tail V via kpos table ----
    {
        __syncthreads();   // previous step's frag reads (incl. PV) done
        // K: threads with mb<8 cover physical slots k8*8+mb (cls=k8, off=mb)
        if (mb < 8) {
            u16x8 krun = *(const u16x8*)(kbh + (size_t)(192 + mb) * DH + dc * 8);
            const u16x8 kz = {0,0,0,0,0,0,0,0};
            #pragma unroll
            for (int k8 = 0; k8 < 8; ++k8) {
                const bool vv = (k8 <= 4) && (mb <= 7 - k8);
                if (k8 > 0 && vv)
                    krun = bmax8(krun, *(const u16x8*)(kbh + (size_t)(192 + mb + k8) * DH + dc * 8));
                int slot = k8 * 8 + mb;
                *(u16x8*)&Ks[slot * 256 + ((dc ^ (slot & 15)) * 8)] = vv ? krun : kz;
            }
        }
        // V: kpos chunk kc holds (cls,off) per derived map; kc==6 o<4 = raw V[192..195]
        {
            u16x8 v0 = *(const u16x8*)(vtb + (size_t)vd * LSEQ + 192);
            float f[8];
            #pragma unroll
            for (int e = 0; e < 8; ++e) f[e] = b2f(v0[e]);
            #pragma unroll
            for (int ck = 0; ck < 4; ++ck) {
                const int kc = vh * 4 + ck;
                const int cls_lo = 4 * (kc >> 2) + ((kc >> 1) & 1);
                const int offb = 4 * (kc & 1);
                u16x8 ov;
                #pragma unroll
                for (int o = 0; o < 8; ++o) {
                    const int cls = cls_lo + 2 * (o >> 2);
                    const int off = offb + (o & 3);
                    ushort_t val = 0;
                    if (cls <= 4 && off <= 7 - cls) {
                        float a = 0.f;
                        #pragma unroll
                        for (int u = 0; u <= 4; ++u)
                            if (u <= cls) a += f[off + u];
                        val = f2b(a);
                    }
                    if (kc == 6 && o < 4) val = v0[o];   // raw V for carry slots
                    ov[o] = val;
                }
                storeVchunk(kc, ov);
            }
        }
        __syncthreads();

        // tail compute: QK (physical slots), softmax + carry injection, PV
        f32x4 sacc[4];
        qk(sacc);
        float pullc[4];
        #pragma unroll
        for (int e = 0; e < 4; ++e) pullc[e] = __shfl(carry[e], (lane + 16) & 63);
        float Pt[4][4];
        #pragma unroll
        for (int ms = 0; ms < 4; ++ms)
            #pragma unroll
            for (int e = 0; e < 4; ++e) {
                const int slot = ms * 16 + 4 * lq + e;   // PHYSICAL slot = 8*cls + off
                const bool inval = ((slot & 7) > 7 - (slot >> 3)) || ((slot >> 3) > 4);
                float pe = __builtin_exp2f(inval ? -1e30f : sacc[ms][e]);
                l4[e] += pe;           // carry slots are invalid -> pe==0 here
                float pfrag = pe;
                if (ms == 2 && lq == 2) pfrag = pullc[e];   // pairs with raw V in kc 6
                Pt[ms][e] = pfrag;
            }
        pv32(Pt);
    }

    // epilogue: reduce l over the 4 lq groups, invert, redistribute
    float l_part = (l4[0] + l4[1]) + (l4[2] + l4[3]);
    l_part += __shfl_xor(l_part, 16);
    l_part += __shfl_xor(l_part, 32);
    const float inv = 1.f / l_part;

    ushort_t* ob = O + ((size_t)b * LSEQ) * HD + h * DH;
    #pragma unroll
    for (int e = 0; e < 4; ++e) {
        const int q = q0 + wave * 16 + 4 * lq + e;
        const float linv = __shfl(inv, 4 * lq + e);
        if (q < LSEQ) {
            #pragma unroll
            for (int dt = 0; dt < 16; ++dt)
                ob[(size_t)q * HD + dt * 16 + l15] = f2b(oacc[dt][e] * linv);
        }
    }
}

// ================= fused prep: hidden f32->bf16 + 6 weight transposes ==========
// Grid layout (block-uniform jobs): [0,3200) cvt hidden; then wtrans tiles:
// Wq 512, Wk 512, Wv 512, Wo 512, W1 256, W2 256. Total 5760 blocks.
__global__ __launch_bounds__(256) void prep_all(
    const float* __restrict__ hidden, ushort_t* __restrict__ hb,
    const float* __restrict__ Wq, ushort_t* __restrict__ WtQ,
    const float* __restrict__ Wk, ushort_t* __restrict__ WtK,
    const float* __restrict__ Wv, ushort_t* __restrict__ WtV,
    const float* __restrict__ Wo, ushort_t* __restrict__ WtO,
    const float* __restrict__ W1, ushort_t* __restrict__ Wt1,
    const float* __restrict__ W2, ushort_t* __restrict__ Wt2)
{
    __shared__ float tile[32][33];
    int bid = blockIdx.x;
    const int t = threadIdx.x;
    if (bid < 3200) {                      // cvt hidden
        const int i = (bid * 256 + t) * 4;
        float4 v = *(const float4*)(hidden + i);
        ushort4 o;
        o.x = f2b(v.x); o.y = f2b(v.y); o.z = f2b(v.z); o.w = f2b(v.w);
        *(ushort4*)(hb + i) = o;
        return;
    }
    bid -= 3200;
    const float* W; ushort_t* Wt; int K, N;
    if (bid < 512)       {             W = Wq; Wt = WtQ; K = HID;     N = HD;      }
    else if (bid < 1024) { bid -= 512; W = Wk; Wt = WtK; K = HID;     N = HD;      }
    else if (bid < 1536) { bid -= 1024; W = Wv; Wt = WtV; K = HID;    N = HD;      }
    else if (bid < 2048) { bid -= 1536; W = Wo; Wt = WtO; K = HD;     N = HID;     }
    else if (bid < 2304) { bid -= 2048; W = W1; Wt = Wt1; K = HID;    N = 4 * HID; }
    else                 { bid -= 2304; W = W2; Wt = Wt2; K = 4 * HID; N = HID;    }
    const int ntx = N / 32;
    const int n0 = (bid % ntx) * 32, k0 = (bid / ntx) * 32;
    const int tx = t & 31, ty = t >> 5;
    #pragma unroll
    for (int s = 0; s < 4; ++s)
        tile[ty + 8 * s][tx] = W[(size_t)(k0 + ty + 8 * s) * N + n0 + tx];
    __syncthreads();
    #pragma unroll
    for (int s = 0; s < 4; ++s)
        Wt[(size_t)(n0 + ty + 8 * s) * K + k0 + tx] = f2b(tile[tx][ty + 8 * s]);
}

// ================= launch =================
extern "C" void kernel_launch(void* const* d_in, const int* in_sizes, int n_in,
                              void* d_out, int out_size, void* d_ws, size_t ws_size,
                              hipStream_t stream) {
    const float* hidden = (const float*)d_in[1];
    const float* Wq = (const float*)d_in[2];  const float* bq = (const float*)d_in[3];
    const float* Wk = (const float*)d_in[4];  const float* bk = (const float*)d_in[5];
    const float* Wv = (const float*)d_in[6];  const float* bv = (const float*)d_in[7];
    const float* Wo = (const float*)d_in[8];  const float* bo = (const float*)d_in[9];
    const float* W1 = (const float*)d_in[10]; const float* b1 = (const float*)d_in[11];
    const float* W2 = (const float*)d_in[12]; const float* b2 = (const float*)d_in[13];
    float* out = (float*)d_out;

    constexpr size_t SZ_BF   = (size_t)MROWS * HD * 2;      // 52,428,800
    constexpr size_t SZ_HBF  = (size_t)MROWS * HID * 2;     // 6,553,600
    constexpr size_t SZ_WQKV = (size_t)HID * HD * 2;        // 1,048,576
    constexpr size_t SZ_W12  = (size_t)HID * 4 * HID * 2;   // 524,288
    char* ws = (char*)d_ws;
    size_t off = 0;
    ushort_t* kb   = (ushort_t*)(ws + off); off += SZ_BF;   // K head-major [b,h][l][d]
    ushort_t* vt   = (ushort_t*)(ws + off); off += SZ_BF;   // V transposed  [b,h][d][l]
    ushort_t* qo   = (ushort_t*)(ws + off); off += SZ_BF;   // q / attn-out / ffn1
    ushort_t* hb   = (ushort_t*)(ws + off); off += SZ_HBF;  // hidden bf16
    ushort_t* at1  = (ushort_t*)(ws + off); off += SZ_HBF;
    ushort_t* at2  = (ushort_t*)(ws + off); off += SZ_HBF;
    ushort_t* proj = (ushort_t*)(ws + off); off += SZ_HBF;  // (unused in v24)
    ushort_t* WtQ  = (ushort_t*)(ws + off); off += SZ_WQKV; // WtQ/WtK/WtV contiguous!
    ushort_t* WtK  = (ushort_t*)(ws + off); off += SZ_WQKV;
    ushort_t* WtV  = (ushort_t*)(ws + off); off += SZ_WQKV;
    ushort_t* WtO  = (ushort_t*)(ws + off); off += SZ_WQKV;
    ushort_t* Wt1  = (ushort_t*)(ws + off); off += SZ_W12;
    ushort_t* Wt2  = (ushort_t*)(ws + off); off += SZ_W12;
    if (ws_size < off) return;  // total == 188,743,680 B (same as passing R3/R5-R11)
    ushort_t* ffn1 = qo;        // alias: qo free after out-proj2
    (void)proj;

    dim3 blk(256);
    prep_all<<<5760, blk, 0, stream>>>(hidden, hb, Wq, WtQ, Wk, WtK, Wv, WtV,
                                       Wo, WtO, W1, Wt1, W2, Wt2);

    const dim3 gQKV(3 * HD / 128, MROWS / 128);     // 48 x 100
    const dim3 gProj(HD / 128, MROWS / 128);        // 16 x 100
    const dim3 gF1(4 * HID / 128, MROWS / 128);     // 8 x 100

    // fused Q/K/V projection (Q pre-scaled; K head-major; V transposed head-major)
    gemm_qkv<<<gQKV, blk, 0, stream>>>(hb, WtQ, bq, bk, bv, qo, kb, vt);

    // MHA1: attn -> fused out-proj + residual(hidden f32) + LN -> at1
    attn_mfma21<<<2 * BATCH * NH, 512, 0, stream>>>(qo, kb, vt, qo);
    gemm_out_ln<float, ushort_t><<<MROWS / 64, 512, 0, stream>>>(qo, WtO, bo, hidden, at1, HD);

    // MHA2: Q proj from at1; attn; fused out-proj + residual(at1) + LN -> at2
    gemm_bt<false, true><<<gProj, blk, 0, stream>>>(at1, WtQ, bq, qo, MROWS, HD, HID);
    attn_mfma21<<<2 * BATCH * NH, 512, 0, stream>>>(qo, kb, vt, qo);
    gemm_out_ln<ushort_t, ushort_t><<<MROWS / 64, 512, 0, stream>>>(qo, WtO, bo, at1, at2, HD);

    // FFN: W1+ReLU; fused W2 + residual(at2) + LN -> out (f32)
    gemm_bt<true, false><<<gF1, blk, 0, stream>>>(at2, Wt1, b1, ffn1, MROWS, 4 * HID, HID);
    gemm_out_ln<ushort_t, float><<<MROWS / 64, 512, 0, stream>>>(ffn1, Wt2, b2, at2, out, 4 * HID);
}

// Round 15
// 799.195 us; speedup vs baseline: 1.4597x; 1.0192x over previous
//
#include <hip/hip_runtime.h>
#include <hip/hip_bf16.h>
#include <cstdint>
#include <cstddef>

// Problem constants
#define BATCH 64
#define LSEQ 200
#define HID 256
#define NH 8
#define DH 256            // per-head dim = HID
#define HD (NH*DH)        // 2048
#define MROWS (BATCH*LSEQ)   // 12800
#define EPS 1e-5f
#define CSCALE 0.09014195f   // (1/sqrt(256)) * log2(e), folded into Q projection

typedef unsigned short ushort_t;
typedef __attribute__((ext_vector_type(8))) short bf16x8;         // MFMA A/B frag (4 VGPR)
typedef __attribute__((ext_vector_type(8))) unsigned short u16x8; // 16B of bf16
typedef __attribute__((ext_vector_type(4))) float f32x4;          // MFMA C/D frag

__device__ __forceinline__ float b2f(ushort_t u) {
    union { unsigned int i; float f; } c; c.i = ((unsigned int)u) << 16; return c.f;
}
__device__ __forceinline__ ushort_t f2b(float f) {
    __hip_bfloat16 h = __float2bfloat16(f);
    union { __hip_bfloat16 h; ushort_t u; } c; c.h = h; return c.u;
}
__device__ __forceinline__ float to_f32(float x) { return x; }
__device__ __forceinline__ float to_f32(ushort_t x) { return b2f(x); }
__device__ __forceinline__ void store_val(float* p, float v) { *p = v; }
__device__ __forceinline__ void store_val(ushort_t* p, float v) { *p = f2b(v); }

// packed bf16 max on 8 elements
__device__ __forceinline__ u16x8 bmax8(u16x8 a, u16x8 b) {
    union U { u16x8 v; __hip_bfloat162 h[4]; };
    U ua, ub, r; ua.v = a; ub.v = b;
    #pragma unroll
    for (int i = 0; i < 4; ++i) r.h[i] = __hmax2(ua.h[i], ub.h[i]);
    return r.v;
}

// async global->LDS, 16 bytes per lane (LDS dest = wave-uniform base + lane*16)
__device__ __forceinline__ void gll16(const void* g, void* l) {
    __builtin_amdgcn_global_load_lds(
        (const __attribute__((address_space(1))) unsigned int*)g,
        (__attribute__((address_space(3))) unsigned int*)l, 16, 0, 0);
}

// ================= bf16 MFMA GEMM:  C[M,N] = A[M,K] @ Bt[N,K]^T + bias =================
// 128x128 tile, BK=128 (v25: K=256 callers -> 2 K-iterations, barriers halved),
// 4 waves (2x2 of 64x64), global_load_lds staging, 16-chunk XOR swizzle
// (phys chunk = logical ^ (row&15); 16-lane frag reads are 2-way = free).
template<bool RELU, bool SCALEC>
__global__ __launch_bounds__(256) void gemm_bt(
    const ushort_t* __restrict__ A, const ushort_t* __restrict__ Bt,
    const float* __restrict__ bias, ushort_t* __restrict__ C,
    int M, int N, int K)
{
    __shared__ ushort_t As[128 * 128];    // 32 KB
    __shared__ ushort_t Bs[128 * 128];    // 32 KB
    const int t = threadIdx.x;
    const int m0 = blockIdx.y * 128, n0 = blockIdx.x * 128;
    const int wave = t >> 6, lane = t & 63;
    const int l15 = lane & 15, lq = lane >> 4;
    const int wr = wave >> 1, wc = wave & 1;

    f32x4 acc[4][4];
    #pragma unroll
    for (int i = 0; i < 4; ++i)
        #pragma unroll
        for (int j = 0; j < 4; ++j) acc[i][j] = (f32x4){0.f, 0.f, 0.f, 0.f};

    for (int k0 = 0; k0 < K; k0 += 128) {
        __syncthreads();
        #pragma unroll
        for (int i = 0; i < 8; ++i) {      // stage A (8 x 16B per thread)
            int li = i * 256 + t;
            int ml = li >> 4, cp = li & 15;
            int cg = cp ^ (ml & 15);
            gll16(A + (size_t)(m0 + ml) * K + k0 + cg * 8, &As[li * 8]);
        }
        #pragma unroll
        for (int i = 0; i < 8; ++i) {      // stage B
            int li = i * 256 + t;
            int nl = li >> 4, cp = li & 15;
            int cg = cp ^ (nl & 15);
            gll16(Bt + (size_t)(n0 + nl) * K + k0 + cg * 8, &Bs[li * 8]);
        }
        __syncthreads();
        #pragma unroll
        for (int ks = 0; ks < 4; ++ks) {   // four K=32 sub-steps per staged tile
            bf16x8 af[4], bfr[4];
            #pragma unroll
            for (int i = 0; i < 4; ++i) {
                int r = wr * 64 + i * 16 + l15;
                int pc = (ks * 4 + lq) ^ (r & 15);
                af[i] = *(const bf16x8*)&As[r * 128 + pc * 8];
            }
            #pragma unroll
            for (int j = 0; j < 4; ++j) {
                int r = wc * 64 + j * 16 + l15;
                int pc = (ks * 4 + lq) ^ (r & 15);
                bfr[j] = *(const bf16x8*)&Bs[r * 128 + pc * 8];
            }
            #pragma unroll
            for (int i = 0; i < 4; ++i)
                #pragma unroll
                for (int j = 0; j < 4; ++j)
                    acc[i][j] = __builtin_amdgcn_mfma_f32_16x16x32_bf16(af[i], bfr[j], acc[i][j], 0, 0, 0);
        }
    }
    #pragma unroll
    for (int i = 0; i < 4; ++i) {
        #pragma unroll
        for (int e = 0; e < 4; ++e) {
            int m = m0 + wr * 64 + i * 16 + 4 * lq + e;
            #pragma unroll
            for (int j = 0; j < 4; ++j) {
                int n = n0 + wc * 64 + j * 16 + l15;
                float v = acc[i][j][e] + bias[n];
                if (RELU) v = fmaxf(v, 0.f);
                if (SCALEC) v *= CSCALE;
                C[(size_t)m * N + n] = f2b(v);
            }
        }
    }
}

// ================= fused QKV projection (BK=128) =================
// One GEMM over N = 3*2048: Bt = [WtQ; WtK; WtV] (contiguous in ws). Segment
// (block-uniform, seg = n0>>11) selects the validated epilogue path.
__global__ __launch_bounds__(256) void gemm_qkv(
    const ushort_t* __restrict__ A, const ushort_t* __restrict__ Bt,
    const float* __restrict__ bq, const float* __restrict__ bk,
    const float* __restrict__ bv,
    ushort_t* __restrict__ Cq, ushort_t* __restrict__ Ck, ushort_t* __restrict__ Cv)
{
    constexpr int K = HID;                 // 256
    __shared__ ushort_t As[128 * 128];
    __shared__ ushort_t Bs[128 * 128];
    const int t = threadIdx.x;
    const int m0 = blockIdx.y * 128, n0 = blockIdx.x * 128;
    const int wave = t >> 6, lane = t & 63;
    const int l15 = lane & 15, lq = lane >> 4;
    const int wr = wave >> 1, wc = wave & 1;

    f32x4 acc[4][4];
    #pragma unroll
    for (int i = 0; i < 4; ++i)
        #pragma unroll
        for (int j = 0; j < 4; ++j) acc[i][j] = (f32x4){0.f, 0.f, 0.f, 0.f};

    for (int k0 = 0; k0 < K; k0 += 128) {
        __syncthreads();
        #pragma unroll
        for (int i = 0; i < 8; ++i) {
            int li = i * 256 + t;
            int ml = li >> 4, cp = li & 15;
            int cg = cp ^ (ml & 15);
            gll16(A + (size_t)(m0 + ml) * K + k0 + cg * 8, &As[li * 8]);
        }
        #pragma unroll
        for (int i = 0; i < 8; ++i) {
            int li = i * 256 + t;
            int nl = li >> 4, cp = li & 15;
            int cg = cp ^ (nl & 15);
            gll16(Bt + (size_t)(n0 + nl) * K + k0 + cg * 8, &Bs[li * 8]);
        }
        __syncthreads();
        #pragma unroll
        for (int ks = 0; ks < 4; ++ks) {
            bf16x8 af[4], bfr[4];
            #pragma unroll
            for (int i = 0; i < 4; ++i) {
                int r = wr * 64 + i * 16 + l15;
                int pc = (ks * 4 + lq) ^ (r & 15);
                af[i] = *(const bf16x8*)&As[r * 128 + pc * 8];
            }
            #pragma unroll
            for (int j = 0; j < 4; ++j) {
                int r = wc * 64 + j * 16 + l15;
                int pc = (ks * 4 + lq) ^ (r & 15);
                bfr[j] = *(const bf16x8*)&Bs[r * 128 + pc * 8];
            }
            #pragma unroll
            for (int i = 0; i < 4; ++i)
                #pragma unroll
                for (int j = 0; j < 4; ++j)
                    acc[i][j] = __builtin_amdgcn_mfma_f32_16x16x32_bf16(af[i], bfr[j], acc[i][j], 0, 0, 0);
        }
    }

    const int seg = n0 >> 11;              // 0=Q, 1=K, 2=V (block-uniform)
    const int nb = n0 & 2047;              // segment-local n0
    if (seg == 2) {
        // V transposed head-major [b,h][d][l]; 200%4==0 so mbase 4-aligned rows pack
        #pragma unroll
        for (int i = 0; i < 4; ++i) {
            int mbase = m0 + wr * 64 + i * 16 + 4 * lq;
            int bb = (int)(((unsigned)mbase * 5243u) >> 20);    // mbase/200
            int ll = mbase - bb * 200;
            #pragma unroll
            for (int j = 0; j < 4; ++j) {
                int nn = nb + wc * 64 + j * 16 + l15;
                float bsv = bv[nn];
                ushort4 o4;
                o4.x = f2b(acc[i][j][0] + bsv); o4.y = f2b(acc[i][j][1] + bsv);
                o4.z = f2b(acc[i][j][2] + bsv); o4.w = f2b(acc[i][j][3] + bsv);
                size_t addr = ((size_t)(bb * NH + (nn >> 8)) * 256 + (nn & 255)) * LSEQ + ll;
                *(ushort4*)&Cv[addr] = o4;
            }
        }
    } else if (seg == 1) {
        // K head-major [b,h][l][d]
        #pragma unroll
        for (int i = 0; i < 4; ++i) {
            #pragma unroll
            for (int e = 0; e < 4; ++e) {
                int m = m0 + wr * 64 + i * 16 + 4 * lq + e;
                int bb = (int)(((unsigned)m * 5243u) >> 20);
                int ll = m - bb * 200;
                #pragma unroll
                for (int j = 0; j < 4; ++j) {
                    int nn = nb + wc * 64 + j * 16 + l15;
                    float v = acc[i][j][e] + bk[nn];
                    size_t addr = ((((size_t)(bb * NH + (nn >> 8))) * LSEQ + ll) << 8) + (nn & 255);
                    Ck[addr] = f2b(v);
                }
            }
        }
    } else {
        // Q row-major [m][2048], pre-scaled by CSCALE
        #pragma unroll
        for (int i = 0; i < 4; ++i) {
            #pragma unroll
            for (int e = 0; e < 4; ++e) {
                int m = m0 + wr * 64 + i * 16 + 4 * lq + e;
                #pragma unroll
                for (int j = 0; j < 4; ++j) {
                    int nn = nb + wc * 64 + j * 16 + l15;
                    float v = (acc[i][j][e] + bq[nn]) * CSCALE;
                    Cq[(size_t)m * HD + nn] = f2b(v);
                }
            }
        }
    }
}

// ================= fused N=256 GEMM + residual + LayerNorm (BK=128) =================
// BM=64, BN=256 (full N -> complete rows per block), 512 threads / 8 waves (2m x 4n),
// grid 200. BK=128 halves barriers (K=2048: 32->16 staged tiles). LDS 82 KB -> 1
// block/CU, free since grid 200 < 256 CUs. Epilogue: v = acc + bias + R; row stats
// via l15-shuffles + LDS table; Out = (v-mean)*rsqrt(var+EPS).
template<typename TR, typename TO>
__global__ __launch_bounds__(512, 1) void gemm_out_ln(
    const ushort_t* __restrict__ A, const ushort_t* __restrict__ Bt,
    const float* __restrict__ bias, const TR* __restrict__ R,
    TO* __restrict__ Out, int K)
{
    __shared__ ushort_t As[64 * 128];      // 16 KB
    __shared__ ushort_t Bs[256 * 128];     // 64 KB
    __shared__ float rs[64][4], rq[64][4]; // 2 KB row-stat partials (per wc)
    const int t = threadIdx.x;
    const int m0 = blockIdx.x * 64;
    const int wave = t >> 6, lane = t & 63;
    const int l15 = lane & 15, lq = lane >> 4;
    const int wr = wave >> 2, wc = wave & 3;   // 2m x 4n

    f32x4 acc[2][4];
    #pragma unroll
    for (int i = 0; i < 2; ++i)
        #pragma unroll
        for (int j = 0; j < 4; ++j) acc[i][j] = (f32x4){0.f, 0.f, 0.f, 0.f};

    for (int k0 = 0; k0 < K; k0 += 128) {
        __syncthreads();
        #pragma unroll
        for (int i = 0; i < 2; ++i) {       // stage A (2 x 16B per thread; 64 rows)
            int li = i * 512 + t;
            int ml = li >> 4, cp = li & 15;
            int cg = cp ^ (ml & 15);
            gll16(A + (size_t)(m0 + ml) * K + k0 + cg * 8, &As[li * 8]);
        }
        #pragma unroll
        for (int i = 0; i < 8; ++i) {       // stage B (8 x 16B per thread; 256 rows)
            int li = i * 512 + t;
            int nl = li >> 4, cp = li & 15;
            int cg = cp ^ (nl & 15);
            gll16(Bt + (size_t)nl * K + k0 + cg * 8, &Bs[li * 8]);
        }
        __syncthreads();
        #pragma unroll
        for (int ks = 0; ks < 4; ++ks) {
            bf16x8 af[2], bfr[4];
            #pragma unroll
            for (int i = 0; i < 2; ++i) {
                int r = wr * 32 + i * 16 + l15;
                int pc = (ks * 4 + lq) ^ (r & 15);
                af[i] = *(const bf16x8*)&As[r * 128 + pc * 8];
            }
            #pragma unroll
            for (int j = 0; j < 4; ++j) {
                int r = wc * 64 + j * 16 + l15;
                int pc = (ks * 4 + lq) ^ (r & 15);
                bfr[j] = *(const bf16x8*)&Bs[r * 128 + pc * 8];
            }
            #pragma unroll
            for (int i = 0; i < 2; ++i)
                #pragma unroll
                for (int j = 0; j < 4; ++j)
                    acc[i][j] = __builtin_amdgcn_mfma_f32_16x16x32_bf16(af[i], bfr[j], acc[i][j], 0, 0, 0);
        }
    }

    // epilogue: v = acc + bias + R (rows m = m0 + wr*32 + i*16 + 4*lq + e)
    float v[2][4][4];
    #pragma unroll
    for (int i = 0; i < 2; ++i)
        #pragma unroll
        for (int e = 0; e < 4; ++e) {
            const int m = m0 + wr * 32 + i * 16 + 4 * lq + e;
            #pragma unroll
            for (int j = 0; j < 4; ++j) {
                const int n = wc * 64 + j * 16 + l15;
                v[i][j][e] = acc[i][j][e] + bias[n] + to_f32(R[(size_t)m * HID + n]);
            }
        }
    // per-row partial sums over this wave's 64 cols -> reduce across the 16 l15 lanes
    #pragma unroll
    for (int i = 0; i < 2; ++i)
        #pragma unroll
        for (int e = 0; e < 4; ++e) {
            float s = (v[i][0][e] + v[i][1][e]) + (v[i][2][e] + v[i][3][e]);
            float q = (v[i][0][e] * v[i][0][e] + v[i][1][e] * v[i][1][e])
                    + (v[i][2][e] * v[i][2][e] + v[i][3][e] * v[i][3][e]);
            #pragma unroll
            for (int o = 1; o < 16; o <<= 1) {
                s += __shfl_xor(s, o);
                q += __shfl_xor(q, o);
            }
            if (l15 == 0) {
                const int row = wr * 32 + i * 16 + 4 * lq + e;
                rs[row][wc] = s; rq[row][wc] = q;
            }
        }
    __syncthreads();
    #pragma unroll
    for (int i = 0; i < 2; ++i)
        #pragma unroll
        for (int e = 0; e < 4; ++e) {
            const int row = wr * 32 + i * 16 + 4 * lq + e;
            const float s = (rs[row][0] + rs[row][1]) + (rs[row][2] + rs[row][3]);
            const float q = (rq[row][0] + rq[row][1]) + (rq[row][2] + rq[row][3]);
            const float mean = s * (1.f / HID);
            const float var  = q * (1.f / HID) - mean * mean;
            const float rstd = rsqrtf(var + EPS);
            const int m = m0 + row;
            #pragma unroll
            for (int j = 0; j < 4; ++j) {
                const int n = wc * 64 + j * 16 + l15;
                store_val(&Out[(size_t)m * HID + n], (v[i][j][e] - mean) * rstd);
            }
        }
}

// ================= fused area-attention v21 (proven 275 us/dispatch) =================
__global__ __launch_bounds__(512, 2) void attn_mfma21(
    const ushort_t* __restrict__ Q, const ushort_t* __restrict__ Khm,
    const ushort_t* __restrict__ Vt, ushort_t* __restrict__ O)  // O may alias Q
{
    const int id = blockIdx.x;
    const int xcd = id & 7, slot_ = id >> 3;    // 1024 blocks: 8 xcd x 128 slots
    const int qt = slot_ & 1;
    const int bh = ((slot_ >> 1) << 3) + xcd;   // both q-blocks of bh share an XCD
    const int b = bh >> 3, h = bh & 7;
    const int q0 = qt * 128;
    const int t = threadIdx.x;
    const int wave = t >> 6, lane = t & 63;
    const int l15 = lane & 15, lq = lane >> 4;

    __shared__ ushort_t Ks[64 * 256];      // pooled K (sigma rows), chunk ^ (m&15), 32 KB
    __shared__ ushort_t Vs[256 * 64];      // V [d][kpos], chunk ^ (d&7), 32 KB

    const ushort_t* kbh = Khm + (size_t)bh * LSEQ * DH;
    const ushort_t* vtb = Vt + (size_t)bh * DH * LSEQ;   // [d][l]
    const ushort_t* qbh = Q + ((size_t)b * LSEQ) * HD + h * DH;
    const int qrow = q0 + wave * 16 + l15;

    // Q fragments (row=lane&15, k=8*quad+j); pre-scaled by CSCALE in GEMM.
    bf16x8 qf[8];
    if (qrow < LSEQ) {
        const ushort_t* qp = qbh + (size_t)qrow * HD + 8 * lq;
        #pragma unroll
        for (int g = 0; g < 8; ++g) qf[g] = *(const bf16x8*)(qp + 32 * g);
    } else {
        bf16x8 zf = {0,0,0,0,0,0,0,0};
        #pragma unroll
        for (int g = 0; g < 8; ++g) qf[g] = zf;
    }

    f32x4 oacc[16];
    #pragma unroll
    for (int i = 0; i < 16; ++i) oacc[i] = (f32x4){0.f, 0.f, 0.f, 0.f};
    float l4[4];
    #pragma unroll
    for (int e = 0; e < 4; ++e) l4[e] = 0.f;
    float carry[4];                        // Pagg spill into next tile's starts 0..3
    #pragma unroll
    for (int e = 0; e < 4; ++e) carry[e] = 0.f;
    float Pagg[4][4];

    // staging roles for 512 threads
    const int dc = t & 31, mb = t >> 5;      // K: lane->d-chunk, thread->4 positions
    const int vd = t >> 1, vh = t & 1;       // V: thread -> d row, half (4 chunks each)
    // sigma: physical position m = mb + 16*k4 holds pooled-K for start srow + 4*k4
    const int srow = ((mb >> 2) << 4) + (mb & 3);

    auto kOff = [&](int k4) {
        int m = mb + 16 * k4;
        return m * 256 + ((dc ^ (m & 15)) * 8);
    };
    auto storeVchunk = [&](int kc, u16x8 val) {   // full 16B, kpos chunk kc
        *(u16x8*)&Vs[vd * 64 + ((kc ^ (vd & 7)) * 8)] = val;
    };

    // QK on Ks -> sacc (swapped operands): sacc[ms][e] = S^T[phys row][q=l15]
    auto qk = [&](f32x4* sacc) {
        __builtin_amdgcn_s_setprio(1);
        #pragma unroll
        for (int ms = 0; ms < 4; ++ms) {
            f32x4 s = (f32x4){0.f, 0.f, 0.f, 0.f};
            const int row = ms * 16 + l15;
            #pragma unroll
            for (int g = 0; g < 8; ++g) {
                const int phys = (lq + 4 * g) ^ l15;
                s = __builtin_amdgcn_mfma_f32_16x16x32_bf16(
                        *(const bf16x8*)&Ks[row * 256 + phys * 8], qf[g], s, 0, 0, 0);
            }
            sacc[ms] = s;
        }
        __builtin_amdgcn_s_setprio(0);
    };

    // softmax for one class under start = lq*16 + 4*ms + e; shift1 = ONE shuffle
    auto smClass = [&](const f32x4* sacc, int cls) {
        float Pc[4][4];
        #pragma unroll
        for (int ms = 0; ms < 4; ++ms)
            #pragma unroll
            for (int e = 0; e < 4; ++e) {
                float pe = __builtin_exp2f(sacc[ms][e]);
                l4[e] += pe;
                Pc[ms][e] = pe;
                Pagg[ms][e] += pe;
            }
        if (cls >= 1) {
            float T[4][4];
            #pragma unroll
            for (int ms = 0; ms < 4; ++ms)
                #pragma unroll
                for (int e = 0; e < 4; ++e) T[ms][e] = Pc[ms][e];
            #pragma unroll
            for (int u = 1; u <= 4; ++u) {
                if (u <= cls) {
                    float up = __shfl(T[3][3], (lane - 16) & 63);
                    #pragma unroll
                    for (int ms = 3; ms >= 0; --ms) {
                        float nv = (ms > 0) ? T[ms - 1][3] : ((lq > 0) ? up : 0.f);
                        T[ms][3] = T[ms][2]; T[ms][2] = T[ms][1]; T[ms][1] = T[ms][0];
                        T[ms][0] = nv;
                    }
                    #pragma unroll
                    for (int ms = 0; ms < 4; ++ms)
                        #pragma unroll
                        for (int e = 0; e < 4; ++e) Pagg[ms][e] += T[ms][e];
                }
            }
        }
        // carry-out: starts 60..63 = (lq==3, ms==3, e)
        #pragma unroll
        for (int i = 0; i < 4; ++i)
            #pragma unroll
            for (int e = 0; e < 4; ++e)
                if (cls >= 4 + i - e) carry[i] += Pc[3][e];
    };

    // PV over Vs with A-frags from float P[4][4]
    auto pv32 = [&](const float P[4][4]) {
        unsigned int w[8];
        #pragma unroll
        for (int ms = 0; ms < 4; ++ms) {
            asm("v_cvt_pk_bf16_f32 %0, %1, %2" : "=v"(w[2*ms])   : "v"(P[ms][0]), "v"(P[ms][1]));
            asm("v_cvt_pk_bf16_f32 %0, %1, %2" : "=v"(w[2*ms+1]) : "v"(P[ms][2]), "v"(P[ms][3]));
        }
        union FR { unsigned int u[4]; bf16x8 v; };
        FR f0, f1;
        f0.u[0] = w[0]; f0.u[1] = w[1]; f0.u[2] = w[2]; f0.u[3] = w[3];
        f1.u[0] = w[4]; f1.u[1] = w[5]; f1.u[2] = w[6]; f1.u[3] = w[7];
        const bf16x8 pf0 = f0.v, pf1 = f1.v;
        __builtin_amdgcn_s_setprio(1);
        #pragma unroll
        for (int dt = 0; dt < 16; ++dt) {
            const int d = dt * 16 + l15;
            const int p0 = lq ^ (d & 7);
            const int p1 = (lq + 4) ^ (d & 7);
            oacc[dt] = __builtin_amdgcn_mfma_f32_16x16x32_bf16(
                           pf0, *(const bf16x8*)&Vs[d * 64 + p0 * 8], oacc[dt], 0, 0, 0);
            oacc[dt] = __builtin_amdgcn_mfma_f32_16x16x32_bf16(
                           pf1, *(const bf16x8*)&Vs[d * 64 + p1 * 8], oacc[dt], 0, 0, 0);
        }
        __builtin_amdgcn_s_setprio(0);
    };

    // ---- 3 full tiles x 5 QK classes + 1 PV each ----
    for (int ti = 0; ti < 3; ++ti) {
        const int st0 = ti * 64;
        // carry-in: prev tile's spill -> this tile's starts 0..3 (lq==0, ms==0)
        {
            float pin0 = __shfl(carry[0], (lane + 48) & 63);
            float pin1 = __shfl(carry[1], (lane + 48) & 63);
            float pin2 = __shfl(carry[2], (lane + 48) & 63);
            float pin3 = __shfl(carry[3], (lane + 48) & 63);
            #pragma unroll
            for (int ms = 0; ms < 4; ++ms)
                #pragma unroll
                for (int e = 0; e < 4; ++e) Pagg[ms][e] = 0.f;
            if (lq == 0) {
                Pagg[0][0] = pin0; Pagg[0][1] = pin1; Pagg[0][2] = pin2; Pagg[0][3] = pin3;
            }
            #pragma unroll
            for (int e = 0; e < 4; ++e) carry[e] = 0.f;
        }
        #pragma unroll
        for (int cls = 0; cls < 5; ++cls) {
            // prefetch sigma-swapped K rows (+cls); raw V rows at cls==0 (once/tile)
            u16x8 kf[4];
            #pragma unroll
            for (int k4 = 0; k4 < 4; ++k4)
                kf[k4] = *(const u16x8*)(kbh + (size_t)(st0 + srow + 4 * k4 + cls) * DH + dc * 8);
            u16x8 vc[4];
            if (cls == 0) {
                const ushort_t* vrow = vtb + (size_t)vd * LSEQ + st0 + vh * 32;
                #pragma unroll
                for (int c2 = 0; c2 < 4; ++c2) vc[c2] = *(const u16x8*)(vrow + c2 * 8);
            }
            __syncthreads();   // previous step's frag reads done

            // K pooled: running max in Ks (in-place RMW), 4 positions/thread
            #pragma unroll
            for (int k4 = 0; k4 < 4; ++k4) {
                ushort_t* kp = &Ks[kOff(k4)];
                *(u16x8*)kp = (cls == 0) ? kf[k4] : bmax8(*(const u16x8*)kp, kf[k4]);
            }
            // raw V staged once per tile: natural chunk cg -> kpos chunk (cg&1)*4+(cg>>1)
            if (cls == 0) {
                #pragma unroll
                for (int cl = 0; cl < 4; ++cl) {
                    const int cg = vh * 4 + cl;
                    storeVchunk((cg & 1) * 4 + (cg >> 1), vc[cl]);
                }
            }
            __syncthreads();

            f32x4 sacc[4];
            qk(sacc);
            smClass(sacc, cls);
            if (cls == 4) pv32(Pagg);   // one PV over raw V for the whole tile
        }
    }

    // ---- tail step: pooled tail K (PHYSICAL layout) + tail V via kpos table ----
    {
        __syncthreads();   // previous step's frag reads (incl. PV) done
        // K: threads with mb<8 cover physical slots k8*8+mb (cls=k8, off=mb)
        if (mb < 8) {
            u16x8 krun = *(const u16x8*)(kbh + (size_t)(192 + mb) * DH + dc * 8);
            const u16x8 kz = {0,0,0,0,0,0,0,0};
            #pragma unroll
            for (int k8 = 0; k8 < 8; ++k8) {
                const bool vv = (k8 <= 4) && (mb <= 7 - k8);
                if (k8 > 0 && vv)
                    krun = bmax8(krun, *(const u16x8*)(kbh + (size_t)(192 + mb + k8) * DH + dc * 8));
                int slot = k8 * 8 + mb;
                *(u16x8*)&Ks[slot * 256 + ((dc ^ (slot & 15)) * 8)] = vv ? krun : kz;
            }
        }
        // V: kpos chunk kc holds (cls,off) per derived map; kc==6 o<4 = raw V[192..195]
        {
            u16x8 v0 = *(const u16x8*)(vtb + (size_t)vd * LSEQ + 192);
            float f[8];
            #pragma unroll
            for (int e = 0; e < 8; ++e) f[e] = b2f(v0[e]);
            #pragma unroll
            for (int ck = 0; ck < 4; ++ck) {
                const int kc = vh * 4 + ck;
                const int cls_lo = 4 * (kc >> 2) + ((kc >> 1) & 1);
                const int offb = 4 * (kc & 1);
                u16x8 ov;
                #pragma unroll
                for (int o = 0; o < 8; ++o) {
                    const int cls = cls_lo + 2 * (o >> 2);
                    const int off = offb + (o & 3);
                    ushort_t val = 0;
                    if (cls <= 4 && off <= 7 - cls) {
                        float a = 0.f;
                        #pragma unroll
                        for (int u = 0; u <= 4; ++u)
                            if (u <= cls) a += f[off + u];
                        val = f2b(a);
                    }
                    if (kc == 6 && o < 4) val = v0[o];   // raw V for carry slots
                    ov[o] = val;
                }
                storeVchunk(kc, ov);
            }
        }
        __syncthreads();

        // tail compute: QK (physical slots), softmax + carry injection, PV
        f32x4 sacc[4];
        qk(sacc);
        float pullc[4];
        #pragma unroll
        for (int e = 0; e < 4; ++e) pullc[e] = __shfl(carry[e], (lane + 16) & 63);
        float Pt[4][4];
        #pragma unroll
        for (int ms = 0; ms < 4; ++ms)
            #pragma unroll
            for (int e = 0; e < 4; ++e) {
                const int slot = ms * 16 + 4 * lq + e;   // PHYSICAL slot = 8*cls + off
                const bool inval = ((slot & 7) > 7 - (slot >> 3)) || ((slot >> 3) > 4);
                float pe = __builtin_exp2f(inval ? -1e30f : sacc[ms][e]);
                l4[e] += pe;           // carry slots are invalid -> pe==0 here
                float pfrag = pe;
                if (ms == 2 && lq == 2) pfrag = pullc[e];   // pairs with raw V in kc 6
                Pt[ms][e] = pfrag;
            }
        pv32(Pt);
    }

    // epilogue: reduce l over the 4 lq groups, invert, redistribute
    float l_part = (l4[0] + l4[1]) + (l4[2] + l4[3]);
    l_part += __shfl_xor(l_part, 16);
    l_part += __shfl_xor(l_part, 32);
    const float inv = 1.f / l_part;

    ushort_t* ob = O + ((size_t)b * LSEQ) * HD + h * DH;
    #pragma unroll
    for (int e = 0; e < 4; ++e) {
        const int q = q0 + wave * 16 + 4 * lq + e;
        const float linv = __shfl(inv, 4 * lq + e);
        if (q < LSEQ) {
            #pragma unroll
            for (int dt = 0; dt < 16; ++dt)
                ob[(size_t)q * HD + dt * 16 + l15] = f2b(oacc[dt][e] * linv);
        }
    }
}

// ================= fused prep: hidden f32->bf16 + 6 weight transposes ==========
// Grid layout (block-uniform jobs): [0,3200) cvt hidden; then wtrans tiles:
// Wq 512, Wk 512, Wv 512, Wo 512, W1 256, W2 256. Total 5760 blocks.
__global__ __launch_bounds__(256) void prep_all(
    const float* __restrict__ hidden, ushort_t* __restrict__ hb,
    const float* __restrict__ Wq, ushort_t* __restrict__ WtQ,
    const float* __restrict__ Wk, ushort_t* __restrict__ WtK,
    const float* __restrict__ Wv, ushort_t* __restrict__ WtV,
    const float* __restrict__ Wo, ushort_t* __restrict__ WtO,
    const float* __restrict__ W1, ushort_t* __restrict__ Wt1,
    const float* __restrict__ W2, ushort_t* __restrict__ Wt2)
{
    __shared__ float tile[32][33];
    int bid = blockIdx.x;
    const int t = threadIdx.x;
    if (bid < 3200) {                      // cvt hidden
        const int i = (bid * 256 + t) * 4;
        float4 v = *(const float4*)(hidden + i);
        ushort4 o;
        o.x = f2b(v.x); o.y = f2b(v.y); o.z = f2b(v.z); o.w = f2b(v.w);
        *(ushort4*)(hb + i) = o;
        return;
    }
    bid -= 3200;
    const float* W; ushort_t* Wt; int K, N;
    if (bid < 512)       {             W = Wq; Wt = WtQ; K = HID;     N = HD;      }
    else if (bid < 1024) { bid -= 512; W = Wk; Wt = WtK; K = HID;     N = HD;      }
    else if (bid < 1536) { bid -= 1024; W = Wv; Wt = WtV; K = HID;    N = HD;      }
    else if (bid < 2048) { bid -= 1536; W = Wo; Wt = WtO; K = HD;     N = HID;     }
    else if (bid < 2304) { bid -= 2048; W = W1; Wt = Wt1; K = HID;    N = 4 * HID; }
    else                 { bid -= 2304; W = W2; Wt = Wt2; K = 4 * HID; N = HID;    }
    const int ntx = N / 32;
    const int n0 = (bid % ntx) * 32, k0 = (bid / ntx) * 32;
    const int tx = t & 31, ty = t >> 5;
    #pragma unroll
    for (int s = 0; s < 4; ++s)
        tile[ty + 8 * s][tx] = W[(size_t)(k0 + ty + 8 * s) * N + n0 + tx];
    __syncthreads();
    #pragma unroll
    for (int s = 0; s < 4; ++s)
        Wt[(size_t)(n0 + ty + 8 * s) * K + k0 + tx] = f2b(tile[tx][ty + 8 * s]);
}

// ================= launch =================
extern "C" void kernel_launch(void* const* d_in, const int* in_sizes, int n_in,
                              void* d_out, int out_size, void* d_ws, size_t ws_size,
                              hipStream_t stream) {
    const float* hidden = (const float*)d_in[1];
    const float* Wq = (const float*)d_in[2];  const float* bq = (const float*)d_in[3];
    const float* Wk = (const float*)d_in[4];  const float* bk = (const float*)d_in[5];
    const float* Wv = (const float*)d_in[6];  const float* bv = (const float*)d_in[7];
    const float* Wo = (const float*)d_in[8];  const float* bo = (const float*)d_in[9];
    const float* W1 = (const float*)d_in[10]; const float* b1 = (const float*)d_in[11];
    const float* W2 = (const float*)d_in[12]; const float* b2 = (const float*)d_in[13];
    float* out = (float*)d_out;

    constexpr size_t SZ_BF   = (size_t)MROWS * HD * 2;      // 52,428,800
    constexpr size_t SZ_HBF  = (size_t)MROWS * HID * 2;     // 6,553,600
    constexpr size_t SZ_WQKV = (size_t)HID * HD * 2;        // 1,048,576
    constexpr size_t SZ_W12  = (size_t)HID * 4 * HID * 2;   // 524,288
    char* ws = (char*)d_ws;
    size_t off = 0;
    ushort_t* kb   = (ushort_t*)(ws + off); off += SZ_BF;   // K head-major [b,h][l][d]
    ushort_t* vt   = (ushort_t*)(ws + off); off += SZ_BF;   // V transposed  [b,h][d][l]
    ushort_t* qo   = (ushort_t*)(ws + off); off += SZ_BF;   // q / attn-out / ffn1
    ushort_t* hb   = (ushort_t*)(ws + off); off += SZ_HBF;  // hidden bf16
    ushort_t* at1  = (ushort_t*)(ws + off); off += SZ_HBF;
    ushort_t* at2  = (ushort_t*)(ws + off); off += SZ_HBF;
    ushort_t* proj = (ushort_t*)(ws + off); off += SZ_HBF;  // (unused in v25)
    ushort_t* WtQ  = (ushort_t*)(ws + off); off += SZ_WQKV; // WtQ/WtK/WtV contiguous!
    ushort_t* WtK  = (ushort_t*)(ws + off); off += SZ_WQKV;
    ushort_t* WtV  = (ushort_t*)(ws + off); off += SZ_WQKV;
    ushort_t* WtO  = (ushort_t*)(ws + off); off += SZ_WQKV;
    ushort_t* Wt1  = (ushort_t*)(ws + off); off += SZ_W12;
    ushort_t* Wt2  = (ushort_t*)(ws + off); off += SZ_W12;
    if (ws_size < off) return;  // total == 188,743,680 B (same as passing R3/R5-R11)
    ushort_t* ffn1 = qo;        // alias: qo free after out-proj2
    (void)proj;

    dim3 blk(256);
    prep_all<<<5760, blk, 0, stream>>>(hidden, hb, Wq, WtQ, Wk, WtK, Wv, WtV,
                                       Wo, WtO, W1, Wt1, W2, Wt2);

    const dim3 gQKV(3 * HD / 128, MROWS / 128);     // 48 x 100
    const dim3 gProj(HD / 128, MROWS / 128);        // 16 x 100
    const dim3 gF1(4 * HID / 128, MROWS / 128);     // 8 x 100

    // fused Q/K/V projection (Q pre-scaled; K head-major; V transposed head-major)
    gemm_qkv<<<gQKV, blk, 0, stream>>>(hb, WtQ, bq, bk, bv, qo, kb, vt);

    // MHA1: attn -> fused out-proj + residual(hidden f32) + LN -> at1
    attn_mfma21<<<2 * BATCH * NH, 512, 0, stream>>>(qo, kb, vt, qo);
    gemm_out_ln<float, ushort_t><<<MROWS / 64, 512, 0, stream>>>(qo, WtO, bo, hidden, at1, HD);

    // MHA2: Q proj from at1; attn; fused out-proj + residual(at1) + LN -> at2
    gemm_bt<false, true><<<gProj, blk, 0, stream>>>(at1, WtQ, bq, qo, MROWS, HD, HID);
    attn_mfma21<<<2 * BATCH * NH, 512, 0, stream>>>(qo, kb, vt, qo);
    gemm_out_ln<ushort_t, ushort_t><<<MROWS / 64, 512, 0, stream>>>(qo, WtO, bo, at1, at2, HD);

    // FFN: W1+ReLU; fused W2 + residual(at2) + LN -> out (f32)
    gemm_bt<true, false><<<gF1, blk, 0, stream>>>(at2, Wt1, b1, ffn1, MROWS, 4 * HID, HID);
    gemm_out_ln<ushort_t, float><<<MROWS / 64, 512, 0, stream>>>(ffn1, Wt2, b2, at2, out, 4 * HID);
}